// Round 5
// baseline (763.267 us; speedup 1.0000x reference)
//
#include <hip/hip_runtime.h>
#include <hip/hip_bf16.h>

#define N_ 2
#define P_ 100
#define C_ 256
#define H_ 128
#define W_ 192
#define HW_ 24576
#define KK_ 9
#define E_ 2304
#define NH_ 8
#define DH_ 288
#define FFN_ 2048
#define NP_ 200
#define ROWS_ 1800   // NP_*KK_
#define XKC_ 64      // xfeat split-K chunks

typedef __attribute__((ext_vector_type(8))) __bf16 bf16x8;
typedef __attribute__((ext_vector_type(4))) float f32x4;

// ---------------- softmax over P axis of mask_preds ----------------
__global__ __launch_bounds__(256) void k_softmax(const float* __restrict__ mp, float* __restrict__ sig){
  int idx = blockIdx.x*256 + threadIdx.x;
  if(idx >= N_*HW_) return;
  int n = idx / HW_, hw = idx - n*HW_;
  const float* base = mp + (size_t)n*P_*HW_ + hw;
  float m = -1e30f;
  for(int p=0;p<P_;p++) m = fmaxf(m, base[(size_t)p*HW_]);
  float s = 0.f;
  for(int p=0;p<P_;p++) s += __expf(base[(size_t)p*HW_] - m);
  float inv = 1.f/s;
  float* ob = sig + (size_t)n*P_*HW_ + hw;
  for(int p=0;p<P_;p++) ob[(size_t)p*HW_] = __expf(base[(size_t)p*HW_] - m)*inv;
}

// ---------------- pf permute: pf[np][kk][c] = prop[n][p][c*9+kk] ----------------
__global__ __launch_bounds__(256) void k_permute_pf(const float* __restrict__ prop, float* __restrict__ pf){
  int i = blockIdx.x*256 + threadIdx.x;
  if(i >= ROWS_*C_) return;
  int c = i & 255;
  int r = i >> 8;            // np*9+kk
  int kk = r % 9, np = r / 9;
  pf[i] = prop[(size_t)np*E_ + c*KK_ + kk];
}

// ---------------- x_feat stage 1: bf16 MFMA split-K ----------------
__global__ __launch_bounds__(256) void k_xfeat1m(const float* __restrict__ sig, const float* __restrict__ x,
                                                 float* __restrict__ partial){
  const int ct = blockIdx.x, kb = blockIdx.y, n = blockIdx.z;
  const int hw0 = kb*384;
  const int tid = threadIdx.x;
  const int wid = tid >> 6, lane = tid & 63;
  const int col = lane & 15, quad = lane >> 4;
  const int wm = wid & 1, wn = wid >> 1;
  const int MT = wm ? 3 : 4;
  __shared__ __bf16 As[112][72];
  __shared__ __bf16 Bs[128][72];
  f32x4 acc[4][4] = {};
  for(int k0=0; k0<384; k0+=64){
    __syncthreads();
    for(int i=tid; i<896; i+=256){
      int p = i >> 3, kg = i & 7;
      bf16x8 v;
      if(p < P_){
        const float* sp = &sig[((size_t)n*P_ + p)*HW_ + hw0 + k0 + kg*8];
        const float4 f0 = *(const float4*)sp;
        const float4 f1 = *(const float4*)(sp+4);
        v[0]=(__bf16)f0.x; v[1]=(__bf16)f0.y; v[2]=(__bf16)f0.z; v[3]=(__bf16)f0.w;
        v[4]=(__bf16)f1.x; v[5]=(__bf16)f1.y; v[6]=(__bf16)f1.z; v[7]=(__bf16)f1.w;
      } else {
        #pragma unroll
        for(int u=0;u<8;u++) v[u] = (__bf16)0.f;
      }
      *(bf16x8*)&As[p][kg*8] = v;
    }
    for(int i=tid; i<1024; i+=256){
      int c = i >> 3, kg = i & 7;
      const float* xp = &x[((size_t)n*C_ + ct*128 + c)*HW_ + hw0 + k0 + kg*8];
      const float4 f0 = *(const float4*)xp;
      const float4 f1 = *(const float4*)(xp+4);
      bf16x8 v;
      v[0]=(__bf16)f0.x; v[1]=(__bf16)f0.y; v[2]=(__bf16)f0.z; v[3]=(__bf16)f0.w;
      v[4]=(__bf16)f1.x; v[5]=(__bf16)f1.y; v[6]=(__bf16)f1.z; v[7]=(__bf16)f1.w;
      *(bf16x8*)&Bs[c][kg*8] = v;
    }
    __syncthreads();
    #pragma unroll
    for(int ks=0; ks<2; ks++){
      bf16x8 b[4];
      #pragma unroll
      for(int t=0;t<4;t++) b[t] = *(const bf16x8*)&Bs[(wn*4+t)*16 + col][ks*32 + quad*8];
      #pragma unroll
      for(int mt=0; mt<4; mt++){
        if(mt < MT){
          bf16x8 a = *(const bf16x8*)&As[(wm*4+mt)*16 + col][ks*32 + quad*8];
          #pragma unroll
          for(int t=0;t<4;t++)
            acc[mt][t] = __builtin_amdgcn_mfma_f32_16x16x32_bf16(a, b[t], acc[mt][t], 0, 0, 0);
        }
      }
    }
  }
  #pragma unroll
  for(int mt=0; mt<4; mt++){
    if(mt < MT){
      #pragma unroll
      for(int r=0;r<4;r++){
        int p = (wm*4+mt)*16 + quad*4 + r;
        if(p < P_){
          float* op = &partial[(((size_t)n*XKC_ + kb)*P_ + p)*C_ + ct*128 + wn*64 + col];
          #pragma unroll
          for(int t=0;t<4;t++) op[t*16] = acc[mt][t][r];
        }
      }
    }
  }
}

// ---------------- x_feat stage 2: reduce over XKC_ chunks ----------------
__global__ __launch_bounds__(256) void k_xfeat2(const float* __restrict__ partial, float* __restrict__ xfeat){
  int np = blockIdx.x;
  int n = np / P_, p = np - n*P_;
  int c = threadIdx.x;
  float s = 0.f;
  for(int kb=0;kb<XKC_;kb++) s += partial[(((size_t)n*XKC_ + kb)*P_ + p)*C_ + c];
  xfeat[(size_t)np*C_ + c] = s;
}

// ---------------- generic bf16 MFMA GEMM: out = act(A @ W^T + bias) ----------------
// BM=64, BN=128, BK=64. act: 0 none, 1 relu, 3 store-bf16.
__global__ __launch_bounds__(256) void k_gemm_mfma(const float* __restrict__ A, const float* __restrict__ Wt,
    const float* __restrict__ bias, float* __restrict__ out, int M, int N, int K, int act)
{
  const int n0 = blockIdx.x*128, m0 = blockIdx.y*64;
  const int tid = threadIdx.x;
  const int wid = tid >> 6, lane = tid & 63;
  const int col = lane & 15, quad = lane >> 4;
  const int wm = wid & 1, wn = wid >> 1;
  __shared__ __bf16 As[64][72];
  __shared__ __bf16 Bs[128][72];
  f32x4 acc[2][4] = {};
  for(int k0=0; k0<K; k0+=64){
    __syncthreads();
    for(int i=tid; i<512; i+=256){
      int r = i >> 3, kg = i & 7;
      int m = m0 + r;
      bf16x8 v;
      if(m < M){
        const float* ap = &A[(size_t)m*K + k0 + kg*8];
        const float4 f0 = *(const float4*)ap;
        const float4 f1 = *(const float4*)(ap+4);
        v[0]=(__bf16)f0.x; v[1]=(__bf16)f0.y; v[2]=(__bf16)f0.z; v[3]=(__bf16)f0.w;
        v[4]=(__bf16)f1.x; v[5]=(__bf16)f1.y; v[6]=(__bf16)f1.z; v[7]=(__bf16)f1.w;
      } else {
        #pragma unroll
        for(int u=0;u<8;u++) v[u] = (__bf16)0.f;
      }
      *(bf16x8*)&As[r][kg*8] = v;
    }
    for(int i=tid; i<1024; i+=256){
      int r = i >> 3, kg = i & 7;
      const float* wp = &Wt[(size_t)(n0 + r)*K + k0 + kg*8];
      const float4 f0 = *(const float4*)wp;
      const float4 f1 = *(const float4*)(wp+4);
      bf16x8 v;
      v[0]=(__bf16)f0.x; v[1]=(__bf16)f0.y; v[2]=(__bf16)f0.z; v[3]=(__bf16)f0.w;
      v[4]=(__bf16)f1.x; v[5]=(__bf16)f1.y; v[6]=(__bf16)f1.z; v[7]=(__bf16)f1.w;
      *(bf16x8*)&Bs[r][kg*8] = v;
    }
    __syncthreads();
    #pragma unroll
    for(int ks=0; ks<2; ks++){
      bf16x8 b[4], a[2];
      #pragma unroll
      for(int t=0;t<4;t++) b[t] = *(const bf16x8*)&Bs[(wn*4+t)*16 + col][ks*32 + quad*8];
      #pragma unroll
      for(int mt=0;mt<2;mt++) a[mt] = *(const bf16x8*)&As[(wm*2+mt)*16 + col][ks*32 + quad*8];
      #pragma unroll
      for(int mt=0;mt<2;mt++)
        #pragma unroll
        for(int t=0;t<4;t++)
          acc[mt][t] = __builtin_amdgcn_mfma_f32_16x16x32_bf16(a[mt], b[t], acc[mt][t], 0, 0, 0);
    }
  }
  #pragma unroll
  for(int mt=0;mt<2;mt++){
    #pragma unroll
    for(int r=0;r<4;r++){
      int m = m0 + (wm*2+mt)*16 + quad*4 + r;
      if(m < M){
        #pragma unroll
        for(int t=0;t<4;t++){
          int n = n0 + (wn*4+t)*16 + col;
          float v = acc[mt][t][r];
          if(bias) v += bias[n];
          if(act == 1) v = fmaxf(v, 0.f);
          if(act == 3) ((__bf16*)out)[(size_t)m*N + n] = (__bf16)v;
          else out[(size_t)m*N + n] = v;
        }
      }
    }
  }
}

// ---------------- full-M split-K GEMM: BM=256 covers all M<=256 rows ----------------
// Each weight element is read by exactly ONE block -> no cross-XCD weight duplication,
// independent of dispatch mapping. grid = (N/128, K/KC). KC%64==0.
__global__ __launch_bounds__(256) void k_gemm_skM256(const float* __restrict__ A, const float* __restrict__ Wt,
    float* __restrict__ part, int M, int N, int K, int KC)
{
  const int n0 = blockIdx.x*128;
  const int kz = blockIdx.y*KC;
  const int tid = threadIdx.x;
  const int wid = tid >> 6, lane = tid & 63;
  const int col = lane & 15, quad = lane >> 4;
  const int wm = wid & 1, wn = wid >> 1;   // wave tile: 128m x 64n
  __shared__ __bf16 As[256][72];
  __shared__ __bf16 Bs[128][72];
  f32x4 acc[8][4] = {};
  for(int k0=kz; k0<kz+KC; k0+=64){
    __syncthreads();
    for(int i=tid; i<2048; i+=256){
      int r = i >> 3, kg = i & 7;
      bf16x8 v;
      if(r < M){
        const float* ap = &A[(size_t)r*K + k0 + kg*8];
        const float4 f0 = *(const float4*)ap;
        const float4 f1 = *(const float4*)(ap+4);
        v[0]=(__bf16)f0.x; v[1]=(__bf16)f0.y; v[2]=(__bf16)f0.z; v[3]=(__bf16)f0.w;
        v[4]=(__bf16)f1.x; v[5]=(__bf16)f1.y; v[6]=(__bf16)f1.z; v[7]=(__bf16)f1.w;
      } else {
        #pragma unroll
        for(int u=0;u<8;u++) v[u] = (__bf16)0.f;
      }
      *(bf16x8*)&As[r][kg*8] = v;
    }
    for(int i=tid; i<1024; i+=256){
      int r = i >> 3, kg = i & 7;
      const float* wp = &Wt[(size_t)(n0 + r)*K + k0 + kg*8];
      const float4 f0 = *(const float4*)wp;
      const float4 f1 = *(const float4*)(wp+4);
      bf16x8 v;
      v[0]=(__bf16)f0.x; v[1]=(__bf16)f0.y; v[2]=(__bf16)f0.z; v[3]=(__bf16)f0.w;
      v[4]=(__bf16)f1.x; v[5]=(__bf16)f1.y; v[6]=(__bf16)f1.z; v[7]=(__bf16)f1.w;
      *(bf16x8*)&Bs[r][kg*8] = v;
    }
    __syncthreads();
    #pragma unroll
    for(int ks=0; ks<2; ks++){
      bf16x8 b[4];
      #pragma unroll
      for(int t=0;t<4;t++) b[t] = *(const bf16x8*)&Bs[(wn*4+t)*16 + col][ks*32 + quad*8];
      #pragma unroll
      for(int mt=0;mt<8;mt++){
        bf16x8 a = *(const bf16x8*)&As[(wm*8+mt)*16 + col][ks*32 + quad*8];
        #pragma unroll
        for(int t=0;t<4;t++)
          acc[mt][t] = __builtin_amdgcn_mfma_f32_16x16x32_bf16(a, b[t], acc[mt][t], 0, 0, 0);
      }
    }
  }
  float* pbase = part + (size_t)blockIdx.y*M*N;
  #pragma unroll
  for(int mt=0;mt<8;mt++){
    #pragma unroll
    for(int r=0;r<4;r++){
      int m = (wm*8+mt)*16 + quad*4 + r;
      if(m < M){
        #pragma unroll
        for(int t=0;t<4;t++){
          int n = n0 + (wn*4+t)*16 + col;
          pbase[(size_t)m*N + n] = acc[mt][t][r];
        }
      }
    }
  }
}

// ---------------- split-K bf16 MFMA GEMM, XCD-grouped 1D grid (ffn2) ----------------
__global__ __launch_bounds__(256) void k_gemm_splitk(const float* __restrict__ A, const float* __restrict__ Wt,
    float* __restrict__ part, int M, int N, int K, int KC, int PX, int MY)
{
  const int wg = blockIdx.x;
  const int xcd = wg & 7, slot = wg >> 3;
  const int mb = slot % MY, pg = slot / MY;
  const int panel = xcd + 8*pg;
  const int PZ = K / KC;
  if(panel >= PX*PZ) return;
  const int px = panel % PX, pz = panel / PX;
  const int n0 = px*128, m0 = mb*64;
  const int kz = pz*KC;
  const int tid = threadIdx.x;
  const int wid = tid >> 6, lane = tid & 63;
  const int col = lane & 15, quad = lane >> 4;
  const int wm = wid & 1, wn = wid >> 1;
  __shared__ __bf16 As[64][72];
  __shared__ __bf16 Bs[128][72];
  f32x4 acc[2][4] = {};
  for(int k0=kz; k0<kz+KC; k0+=64){
    __syncthreads();
    for(int i=tid; i<512; i+=256){
      int r = i >> 3, kg = i & 7;
      int m = m0 + r;
      bf16x8 v;
      if(m < M){
        const float* ap = &A[(size_t)m*K + k0 + kg*8];
        const float4 f0 = *(const float4*)ap;
        const float4 f1 = *(const float4*)(ap+4);
        v[0]=(__bf16)f0.x; v[1]=(__bf16)f0.y; v[2]=(__bf16)f0.z; v[3]=(__bf16)f0.w;
        v[4]=(__bf16)f1.x; v[5]=(__bf16)f1.y; v[6]=(__bf16)f1.z; v[7]=(__bf16)f1.w;
      } else {
        #pragma unroll
        for(int u=0;u<8;u++) v[u] = (__bf16)0.f;
      }
      *(bf16x8*)&As[r][kg*8] = v;
    }
    for(int i=tid; i<1024; i+=256){
      int r = i >> 3, kg = i & 7;
      const float* wp = &Wt[(size_t)(n0 + r)*K + k0 + kg*8];
      const float4 f0 = *(const float4*)wp;
      const float4 f1 = *(const float4*)(wp+4);
      bf16x8 v;
      v[0]=(__bf16)f0.x; v[1]=(__bf16)f0.y; v[2]=(__bf16)f0.z; v[3]=(__bf16)f0.w;
      v[4]=(__bf16)f1.x; v[5]=(__bf16)f1.y; v[6]=(__bf16)f1.z; v[7]=(__bf16)f1.w;
      *(bf16x8*)&Bs[r][kg*8] = v;
    }
    __syncthreads();
    #pragma unroll
    for(int ks=0; ks<2; ks++){
      bf16x8 b[4], a[2];
      #pragma unroll
      for(int t=0;t<4;t++) b[t] = *(const bf16x8*)&Bs[(wn*4+t)*16 + col][ks*32 + quad*8];
      #pragma unroll
      for(int mt=0;mt<2;mt++) a[mt] = *(const bf16x8*)&As[(wm*2+mt)*16 + col][ks*32 + quad*8];
      #pragma unroll
      for(int mt=0;mt<2;mt++)
        #pragma unroll
        for(int t=0;t<4;t++)
          acc[mt][t] = __builtin_amdgcn_mfma_f32_16x16x32_bf16(a[mt], b[t], acc[mt][t], 0, 0, 0);
    }
  }
  float* pbase = part + (size_t)pz*M*N;
  #pragma unroll
  for(int mt=0;mt<2;mt++){
    #pragma unroll
    for(int r=0;r<4;r++){
      int m = m0 + (wm*2+mt)*16 + quad*4 + r;
      if(m < M){
        #pragma unroll
        for(int t=0;t<4;t++){
          int n = n0 + (wn*4+t)*16 + col;
          pbase[(size_t)m*N + n] = acc[mt][t][r];
        }
      }
    }
  }
}

// ---------------- split-K reduce: out = sum_z part[z] + bias ----------------
__global__ __launch_bounds__(256) void k_redk(const float* __restrict__ part, const float* __restrict__ bias,
    float* __restrict__ out, int M, int N, int S)
{
  size_t i4 = ((size_t)blockIdx.x*256 + threadIdx.x)*4;
  size_t MN = (size_t)M*N;
  if(i4 >= MN) return;
  float4 s = *(const float4*)&part[i4];
  for(int z=1; z<S; z++){
    const float4 p = *(const float4*)&part[(size_t)z*MN + i4];
    s.x+=p.x; s.y+=p.y; s.z+=p.z; s.w+=p.w;
  }
  if(bias){
    int n = (int)(i4 % (size_t)N);
    const float4 b = *(const float4*)&bias[n];
    s.x+=b.x; s.y+=b.y; s.z+=b.z; s.w+=b.w;
  }
  *(float4*)&out[i4] = s;
}

// ---------------- row LayerNorm over C=256 (+residual, +act) ----------------
__global__ __launch_bounds__(256) void k_ln256(const float* __restrict__ in, const float* __restrict__ res,
    const float* __restrict__ g, const float* __restrict__ b, float* __restrict__ out, int M, int act)
{
  int row = blockIdx.x*4 + (threadIdx.x >> 6);
  int lane = threadIdx.x & 63;
  if(row >= M) return;
  float4 v = *(const float4*)&in[(size_t)row*C_ + lane*4];
  if(res){
    const float4 rv = *(const float4*)&res[(size_t)row*C_ + lane*4];
    v.x += rv.x; v.y += rv.y; v.z += rv.z; v.w += rv.w;
  }
  float s = v.x + v.y + v.z + v.w;
  float q = v.x*v.x + v.y*v.y + v.z*v.z + v.w*v.w;
  #pragma unroll
  for(int off=32; off; off>>=1){ s += __shfl_xor(s, off, 64); q += __shfl_xor(q, off, 64); }
  float mean = s*(1.f/256.f);
  float rstd = rsqrtf(q*(1.f/256.f) - mean*mean + 1e-5f);
  const float4 gv = *(const float4*)&g[lane*4];
  const float4 bv = *(const float4*)&b[lane*4];
  float o[4] = {(v.x-mean)*rstd*gv.x + bv.x, (v.y-mean)*rstd*gv.y + bv.y,
                (v.z-mean)*rstd*gv.z + bv.z, (v.w-mean)*rstd*gv.w + bv.w};
  #pragma unroll
  for(int j=0;j<4;j++){
    if(act==1) o[j] = fmaxf(o[j], 0.f);
    else if(act==2) o[j] = 1.f/(1.f + __expf(-o[j]));
  }
  float4 ov = {o[0],o[1],o[2],o[3]};
  *(float4*)&out[(size_t)row*C_ + lane*4] = ov;
}

// ---------------- gate = i_in * p_in ----------------
__global__ __launch_bounds__(256) void k_gate(const float* __restrict__ inp, const float* __restrict__ params,
                                              float* __restrict__ gate){
  int i = blockIdx.x*256 + threadIdx.x;
  if(i >= ROWS_*C_) return;
  int c = i & 255, r = i >> 8;
  int np = r / 9;
  gate[i] = inp[(size_t)r*512 + c] * params[(size_t)np*512 + c];
}

// ---------------- block LN helper ----------------
__device__ __forceinline__ void block_stats(float v, float* red, int slot, float& mean, float& rstd){
  float s = v, q = v*v;
  #pragma unroll
  for(int off=32; off; off>>=1){ s += __shfl_xor(s, off, 64); q += __shfl_xor(q, off, 64); }
  int wid = threadIdx.x >> 6;
  if((threadIdx.x & 63) == 0){ red[slot + wid] = s; red[slot + 4 + wid] = q; }
  __syncthreads();
  s = red[slot+0]+red[slot+1]+red[slot+2]+red[slot+3];
  q = red[slot+4]+red[slot+5]+red[slot+6]+red[slot+7];
  mean = s*(1.f/256.f);
  rstd = rsqrtf(q*(1.f/256.f) - mean*mean + 1e-5f);
}

// ---------------- feat = ug * LN(p_out) + ig * LN(i_out) ----------------
__global__ __launch_bounds__(256) void k_combine(const float* __restrict__ params, const float* __restrict__ inp,
  const float* __restrict__ ug, const float* __restrict__ ig,
  const float* __restrict__ nout_g, const float* __restrict__ nout_b,
  const float* __restrict__ inout_g, const float* __restrict__ inout_b,
  float* __restrict__ feat)
{
  __shared__ float red[16];
  int r = blockIdx.x;           // np*9+kk
  int np = r / 9;
  int c = threadIdx.x;
  float pv = params[(size_t)np*512 + 256 + c];
  float mean, rstd;
  block_stats(pv, red, 0, mean, rstd);
  float pn = (pv - mean)*rstd*nout_g[c] + nout_b[c];
  float iv = inp[(size_t)r*512 + 256 + c];
  float mean2, rstd2;
  block_stats(iv, red, 8, mean2, rstd2);
  float iw = (iv - mean2)*rstd2*inout_g[c] + inout_b[c];
  size_t o = (size_t)r*C_ + c;
  feat[o] = ug[o]*pn + ig[o]*iw;
}

// ---------------- attention v2 ----------------
__global__ __launch_bounds__(256) void k_attn2(const float* __restrict__ qkv, float* __restrict__ attnO){
  const int qt = blockIdx.x, h = blockIdx.y, n = blockIdx.z;
  const int q0 = qt*10;
  const int tid = threadIdx.x;
  __shared__ float Qs[10][292];
  __shared__ float KVs[25][292];
  __shared__ float Ss[10][104];
  const float scale = 0.05892556509887896f;   // 1/sqrt(288)
  const size_t base = (size_t)n*P_*6912 + (size_t)h*DH_;
  for(int i=tid; i<10*DH_; i+=256){
    int qi = i/DH_, d = i - qi*DH_;
    Qs[qi][d] = qkv[base + (size_t)(q0+qi)*6912 + d] * scale;
  }
  for(int kt=0; kt<4; kt++){
    int kp0 = kt*25;
    __syncthreads();
    for(int i=tid; i<25*DH_; i+=256){
      int ki = i/DH_, d = i - ki*DH_;
      KVs[ki][d] = qkv[base + (size_t)(kp0+ki)*6912 + E_ + d];
    }
    __syncthreads();
    if(tid < 250){
      int qi = tid/25, ki = tid - qi*25;
      float s = 0.f;
      #pragma unroll 9
      for(int d=0; d<DH_; d+=4){
        const float4 a = *(const float4*)&Qs[qi][d];
        const float4 b = *(const float4*)&KVs[ki][d];
        s += a.x*b.x + a.y*b.y + a.z*b.z + a.w*b.w;
      }
      Ss[qi][kp0+ki] = s;
    }
  }
  __syncthreads();
  {
    int w = tid >> 6, lane = tid & 63;
    for(int r=w; r<10; r+=4){
      float v0 = (lane < 100) ? Ss[r][lane] : -1e30f;
      float v1 = (lane < 36)  ? Ss[r][64+lane] : -1e30f;
      float m = fmaxf(v0, v1);
      #pragma unroll
      for(int off=32; off; off>>=1) m = fmaxf(m, __shfl_xor(m, off, 64));
      float e0 = (lane < 100) ? __expf(v0-m) : 0.f;
      float e1 = (lane < 36)  ? __expf(v1-m) : 0.f;
      float s = e0 + e1;
      #pragma unroll
      for(int off=32; off; off>>=1) s += __shfl_xor(s, off, 64);
      float inv = 1.f/s;
      if(lane < 100) Ss[r][lane] = e0*inv;
      if(lane < 36)  Ss[r][64+lane] = e1*inv;
    }
  }
  float acc[12];
  #pragma unroll
  for(int j=0;j<12;j++) acc[j]=0.f;
  for(int kt=0; kt<4; kt++){
    int kp0 = kt*25;
    __syncthreads();
    for(int i=tid; i<25*DH_; i+=256){
      int ki = i/DH_, d = i - ki*DH_;
      KVs[ki][d] = qkv[base + (size_t)(kp0+ki)*6912 + 2*E_ + d];
    }
    __syncthreads();
    int j = 0;
    for(int i=tid; i<10*DH_; i+=256, j++){
      int qi = i/DH_, d = i - qi*DH_;
      float s = acc[j];
      #pragma unroll
      for(int ki=0; ki<25; ki++) s += Ss[qi][kp0+ki]*KVs[ki][d];
      acc[j] = s;
    }
  }
  {
    int j = 0;
    for(int i=tid; i<10*DH_; i+=256, j++){
      int qi = i/DH_, d = i - qi*DH_;
      attnO[(size_t)(n*P_ + q0 + qi)*E_ + h*DH_ + d] = acc[j];
    }
  }
}

// ---------------- obj1 = LN(obj0 + tproj) over E=2304 ----------------
__global__ __launch_bounds__(256) void k_add_ln2304(const float* __restrict__ obj0, const float* __restrict__ tp,
  const float* __restrict__ g, const float* __restrict__ b, float* __restrict__ out)
{
  __shared__ float red[8];
  int row = blockIdx.x;
  float v[9]; float s=0.f, q=0.f;
  #pragma unroll
  for(int j=0;j<9;j++){
    int e = threadIdx.x + j*256;
    float t = obj0[(size_t)row*E_ + e] + tp[(size_t)row*E_ + e];
    v[j]=t; s+=t; q+=t*t;
  }
  #pragma unroll
  for(int off=32; off; off>>=1){ s += __shfl_xor(s, off, 64); q += __shfl_xor(q, off, 64); }
  int wid = threadIdx.x>>6;
  if((threadIdx.x&63)==0){ red[wid]=s; red[4+wid]=q; }
  __syncthreads();
  s = red[0]+red[1]+red[2]+red[3]; q = red[4]+red[5]+red[6]+red[7];
  float mean = s*(1.f/2304.f);
  float rstd = rsqrtf(q*(1.f/2304.f) - mean*mean + 1e-5f);
  #pragma unroll
  for(int j=0;j<9;j++){
    int e = threadIdx.x + j*256;
    out[(size_t)row*E_ + e] = (v[j]-mean)*rstd*g[e] + b[e];
  }
}

// ---------------- obj_kernels output transpose ----------------
__global__ __launch_bounds__(256) void k_objk(const float* __restrict__ obj2, float* __restrict__ outk){
  int i = blockIdx.x*256 + threadIdx.x;
  if(i >= ROWS_*C_) return;
  int kk = i % 9; int t = i / 9; int c = t & 255; int np = t >> 8;
  outk[i] = obj2[((size_t)np*9 + kk)*C_ + c];
}

// ---------------- x pre-transpose to bf16: xT[n][c/8][h][w][8] ----------------
__global__ __launch_bounds__(256) void k_prep_x(const float* __restrict__ x, __bf16* __restrict__ xT){
  int i = blockIdx.x*256 + threadIdx.x;     // (n, g, h, w) flattened
  if(i >= N_*32*H_*W_) return;
  int w = i % W_; int t = i / W_;
  int h = t % H_; t /= H_;
  int g = t % 32; int n = t / 32;
  const float* xp = &x[((size_t)(n*C_ + g*8)*H_ + h)*W_ + w];
  bf16x8 v;
  #pragma unroll
  for(int u=0;u<8;u++) v[u] = (__bf16)xp[(size_t)u*HW_];
  *(bf16x8*)&xT[(size_t)i*8] = v;
}

// ---------------- kernel permute: kerP[nps][c0b][tap][oct][pl][8] from mfF(bf16) ----------------
// Exact LDS staging order of k_conv_mfma -> conv's ks stage is a linear coalesced copy.
// Zero-pads pl rows where p >= P_.
__global__ __launch_bounds__(256) void k_permute_ker(const __bf16* __restrict__ mfFb, __bf16* __restrict__ kerP){
  int i = blockIdx.x*256 + threadIdx.x;   // bf16x8 index
  if(i >= 73728) return;                  // 4 nps * 8 c0b * 9 tap * 4 oct * 64 pl
  int pl = i & 63; int t = i >> 6;
  int oct = t & 3; t >>= 2;
  int tap = t % 9; t /= 9;
  int c0b = t & 7; int nps = t >> 3;
  int n = nps >> 1, ps = nps & 1;
  int p = ps*64 + pl;
  bf16x8 v;
  if(p < P_){
    v = *(const bf16x8*)&mfFb[((size_t)(n*P_+p)*9 + tap)*C_ + c0b*32 + oct*8];
  } else {
    #pragma unroll
    for(int u=0;u<8;u++) v[u] = (__bf16)0.f;
  }
  *(bf16x8*)&kerP[(size_t)i*8] = v;
}

// ---------------- dynamic conv via implicit-GEMM bf16 MFMA ----------------
// 64-wide w tiles, kerP pre-permuted: ks staging is a linear coalesced 36.9KB copy
// (was a 4.6KB-strided gather = 64 cache lines per wave = the R4 bottleneck).
__global__ __launch_bounds__(256) void k_conv_mfma(const __bf16* __restrict__ xT, const __bf16* __restrict__ kerP,
                                                   float* __restrict__ out){
  const int wt = blockIdx.x, ht = blockIdx.y, z = blockIdx.z;
  const int n = z >> 1, ps = z & 1;
  const int pbase = ps*64;
  const int NT = ps ? 3 : 4;
  const int tid = threadIdx.x;
  const int hi = tid >> 6;
  const int lane = tid & 63;
  const int col = lane & 15, quad = lane >> 4;
  const int w0 = wt*64, h0 = ht*4;

  __shared__ __bf16 xs[6][4][66][8];
  __shared__ __bf16 ks[9][4][64][8];
  __bf16* ksf = &ks[0][0][0][0];

  f32x4 acc[4][4] = {};

  for(int c0=0; c0<C_; c0+=32){
    __syncthreads();
    // stage x tile: coalesced 16B loads, linear LDS write
    for(int i=tid; i<1584; i+=256){
      int oct = i / 396;
      int rem = i - oct*396;
      int hy = rem / 66, wx = rem - hy*66;
      int hh = h0 - 1 + hy, ww = w0 - 1 + wx;
      bf16x8 v;
      if(hh >= 0 && hh < H_ && ww >= 0 && ww < W_){
        v = *(const bf16x8*)&xT[((((size_t)n*32 + (c0>>3) + oct)*H_ + hh)*W_ + ww)*8];
      } else {
        #pragma unroll
        for(int u=0;u<8;u++) v[u] = (__bf16)0.f;
      }
      *(bf16x8*)&xs[hy][oct][wx][0] = v;
    }
    // stage kernel tile: LINEAR copy from kerP chunk (perfectly coalesced)
    {
      const __bf16* kp = kerP + ((size_t)(n*2+ps)*8 + (c0>>5))*2304*8;
      for(int i=tid; i<2304; i+=256)
        *(bf16x8*)&ksf[(size_t)i*8] = *(const bf16x8*)&kp[(size_t)i*8];
    }
    __syncthreads();
    #pragma unroll
    for(int ky=0; ky<3; ky++){
      #pragma unroll
      for(int kx=0; kx<3; kx++){
        const int tap = ky*3 + kx;
        const int hy = hi + ky;
        bf16x8 b[4];
        #pragma unroll
        for(int t=0;t<4;t++) b[t] = *(const bf16x8*)&xs[hy][quad][t*16 + col + kx][0];
        #pragma unroll
        for(int pt=0; pt<4; pt++){
          if(pt < NT){
            bf16x8 a = *(const bf16x8*)&ks[tap][quad][pt*16 + col][0];
            #pragma unroll
            for(int t=0;t<4;t++)
              acc[pt][t] = __builtin_amdgcn_mfma_f32_16x16x32_bf16(a, b[t], acc[pt][t], 0, 0, 0);
          }
        }
      }
    }
  }
  const int h = h0 + hi;
  #pragma unroll
  for(int pt=0; pt<4; pt++){
    if(pt < NT){
      #pragma unroll
      for(int r=0;r<4;r++){
        int p = pbase + pt*16 + quad*4 + r;
        if(p < P_){
          float* op = &out[((size_t)(n*P_+p)*H_ + h)*W_ + w0 + col];
          #pragma unroll
          for(int t=0;t<4;t++) op[t*16] = acc[pt][t][r];
        }
      }
    }
  }
}

extern "C" void kernel_launch(void* const* d_in, const int* in_sizes, int n_in,
                              void* d_out, int out_size, void* d_ws, size_t ws_size,
                              hipStream_t stream)
{
  (void)in_sizes; (void)n_in; (void)out_size; (void)ws_size;
  const float* x          = (const float*)d_in[0];
  const float* prop       = (const float*)d_in[1];
  const float* mask_pred  = (const float*)d_in[2];
  const float* ku_dyn_w   = (const float*)d_in[3];
  const float* ku_dyn_b   = (const float*)d_in[4];
  const float* ku_in_w    = (const float*)d_in[5];
  const float* ku_in_b    = (const float*)d_in[6];
  const float* ku_ig_w    = (const float*)d_in[7];
  const float* ku_ig_b    = (const float*)d_in[8];
  const float* ku_ug_w    = (const float*)d_in[9];
  const float* ku_ug_b    = (const float*)d_in[10];
  const float* ku_nin_g   = (const float*)d_in[11];
  const float* ku_nin_b   = (const float*)d_in[12];
  const float* ku_nout_g  = (const float*)d_in[13];
  const float* ku_nout_b  = (const float*)d_in[14];
  const float* ku_inin_g  = (const float*)d_in[15];
  const float* ku_inin_b  = (const float*)d_in[16];
  const float* ku_inout_g = (const float*)d_in[17];
  const float* ku_inout_b = (const float*)d_in[18];
  const float* ku_fc_w    = (const float*)d_in[19];
  const float* ku_fc_b    = (const float*)d_in[20];
  const float* ku_fcn_g   = (const float*)d_in[21];
  const float* ku_fcn_b   = (const float*)d_in[22];
  const float* attn_in_w  = (const float*)d_in[23];
  const float* attn_in_b  = (const float*)d_in[24];
  const float* attn_out_w = (const float*)d_in[25];
  const float* attn_out_b = (const float*)d_in[26];
  const float* attn_ln_g  = (const float*)d_in[27];
  const float* attn_ln_b  = (const float*)d_in[28];
  const float* ffn_w1     = (const float*)d_in[29];
  const float* ffn_b1     = (const float*)d_in[30];
  const float* ffn_w2     = (const float*)d_in[31];
  const float* ffn_b2     = (const float*)d_in[32];
  const float* ffn_ln_g   = (const float*)d_in[33];
  const float* ffn_ln_b   = (const float*)d_in[34];
  const float* mask_fc_ws = (const float*)d_in[35];
  const float* mask_fc_ln_g = (const float*)d_in[36];
  const float* mask_fc_ln_b = (const float*)d_in[37];
  const float* fc_mask_w  = (const float*)d_in[38];
  const float* fc_mask_b  = (const float*)d_in[39];

  float* ws = (float*)d_ws;
  float* sig     = ws;
  float* hbuf    = ws;
  float* skA     = ws;                // split-K scratch (attn GEMMs): 4.92M floats
  float* partial = ws + 4915200;      // dead after k_xfeat2
  float* qkv     = ws + 4915200;
  float* skB     = ws + 4915200;      // split-K scratch (ffn2)
  float* attnO   = ws + 4915200 + 1382400;
  float* tproj   = ws + 4915200 + 1843200;
  float* tmp     = ws + 4915200 + 2304000;  // pre-LN gemm output (1800x256)
  float* xfeat   = ws + 9830400;
  float* params  = xfeat + 51200;
  float* pf      = params + 102400;
  float* inp     = pf + 460800;
  float* gate    = inp + 921600;
  float* ig      = gate + 460800;
  float* ug      = ig + 460800;
  float* feat    = ug + 460800;
  float* obj0    = feat + 460800;
  float* obj1    = obj0 + 460800;
  float* obj2    = obj1 + 460800;
  float* mf1     = obj2 + 460800;
  float* mf2     = mf1 + 460800;
  float* mfF     = mf2 + 460800;
  // xT (bf16) at ws[0..6291456 float slots): sig/hbuf/skA/qkv/skB dead by k_prep_x.
  __bf16* xT = (__bf16*)ws;
  // kerP (bf16, 589824 elems = 294912 float slots) in dead tproj region (cap 460800);
  // written after the mask_fc chain (tproj long dead), xT ends at 6291456 < 6758400.
  __bf16* kerP = (__bf16*)(ws + 6758400);

  float* out_masks = (float*)d_out;
  float* out_kern  = out_masks + (size_t)N_*P_*HW_;

  k_softmax<<<192, 256, 0, stream>>>(mask_pred, sig);
  k_permute_pf<<<1800, 256, 0, stream>>>(prop, pf);
  k_xfeat1m<<<dim3(2,XKC_,2), 256, 0, stream>>>(sig, x, partial);
  k_xfeat2<<<200, 256, 0, stream>>>(partial, xfeat);
  k_gemm_mfma<<<dim3(4,4),   256, 0, stream>>>(xfeat, ku_dyn_w, ku_dyn_b, params, 200, 512, 256, 0);
  k_gemm_mfma<<<dim3(4,29),  256, 0, stream>>>(pf, ku_in_w, ku_in_b, inp, 1800, 512, 256, 0);
  k_gate<<<1800, 256, 0, stream>>>(inp, params, gate);
  k_gemm_mfma<<<dim3(2,29),  256, 0, stream>>>(gate, ku_ig_w, ku_ig_b, tmp, 1800, 256, 256, 0);
  k_ln256<<<450, 256, 0, stream>>>(tmp, nullptr, ku_inin_g, ku_inin_b, ig, 1800, 2);
  k_gemm_mfma<<<dim3(2,29),  256, 0, stream>>>(gate, ku_ug_w, ku_ug_b, tmp, 1800, 256, 256, 0);
  k_ln256<<<450, 256, 0, stream>>>(tmp, nullptr, ku_nin_g, ku_nin_b, ug, 1800, 2);
  k_combine<<<1800, 256, 0, stream>>>(params, inp, ug, ig, ku_nout_g, ku_nout_b, ku_inout_g, ku_inout_b, feat);
  k_gemm_mfma<<<dim3(2,29),  256, 0, stream>>>(feat, ku_fc_w, ku_fc_b, tmp, 1800, 256, 256, 0);
  k_ln256<<<450, 256, 0, stream>>>(tmp, nullptr, ku_fcn_g, ku_fcn_b, obj0, 1800, 1);
  // attn_in: full-M blocks, split-K x3 (KC=768): each weight element read by exactly one block
  k_gemm_skM256<<<dim3(54,3), 256, 0, stream>>>(obj0, attn_in_w, skA, 200, 6912, 2304, 768);
  k_redk<<<1350, 256, 0, stream>>>(skA, attn_in_b, qkv, 200, 6912, 3);
  k_attn2<<<dim3(10,8,2), 256, 0, stream>>>(qkv, attnO);
  // attn_out: full-M blocks, split-K x9 (KC=256)
  k_gemm_skM256<<<dim3(18,9), 256, 0, stream>>>(attnO, attn_out_w, skA, 200, 2304, 2304, 256);
  k_redk<<<450, 256, 0, stream>>>(skA, attn_out_b, tproj, 200, 2304, 9);
  k_add_ln2304<<<200, 256, 0, stream>>>(obj0, tproj, attn_ln_g, attn_ln_b, obj1);
  k_gemm_mfma<<<dim3(16,29), 256, 0, stream>>>(obj1, ffn_w1, ffn_b1, hbuf, 1800, 2048, 256, 1);
  // ffn2: split-K x4 (K=2048 -> 4x512); scratch in dead qkv region
  k_gemm_splitk<<<232, 256, 0, stream>>>(hbuf, ffn_w2, skB, 1800, 256, 2048, 512, 2, 29);
  k_redk<<<450, 256, 0, stream>>>(skB, ffn_b2, tmp, 1800, 256, 4);
  k_ln256<<<450, 256, 0, stream>>>(tmp, obj1, ffn_ln_g, ffn_ln_b, obj2, 1800, 0);
  k_gemm_mfma<<<dim3(2,29),  256, 0, stream>>>(obj2, mask_fc_ws,          nullptr, tmp, 1800, 256, 256, 0);
  k_ln256<<<450, 256, 0, stream>>>(tmp, nullptr, mask_fc_ln_g,       mask_fc_ln_b,       mf1, 1800, 1);
  k_gemm_mfma<<<dim3(2,29),  256, 0, stream>>>(mf1,  mask_fc_ws + 65536,  nullptr, tmp, 1800, 256, 256, 0);
  k_ln256<<<450, 256, 0, stream>>>(tmp, nullptr, mask_fc_ln_g + 256, mask_fc_ln_b + 256, mf2, 1800, 1);
  k_gemm_mfma<<<dim3(2,29),  256, 0, stream>>>(mf2,  mask_fc_ws + 131072, nullptr, tmp, 1800, 256, 256, 0);
  k_ln256<<<450, 256, 0, stream>>>(tmp, nullptr, mask_fc_ln_g + 512, mask_fc_ln_b + 512, mf1, 1800, 1);
  // final kernel GEMM stores bf16 directly (identical numerics: same RNE convert)
  k_gemm_mfma<<<dim3(2,29),  256, 0, stream>>>(mf1, fc_mask_w, fc_mask_b, mfF, 1800, 256, 256, 3);
  k_objk<<<1800, 256, 0, stream>>>(obj2, out_kern);
  k_permute_ker<<<288, 256, 0, stream>>>((const __bf16*)mfF, kerP);
  k_prep_x<<<6144, 256, 0, stream>>>(x, xT);
  k_conv_mfma<<<dim3(3,32,4), 256, 0, stream>>>(xT, kerP, out_masks);
}

// Round 6
// 722.387 us; speedup vs baseline: 1.0566x; 1.0566x over previous
//
#include <hip/hip_runtime.h>
#include <hip/hip_bf16.h>

#define N_ 2
#define P_ 100
#define C_ 256
#define H_ 128
#define W_ 192
#define HW_ 24576
#define KK_ 9
#define E_ 2304
#define NH_ 8
#define DH_ 288
#define FFN_ 2048
#define NP_ 200
#define ROWS_ 1800   // NP_*KK_
#define XKC_ 64      // xfeat split-K chunks

typedef __attribute__((ext_vector_type(8))) __bf16 bf16x8;
typedef __attribute__((ext_vector_type(4))) float f32x4;

// ---------------- softmax over P axis of mask_preds ----------------
__global__ __launch_bounds__(256) void k_softmax(const float* __restrict__ mp, float* __restrict__ sig){
  int idx = blockIdx.x*256 + threadIdx.x;
  if(idx >= N_*HW_) return;
  int n = idx / HW_, hw = idx - n*HW_;
  const float* base = mp + (size_t)n*P_*HW_ + hw;
  float m = -1e30f;
  for(int p=0;p<P_;p++) m = fmaxf(m, base[(size_t)p*HW_]);
  float s = 0.f;
  for(int p=0;p<P_;p++) s += __expf(base[(size_t)p*HW_] - m);
  float inv = 1.f/s;
  float* ob = sig + (size_t)n*P_*HW_ + hw;
  for(int p=0;p<P_;p++) ob[(size_t)p*HW_] = __expf(base[(size_t)p*HW_] - m)*inv;
}

// ---------------- pf permute: pf[np][kk][c] = prop[n][p][c*9+kk] ----------------
__global__ __launch_bounds__(256) void k_permute_pf(const float* __restrict__ prop, float* __restrict__ pf){
  int i = blockIdx.x*256 + threadIdx.x;
  if(i >= ROWS_*C_) return;
  int c = i & 255;
  int r = i >> 8;            // np*9+kk
  int kk = r % 9, np = r / 9;
  pf[i] = prop[(size_t)np*E_ + c*KK_ + kk];
}

// ---------------- x_feat stage 1: bf16 MFMA split-K ----------------
__global__ __launch_bounds__(256) void k_xfeat1m(const float* __restrict__ sig, const float* __restrict__ x,
                                                 float* __restrict__ partial){
  const int ct = blockIdx.x, kb = blockIdx.y, n = blockIdx.z;
  const int hw0 = kb*384;
  const int tid = threadIdx.x;
  const int wid = tid >> 6, lane = tid & 63;
  const int col = lane & 15, quad = lane >> 4;
  const int wm = wid & 1, wn = wid >> 1;
  const int MT = wm ? 3 : 4;
  __shared__ __bf16 As[112][72];
  __shared__ __bf16 Bs[128][72];
  f32x4 acc[4][4] = {};
  for(int k0=0; k0<384; k0+=64){
    __syncthreads();
    for(int i=tid; i<896; i+=256){
      int p = i >> 3, kg = i & 7;
      bf16x8 v;
      if(p < P_){
        const float* sp = &sig[((size_t)n*P_ + p)*HW_ + hw0 + k0 + kg*8];
        const float4 f0 = *(const float4*)sp;
        const float4 f1 = *(const float4*)(sp+4);
        v[0]=(__bf16)f0.x; v[1]=(__bf16)f0.y; v[2]=(__bf16)f0.z; v[3]=(__bf16)f0.w;
        v[4]=(__bf16)f1.x; v[5]=(__bf16)f1.y; v[6]=(__bf16)f1.z; v[7]=(__bf16)f1.w;
      } else {
        #pragma unroll
        for(int u=0;u<8;u++) v[u] = (__bf16)0.f;
      }
      *(bf16x8*)&As[p][kg*8] = v;
    }
    for(int i=tid; i<1024; i+=256){
      int c = i >> 3, kg = i & 7;
      const float* xp = &x[((size_t)n*C_ + ct*128 + c)*HW_ + hw0 + k0 + kg*8];
      const float4 f0 = *(const float4*)xp;
      const float4 f1 = *(const float4*)(xp+4);
      bf16x8 v;
      v[0]=(__bf16)f0.x; v[1]=(__bf16)f0.y; v[2]=(__bf16)f0.z; v[3]=(__bf16)f0.w;
      v[4]=(__bf16)f1.x; v[5]=(__bf16)f1.y; v[6]=(__bf16)f1.z; v[7]=(__bf16)f1.w;
      *(bf16x8*)&Bs[c][kg*8] = v;
    }
    __syncthreads();
    #pragma unroll
    for(int ks=0; ks<2; ks++){
      bf16x8 b[4];
      #pragma unroll
      for(int t=0;t<4;t++) b[t] = *(const bf16x8*)&Bs[(wn*4+t)*16 + col][ks*32 + quad*8];
      #pragma unroll
      for(int mt=0; mt<4; mt++){
        if(mt < MT){
          bf16x8 a = *(const bf16x8*)&As[(wm*4+mt)*16 + col][ks*32 + quad*8];
          #pragma unroll
          for(int t=0;t<4;t++)
            acc[mt][t] = __builtin_amdgcn_mfma_f32_16x16x32_bf16(a, b[t], acc[mt][t], 0, 0, 0);
        }
      }
    }
  }
  #pragma unroll
  for(int mt=0; mt<4; mt++){
    if(mt < MT){
      #pragma unroll
      for(int r=0;r<4;r++){
        int p = (wm*4+mt)*16 + quad*4 + r;
        if(p < P_){
          float* op = &partial[(((size_t)n*XKC_ + kb)*P_ + p)*C_ + ct*128 + wn*64 + col];
          #pragma unroll
          for(int t=0;t<4;t++) op[t*16] = acc[mt][t][r];
        }
      }
    }
  }
}

// ---------------- x_feat stage 2: reduce over XKC_ chunks ----------------
__global__ __launch_bounds__(256) void k_xfeat2(const float* __restrict__ partial, float* __restrict__ xfeat){
  int np = blockIdx.x;
  int n = np / P_, p = np - n*P_;
  int c = threadIdx.x;
  float s = 0.f;
  for(int kb=0;kb<XKC_;kb++) s += partial[(((size_t)n*XKC_ + kb)*P_ + p)*C_ + c];
  xfeat[(size_t)np*C_ + c] = s;
}

// ---------------- generic bf16 MFMA GEMM: out = act(A @ W^T + bias) ----------------
// BM=64, BN=128, BK=64. act: 0 none, 1 relu, 3 store-bf16.
__global__ __launch_bounds__(256) void k_gemm_mfma(const float* __restrict__ A, const float* __restrict__ Wt,
    const float* __restrict__ bias, float* __restrict__ out, int M, int N, int K, int act)
{
  const int n0 = blockIdx.x*128, m0 = blockIdx.y*64;
  const int tid = threadIdx.x;
  const int wid = tid >> 6, lane = tid & 63;
  const int col = lane & 15, quad = lane >> 4;
  const int wm = wid & 1, wn = wid >> 1;
  __shared__ __bf16 As[64][72];
  __shared__ __bf16 Bs[128][72];
  f32x4 acc[2][4] = {};
  for(int k0=0; k0<K; k0+=64){
    __syncthreads();
    for(int i=tid; i<512; i+=256){
      int r = i >> 3, kg = i & 7;
      int m = m0 + r;
      bf16x8 v;
      if(m < M){
        const float* ap = &A[(size_t)m*K + k0 + kg*8];
        const float4 f0 = *(const float4*)ap;
        const float4 f1 = *(const float4*)(ap+4);
        v[0]=(__bf16)f0.x; v[1]=(__bf16)f0.y; v[2]=(__bf16)f0.z; v[3]=(__bf16)f0.w;
        v[4]=(__bf16)f1.x; v[5]=(__bf16)f1.y; v[6]=(__bf16)f1.z; v[7]=(__bf16)f1.w;
      } else {
        #pragma unroll
        for(int u=0;u<8;u++) v[u] = (__bf16)0.f;
      }
      *(bf16x8*)&As[r][kg*8] = v;
    }
    for(int i=tid; i<1024; i+=256){
      int r = i >> 3, kg = i & 7;
      const float* wp = &Wt[(size_t)(n0 + r)*K + k0 + kg*8];
      const float4 f0 = *(const float4*)wp;
      const float4 f1 = *(const float4*)(wp+4);
      bf16x8 v;
      v[0]=(__bf16)f0.x; v[1]=(__bf16)f0.y; v[2]=(__bf16)f0.z; v[3]=(__bf16)f0.w;
      v[4]=(__bf16)f1.x; v[5]=(__bf16)f1.y; v[6]=(__bf16)f1.z; v[7]=(__bf16)f1.w;
      *(bf16x8*)&Bs[r][kg*8] = v;
    }
    __syncthreads();
    #pragma unroll
    for(int ks=0; ks<2; ks++){
      bf16x8 b[4], a[2];
      #pragma unroll
      for(int t=0;t<4;t++) b[t] = *(const bf16x8*)&Bs[(wn*4+t)*16 + col][ks*32 + quad*8];
      #pragma unroll
      for(int mt=0;mt<2;mt++) a[mt] = *(const bf16x8*)&As[(wm*2+mt)*16 + col][ks*32 + quad*8];
      #pragma unroll
      for(int mt=0;mt<2;mt++)
        #pragma unroll
        for(int t=0;t<4;t++)
          acc[mt][t] = __builtin_amdgcn_mfma_f32_16x16x32_bf16(a[mt], b[t], acc[mt][t], 0, 0, 0);
    }
  }
  #pragma unroll
  for(int mt=0;mt<2;mt++){
    #pragma unroll
    for(int r=0;r<4;r++){
      int m = m0 + (wm*2+mt)*16 + quad*4 + r;
      if(m < M){
        #pragma unroll
        for(int t=0;t<4;t++){
          int n = n0 + (wn*4+t)*16 + col;
          float v = acc[mt][t][r];
          if(bias) v += bias[n];
          if(act == 1) v = fmaxf(v, 0.f);
          if(act == 3) ((__bf16*)out)[(size_t)m*N + n] = (__bf16)v;
          else out[(size_t)m*N + n] = v;
        }
      }
    }
  }
}

// ---------------- full-M split-K GEMM: BM=256 x BN=64 ----------------
// Covers all M<=256 rows in one block (weight element -> exactly one block, no
// cross-XCD weight duplication) while BN=64 + deep split-K restores parallelism
// (R5 lesson: dedup at 162 blocks was latency-bound, 6.6% occupancy).
// grid = (N/64, K/KC). KC%64==0. LDS 46KB -> 3 blocks/CU.
__global__ __launch_bounds__(256) void k_gemm_skM256(const float* __restrict__ A, const float* __restrict__ Wt,
    float* __restrict__ part, int M, int N, int K, int KC)
{
  const int n0 = blockIdx.x*64;
  const int kz = blockIdx.y*KC;
  const int tid = threadIdx.x;
  const int wid = tid >> 6, lane = tid & 63;
  const int col = lane & 15, quad = lane >> 4;
  const int wm = wid & 1, wn = wid >> 1;   // wave tile: 128m x 32n
  __shared__ __bf16 As[256][72];
  __shared__ __bf16 Bs[64][72];
  f32x4 acc[8][2] = {};
  for(int k0=kz; k0<kz+KC; k0+=64){
    __syncthreads();
    for(int i=tid; i<2048; i+=256){
      int r = i >> 3, kg = i & 7;
      bf16x8 v;
      if(r < M){
        const float* ap = &A[(size_t)r*K + k0 + kg*8];
        const float4 f0 = *(const float4*)ap;
        const float4 f1 = *(const float4*)(ap+4);
        v[0]=(__bf16)f0.x; v[1]=(__bf16)f0.y; v[2]=(__bf16)f0.z; v[3]=(__bf16)f0.w;
        v[4]=(__bf16)f1.x; v[5]=(__bf16)f1.y; v[6]=(__bf16)f1.z; v[7]=(__bf16)f1.w;
      } else {
        #pragma unroll
        for(int u=0;u<8;u++) v[u] = (__bf16)0.f;
      }
      *(bf16x8*)&As[r][kg*8] = v;
    }
    for(int i=tid; i<512; i+=256){
      int r = i >> 3, kg = i & 7;
      const float* wp = &Wt[(size_t)(n0 + r)*K + k0 + kg*8];
      const float4 f0 = *(const float4*)wp;
      const float4 f1 = *(const float4*)(wp+4);
      bf16x8 v;
      v[0]=(__bf16)f0.x; v[1]=(__bf16)f0.y; v[2]=(__bf16)f0.z; v[3]=(__bf16)f0.w;
      v[4]=(__bf16)f1.x; v[5]=(__bf16)f1.y; v[6]=(__bf16)f1.z; v[7]=(__bf16)f1.w;
      *(bf16x8*)&Bs[r][kg*8] = v;
    }
    __syncthreads();
    #pragma unroll
    for(int ks=0; ks<2; ks++){
      bf16x8 b[2];
      #pragma unroll
      for(int t=0;t<2;t++) b[t] = *(const bf16x8*)&Bs[(wn*2+t)*16 + col][ks*32 + quad*8];
      #pragma unroll
      for(int mt=0;mt<8;mt++){
        bf16x8 a = *(const bf16x8*)&As[(wm*8+mt)*16 + col][ks*32 + quad*8];
        #pragma unroll
        for(int t=0;t<2;t++)
          acc[mt][t] = __builtin_amdgcn_mfma_f32_16x16x32_bf16(a, b[t], acc[mt][t], 0, 0, 0);
      }
    }
  }
  float* pbase = part + (size_t)blockIdx.y*M*N;
  #pragma unroll
  for(int mt=0;mt<8;mt++){
    #pragma unroll
    for(int r=0;r<4;r++){
      int m = (wm*8+mt)*16 + quad*4 + r;
      if(m < M){
        #pragma unroll
        for(int t=0;t<2;t++){
          int n = n0 + (wn*2+t)*16 + col;
          pbase[(size_t)m*N + n] = acc[mt][t][r];
        }
      }
    }
  }
}

// ---------------- split-K bf16 MFMA GEMM, XCD-grouped 1D grid (ffn2) ----------------
__global__ __launch_bounds__(256) void k_gemm_splitk(const float* __restrict__ A, const float* __restrict__ Wt,
    float* __restrict__ part, int M, int N, int K, int KC, int PX, int MY)
{
  const int wg = blockIdx.x;
  const int xcd = wg & 7, slot = wg >> 3;
  const int mb = slot % MY, pg = slot / MY;
  const int panel = xcd + 8*pg;
  const int PZ = K / KC;
  if(panel >= PX*PZ) return;
  const int px = panel % PX, pz = panel / PX;
  const int n0 = px*128, m0 = mb*64;
  const int kz = pz*KC;
  const int tid = threadIdx.x;
  const int wid = tid >> 6, lane = tid & 63;
  const int col = lane & 15, quad = lane >> 4;
  const int wm = wid & 1, wn = wid >> 1;
  __shared__ __bf16 As[64][72];
  __shared__ __bf16 Bs[128][72];
  f32x4 acc[2][4] = {};
  for(int k0=kz; k0<kz+KC; k0+=64){
    __syncthreads();
    for(int i=tid; i<512; i+=256){
      int r = i >> 3, kg = i & 7;
      int m = m0 + r;
      bf16x8 v;
      if(m < M){
        const float* ap = &A[(size_t)m*K + k0 + kg*8];
        const float4 f0 = *(const float4*)ap;
        const float4 f1 = *(const float4*)(ap+4);
        v[0]=(__bf16)f0.x; v[1]=(__bf16)f0.y; v[2]=(__bf16)f0.z; v[3]=(__bf16)f0.w;
        v[4]=(__bf16)f1.x; v[5]=(__bf16)f1.y; v[6]=(__bf16)f1.z; v[7]=(__bf16)f1.w;
      } else {
        #pragma unroll
        for(int u=0;u<8;u++) v[u] = (__bf16)0.f;
      }
      *(bf16x8*)&As[r][kg*8] = v;
    }
    for(int i=tid; i<1024; i+=256){
      int r = i >> 3, kg = i & 7;
      const float* wp = &Wt[(size_t)(n0 + r)*K + k0 + kg*8];
      const float4 f0 = *(const float4*)wp;
      const float4 f1 = *(const float4*)(wp+4);
      bf16x8 v;
      v[0]=(__bf16)f0.x; v[1]=(__bf16)f0.y; v[2]=(__bf16)f0.z; v[3]=(__bf16)f0.w;
      v[4]=(__bf16)f1.x; v[5]=(__bf16)f1.y; v[6]=(__bf16)f1.z; v[7]=(__bf16)f1.w;
      *(bf16x8*)&Bs[r][kg*8] = v;
    }
    __syncthreads();
    #pragma unroll
    for(int ks=0; ks<2; ks++){
      bf16x8 b[4], a[2];
      #pragma unroll
      for(int t=0;t<4;t++) b[t] = *(const bf16x8*)&Bs[(wn*4+t)*16 + col][ks*32 + quad*8];
      #pragma unroll
      for(int mt=0;mt<2;mt++) a[mt] = *(const bf16x8*)&As[(wm*2+mt)*16 + col][ks*32 + quad*8];
      #pragma unroll
      for(int mt=0;mt<2;mt++)
        #pragma unroll
        for(int t=0;t<4;t++)
          acc[mt][t] = __builtin_amdgcn_mfma_f32_16x16x32_bf16(a[mt], b[t], acc[mt][t], 0, 0, 0);
    }
  }
  float* pbase = part + (size_t)pz*M*N;
  #pragma unroll
  for(int mt=0;mt<2;mt++){
    #pragma unroll
    for(int r=0;r<4;r++){
      int m = m0 + (wm*2+mt)*16 + quad*4 + r;
      if(m < M){
        #pragma unroll
        for(int t=0;t<4;t++){
          int n = n0 + (wn*4+t)*16 + col;
          pbase[(size_t)m*N + n] = acc[mt][t][r];
        }
      }
    }
  }
}

// ---------------- split-K reduce: out = sum_z part[z] + bias ----------------
__global__ __launch_bounds__(256) void k_redk(const float* __restrict__ part, const float* __restrict__ bias,
    float* __restrict__ out, int M, int N, int S)
{
  size_t i4 = ((size_t)blockIdx.x*256 + threadIdx.x)*4;
  size_t MN = (size_t)M*N;
  if(i4 >= MN) return;
  float4 s = *(const float4*)&part[i4];
  for(int z=1; z<S; z++){
    const float4 p = *(const float4*)&part[(size_t)z*MN + i4];
    s.x+=p.x; s.y+=p.y; s.z+=p.z; s.w+=p.w;
  }
  if(bias){
    int n = (int)(i4 % (size_t)N);
    const float4 b = *(const float4*)&bias[n];
    s.x+=b.x; s.y+=b.y; s.z+=b.z; s.w+=b.w;
  }
  *(float4*)&out[i4] = s;
}

// ---------------- row LayerNorm over C=256 (+residual, +act) ----------------
__global__ __launch_bounds__(256) void k_ln256(const float* __restrict__ in, const float* __restrict__ res,
    const float* __restrict__ g, const float* __restrict__ b, float* __restrict__ out, int M, int act)
{
  int row = blockIdx.x*4 + (threadIdx.x >> 6);
  int lane = threadIdx.x & 63;
  if(row >= M) return;
  float4 v = *(const float4*)&in[(size_t)row*C_ + lane*4];
  if(res){
    const float4 rv = *(const float4*)&res[(size_t)row*C_ + lane*4];
    v.x += rv.x; v.y += rv.y; v.z += rv.z; v.w += rv.w;
  }
  float s = v.x + v.y + v.z + v.w;
  float q = v.x*v.x + v.y*v.y + v.z*v.z + v.w*v.w;
  #pragma unroll
  for(int off=32; off; off>>=1){ s += __shfl_xor(s, off, 64); q += __shfl_xor(q, off, 64); }
  float mean = s*(1.f/256.f);
  float rstd = rsqrtf(q*(1.f/256.f) - mean*mean + 1e-5f);
  const float4 gv = *(const float4*)&g[lane*4];
  const float4 bv = *(const float4*)&b[lane*4];
  float o[4] = {(v.x-mean)*rstd*gv.x + bv.x, (v.y-mean)*rstd*gv.y + bv.y,
                (v.z-mean)*rstd*gv.z + bv.z, (v.w-mean)*rstd*gv.w + bv.w};
  #pragma unroll
  for(int j=0;j<4;j++){
    if(act==1) o[j] = fmaxf(o[j], 0.f);
    else if(act==2) o[j] = 1.f/(1.f + __expf(-o[j]));
  }
  float4 ov = {o[0],o[1],o[2],o[3]};
  *(float4*)&out[(size_t)row*C_ + lane*4] = ov;
}

// ---------------- gate = i_in * p_in ----------------
__global__ __launch_bounds__(256) void k_gate(const float* __restrict__ inp, const float* __restrict__ params,
                                              float* __restrict__ gate){
  int i = blockIdx.x*256 + threadIdx.x;
  if(i >= ROWS_*C_) return;
  int c = i & 255, r = i >> 8;
  int np = r / 9;
  gate[i] = inp[(size_t)r*512 + c] * params[(size_t)np*512 + c];
}

// ---------------- block LN helper ----------------
__device__ __forceinline__ void block_stats(float v, float* red, int slot, float& mean, float& rstd){
  float s = v, q = v*v;
  #pragma unroll
  for(int off=32; off; off>>=1){ s += __shfl_xor(s, off, 64); q += __shfl_xor(q, off, 64); }
  int wid = threadIdx.x >> 6;
  if((threadIdx.x & 63) == 0){ red[slot + wid] = s; red[slot + 4 + wid] = q; }
  __syncthreads();
  s = red[slot+0]+red[slot+1]+red[slot+2]+red[slot+3];
  q = red[slot+4]+red[slot+5]+red[slot+6]+red[slot+7];
  mean = s*(1.f/256.f);
  rstd = rsqrtf(q*(1.f/256.f) - mean*mean + 1e-5f);
}

// ---------------- feat = ug * LN(p_out) + ig * LN(i_out) ----------------
__global__ __launch_bounds__(256) void k_combine(const float* __restrict__ params, const float* __restrict__ inp,
  const float* __restrict__ ug, const float* __restrict__ ig,
  const float* __restrict__ nout_g, const float* __restrict__ nout_b,
  const float* __restrict__ inout_g, const float* __restrict__ inout_b,
  float* __restrict__ feat)
{
  __shared__ float red[16];
  int r = blockIdx.x;           // np*9+kk
  int np = r / 9;
  int c = threadIdx.x;
  float pv = params[(size_t)np*512 + 256 + c];
  float mean, rstd;
  block_stats(pv, red, 0, mean, rstd);
  float pn = (pv - mean)*rstd*nout_g[c] + nout_b[c];
  float iv = inp[(size_t)r*512 + 256 + c];
  float mean2, rstd2;
  block_stats(iv, red, 8, mean2, rstd2);
  float iw = (iv - mean2)*rstd2*inout_g[c] + inout_b[c];
  size_t o = (size_t)r*C_ + c;
  feat[o] = ug[o]*pn + ig[o]*iw;
}

// ---------------- attention v2 ----------------
__global__ __launch_bounds__(256) void k_attn2(const float* __restrict__ qkv, float* __restrict__ attnO){
  const int qt = blockIdx.x, h = blockIdx.y, n = blockIdx.z;
  const int q0 = qt*10;
  const int tid = threadIdx.x;
  __shared__ float Qs[10][292];
  __shared__ float KVs[25][292];
  __shared__ float Ss[10][104];
  const float scale = 0.05892556509887896f;   // 1/sqrt(288)
  const size_t base = (size_t)n*P_*6912 + (size_t)h*DH_;
  for(int i=tid; i<10*DH_; i+=256){
    int qi = i/DH_, d = i - qi*DH_;
    Qs[qi][d] = qkv[base + (size_t)(q0+qi)*6912 + d] * scale;
  }
  for(int kt=0; kt<4; kt++){
    int kp0 = kt*25;
    __syncthreads();
    for(int i=tid; i<25*DH_; i+=256){
      int ki = i/DH_, d = i - ki*DH_;
      KVs[ki][d] = qkv[base + (size_t)(kp0+ki)*6912 + E_ + d];
    }
    __syncthreads();
    if(tid < 250){
      int qi = tid/25, ki = tid - qi*25;
      float s = 0.f;
      #pragma unroll 9
      for(int d=0; d<DH_; d+=4){
        const float4 a = *(const float4*)&Qs[qi][d];
        const float4 b = *(const float4*)&KVs[ki][d];
        s += a.x*b.x + a.y*b.y + a.z*b.z + a.w*b.w;
      }
      Ss[qi][kp0+ki] = s;
    }
  }
  __syncthreads();
  {
    int w = tid >> 6, lane = tid & 63;
    for(int r=w; r<10; r+=4){
      float v0 = (lane < 100) ? Ss[r][lane] : -1e30f;
      float v1 = (lane < 36)  ? Ss[r][64+lane] : -1e30f;
      float m = fmaxf(v0, v1);
      #pragma unroll
      for(int off=32; off; off>>=1) m = fmaxf(m, __shfl_xor(m, off, 64));
      float e0 = (lane < 100) ? __expf(v0-m) : 0.f;
      float e1 = (lane < 36)  ? __expf(v1-m) : 0.f;
      float s = e0 + e1;
      #pragma unroll
      for(int off=32; off; off>>=1) s += __shfl_xor(s, off, 64);
      float inv = 1.f/s;
      if(lane < 100) Ss[r][lane] = e0*inv;
      if(lane < 36)  Ss[r][64+lane] = e1*inv;
    }
  }
  float acc[12];
  #pragma unroll
  for(int j=0;j<12;j++) acc[j]=0.f;
  for(int kt=0; kt<4; kt++){
    int kp0 = kt*25;
    __syncthreads();
    for(int i=tid; i<25*DH_; i+=256){
      int ki = i/DH_, d = i - ki*DH_;
      KVs[ki][d] = qkv[base + (size_t)(kp0+ki)*6912 + 2*E_ + d];
    }
    __syncthreads();
    int j = 0;
    for(int i=tid; i<10*DH_; i+=256, j++){
      int qi = i/DH_, d = i - qi*DH_;
      float s = acc[j];
      #pragma unroll
      for(int ki=0; ki<25; ki++) s += Ss[qi][kp0+ki]*KVs[ki][d];
      acc[j] = s;
    }
  }
  {
    int j = 0;
    for(int i=tid; i<10*DH_; i+=256, j++){
      int qi = i/DH_, d = i - qi*DH_;
      attnO[(size_t)(n*P_ + q0 + qi)*E_ + h*DH_ + d] = acc[j];
    }
  }
}

// ---------------- obj1 = LN(obj0 + tproj) over E=2304 ----------------
__global__ __launch_bounds__(256) void k_add_ln2304(const float* __restrict__ obj0, const float* __restrict__ tp,
  const float* __restrict__ g, const float* __restrict__ b, float* __restrict__ out)
{
  __shared__ float red[8];
  int row = blockIdx.x;
  float v[9]; float s=0.f, q=0.f;
  #pragma unroll
  for(int j=0;j<9;j++){
    int e = threadIdx.x + j*256;
    float t = obj0[(size_t)row*E_ + e] + tp[(size_t)row*E_ + e];
    v[j]=t; s+=t; q+=t*t;
  }
  #pragma unroll
  for(int off=32; off; off>>=1){ s += __shfl_xor(s, off, 64); q += __shfl_xor(q, off, 64); }
  int wid = threadIdx.x>>6;
  if((threadIdx.x&63)==0){ red[wid]=s; red[4+wid]=q; }
  __syncthreads();
  s = red[0]+red[1]+red[2]+red[3]; q = red[4]+red[5]+red[6]+red[7];
  float mean = s*(1.f/2304.f);
  float rstd = rsqrtf(q*(1.f/2304.f) - mean*mean + 1e-5f);
  #pragma unroll
  for(int j=0;j<9;j++){
    int e = threadIdx.x + j*256;
    out[(size_t)row*E_ + e] = (v[j]-mean)*rstd*g[e] + b[e];
  }
}

// ---------------- obj_kernels output transpose ----------------
__global__ __launch_bounds__(256) void k_objk(const float* __restrict__ obj2, float* __restrict__ outk){
  int i = blockIdx.x*256 + threadIdx.x;
  if(i >= ROWS_*C_) return;
  int kk = i % 9; int t = i / 9; int c = t & 255; int np = t >> 8;
  outk[i] = obj2[((size_t)np*9 + kk)*C_ + c];
}

// ---------------- x pre-transpose to bf16: xT[n][c/8][h][w][8] ----------------
__global__ __launch_bounds__(256) void k_prep_x(const float* __restrict__ x, __bf16* __restrict__ xT){
  int i = blockIdx.x*256 + threadIdx.x;     // (n, g, h, w) flattened
  if(i >= N_*32*H_*W_) return;
  int w = i % W_; int t = i / W_;
  int h = t % H_; t /= H_;
  int g = t % 32; int n = t / 32;
  const float* xp = &x[((size_t)(n*C_ + g*8)*H_ + h)*W_ + w];
  bf16x8 v;
  #pragma unroll
  for(int u=0;u<8;u++) v[u] = (__bf16)xp[(size_t)u*HW_];
  *(bf16x8*)&xT[(size_t)i*8] = v;
}

// ---------------- kernel permute: kerP[nps][c0b][tap][oct][pl][8] from mfF(bf16) ----------------
__global__ __launch_bounds__(256) void k_permute_ker(const __bf16* __restrict__ mfFb, __bf16* __restrict__ kerP){
  int i = blockIdx.x*256 + threadIdx.x;   // bf16x8 index
  if(i >= 73728) return;                  // 4 nps * 8 c0b * 9 tap * 4 oct * 64 pl
  int pl = i & 63; int t = i >> 6;
  int oct = t & 3; t >>= 2;
  int tap = t % 9; t /= 9;
  int c0b = t & 7; int nps = t >> 3;
  int n = nps >> 1, ps = nps & 1;
  int p = ps*64 + pl;
  bf16x8 v;
  if(p < P_){
    v = *(const bf16x8*)&mfFb[((size_t)(n*P_+p)*9 + tap)*C_ + c0b*32 + oct*8];
  } else {
    #pragma unroll
    for(int u=0;u<8;u++) v[u] = (__bf16)0.f;
  }
  *(bf16x8*)&kerP[(size_t)i*8] = v;
}

// ---------------- dynamic conv via implicit-GEMM bf16 MFMA ----------------
// 64-wide w tiles, kerP pre-permuted: ks staging is a linear coalesced copy.
__global__ __launch_bounds__(256) void k_conv_mfma(const __bf16* __restrict__ xT, const __bf16* __restrict__ kerP,
                                                   float* __restrict__ out){
  const int wt = blockIdx.x, ht = blockIdx.y, z = blockIdx.z;
  const int n = z >> 1, ps = z & 1;
  const int pbase = ps*64;
  const int NT = ps ? 3 : 4;
  const int tid = threadIdx.x;
  const int hi = tid >> 6;
  const int lane = tid & 63;
  const int col = lane & 15, quad = lane >> 4;
  const int w0 = wt*64, h0 = ht*4;

  __shared__ __bf16 xs[6][4][66][8];
  __shared__ __bf16 ks[9][4][64][8];
  __bf16* ksf = &ks[0][0][0][0];

  f32x4 acc[4][4] = {};

  for(int c0=0; c0<C_; c0+=32){
    __syncthreads();
    for(int i=tid; i<1584; i+=256){
      int oct = i / 396;
      int rem = i - oct*396;
      int hy = rem / 66, wx = rem - hy*66;
      int hh = h0 - 1 + hy, ww = w0 - 1 + wx;
      bf16x8 v;
      if(hh >= 0 && hh < H_ && ww >= 0 && ww < W_){
        v = *(const bf16x8*)&xT[((((size_t)n*32 + (c0>>3) + oct)*H_ + hh)*W_ + ww)*8];
      } else {
        #pragma unroll
        for(int u=0;u<8;u++) v[u] = (__bf16)0.f;
      }
      *(bf16x8*)&xs[hy][oct][wx][0] = v;
    }
    {
      const __bf16* kp = kerP + ((size_t)(n*2+ps)*8 + (c0>>5))*2304*8;
      for(int i=tid; i<2304; i+=256)
        *(bf16x8*)&ksf[(size_t)i*8] = *(const bf16x8*)&kp[(size_t)i*8];
    }
    __syncthreads();
    #pragma unroll
    for(int ky=0; ky<3; ky++){
      #pragma unroll
      for(int kx=0; kx<3; kx++){
        const int tap = ky*3 + kx;
        const int hy = hi + ky;
        bf16x8 b[4];
        #pragma unroll
        for(int t=0;t<4;t++) b[t] = *(const bf16x8*)&xs[hy][quad][t*16 + col + kx][0];
        #pragma unroll
        for(int pt=0; pt<4; pt++){
          if(pt < NT){
            bf16x8 a = *(const bf16x8*)&ks[tap][quad][pt*16 + col][0];
            #pragma unroll
            for(int t=0;t<4;t++)
              acc[pt][t] = __builtin_amdgcn_mfma_f32_16x16x32_bf16(a, b[t], acc[pt][t], 0, 0, 0);
          }
        }
      }
    }
  }
  const int h = h0 + hi;
  #pragma unroll
  for(int pt=0; pt<4; pt++){
    if(pt < NT){
      #pragma unroll
      for(int r=0;r<4;r++){
        int p = pbase + pt*16 + quad*4 + r;
        if(p < P_){
          float* op = &out[((size_t)(n*P_+p)*H_ + h)*W_ + w0 + col];
          #pragma unroll
          for(int t=0;t<4;t++) op[t*16] = acc[pt][t][r];
        }
      }
    }
  }
}

extern "C" void kernel_launch(void* const* d_in, const int* in_sizes, int n_in,
                              void* d_out, int out_size, void* d_ws, size_t ws_size,
                              hipStream_t stream)
{
  (void)in_sizes; (void)n_in; (void)out_size; (void)ws_size;
  const float* x          = (const float*)d_in[0];
  const float* prop       = (const float*)d_in[1];
  const float* mask_pred  = (const float*)d_in[2];
  const float* ku_dyn_w   = (const float*)d_in[3];
  const float* ku_dyn_b   = (const float*)d_in[4];
  const float* ku_in_w    = (const float*)d_in[5];
  const float* ku_in_b    = (const float*)d_in[6];
  const float* ku_ig_w    = (const float*)d_in[7];
  const float* ku_ig_b    = (const float*)d_in[8];
  const float* ku_ug_w    = (const float*)d_in[9];
  const float* ku_ug_b    = (const float*)d_in[10];
  const float* ku_nin_g   = (const float*)d_in[11];
  const float* ku_nin_b   = (const float*)d_in[12];
  const float* ku_nout_g  = (const float*)d_in[13];
  const float* ku_nout_b  = (const float*)d_in[14];
  const float* ku_inin_g  = (const float*)d_in[15];
  const float* ku_inin_b  = (const float*)d_in[16];
  const float* ku_inout_g = (const float*)d_in[17];
  const float* ku_inout_b = (const float*)d_in[18];
  const float* ku_fc_w    = (const float*)d_in[19];
  const float* ku_fc_b    = (const float*)d_in[20];
  const float* ku_fcn_g   = (const float*)d_in[21];
  const float* ku_fcn_b   = (const float*)d_in[22];
  const float* attn_in_w  = (const float*)d_in[23];
  const float* attn_in_b  = (const float*)d_in[24];
  const float* attn_out_w = (const float*)d_in[25];
  const float* attn_out_b = (const float*)d_in[26];
  const float* attn_ln_g  = (const float*)d_in[27];
  const float* attn_ln_b  = (const float*)d_in[28];
  const float* ffn_w1     = (const float*)d_in[29];
  const float* ffn_b1     = (const float*)d_in[30];
  const float* ffn_w2     = (const float*)d_in[31];
  const float* ffn_b2     = (const float*)d_in[32];
  const float* ffn_ln_g   = (const float*)d_in[33];
  const float* ffn_ln_b   = (const float*)d_in[34];
  const float* mask_fc_ws = (const float*)d_in[35];
  const float* mask_fc_ln_g = (const float*)d_in[36];
  const float* mask_fc_ln_b = (const float*)d_in[37];
  const float* fc_mask_w  = (const float*)d_in[38];
  const float* fc_mask_b  = (const float*)d_in[39];

  float* ws = (float*)d_ws;
  float* sig     = ws;
  float* hbuf    = ws;
  float* skA     = ws;                // split-K scratch: attn_in S=6 needs 8.29M floats [0..8294400)
  float* partial = ws + 4915200;      // dead after k_xfeat2
  float* skB     = ws + 4915200;      // split-K scratch (ffn2)
  float* attnO   = ws + 4915200 + 1382400;
  float* tproj   = ws + 4915200 + 1843200;
  float* tmp     = ws + 4915200 + 2304000;  // pre-LN gemm output (1800x256)
  // qkv relocated to [8294400..9676800) so attn_in's 6 partial slabs fit below it.
  float* qkv     = ws + 8294400;
  float* xfeat   = ws + 9830400;
  float* params  = xfeat + 51200;
  float* pf      = params + 102400;
  float* inp     = pf + 460800;
  float* gate    = inp + 921600;
  float* ig      = gate + 460800;
  float* ug      = ig + 460800;
  float* feat    = ug + 460800;
  float* obj0    = feat + 460800;
  float* obj1    = obj0 + 460800;
  float* obj2    = obj1 + 460800;
  float* mf1     = obj2 + 460800;
  float* mf2     = mf1 + 460800;
  float* mfF     = mf2 + 460800;
  // xT (bf16) at ws[0..6291456 float slots): sig/hbuf/skA/skB dead by k_prep_x.
  __bf16* xT = (__bf16*)ws;
  // kerP (bf16, 589824 elems = 294912 float slots) in dead tproj region (cap 460800).
  __bf16* kerP = (__bf16*)(ws + 6758400);

  float* out_masks = (float*)d_out;
  float* out_kern  = out_masks + (size_t)N_*P_*HW_;

  k_softmax<<<192, 256, 0, stream>>>(mask_pred, sig);
  k_permute_pf<<<1800, 256, 0, stream>>>(prop, pf);
  k_xfeat1m<<<dim3(2,XKC_,2), 256, 0, stream>>>(sig, x, partial);
  k_xfeat2<<<200, 256, 0, stream>>>(partial, xfeat);
  k_gemm_mfma<<<dim3(4,4),   256, 0, stream>>>(xfeat, ku_dyn_w, ku_dyn_b, params, 200, 512, 256, 0);
  k_gemm_mfma<<<dim3(4,29),  256, 0, stream>>>(pf, ku_in_w, ku_in_b, inp, 1800, 512, 256, 0);
  k_gate<<<1800, 256, 0, stream>>>(inp, params, gate);
  k_gemm_mfma<<<dim3(2,29),  256, 0, stream>>>(gate, ku_ig_w, ku_ig_b, tmp, 1800, 256, 256, 0);
  k_ln256<<<450, 256, 0, stream>>>(tmp, nullptr, ku_inin_g, ku_inin_b, ig, 1800, 2);
  k_gemm_mfma<<<dim3(2,29),  256, 0, stream>>>(gate, ku_ug_w, ku_ug_b, tmp, 1800, 256, 256, 0);
  k_ln256<<<450, 256, 0, stream>>>(tmp, nullptr, ku_nin_g, ku_nin_b, ug, 1800, 2);
  k_combine<<<1800, 256, 0, stream>>>(params, inp, ug, ig, ku_nout_g, ku_nout_b, ku_inout_g, ku_inout_b, feat);
  k_gemm_mfma<<<dim3(2,29),  256, 0, stream>>>(feat, ku_fc_w, ku_fc_b, tmp, 1800, 256, 256, 0);
  k_ln256<<<450, 256, 0, stream>>>(tmp, nullptr, ku_fcn_g, ku_fcn_b, obj0, 1800, 1);
  // attn_in: BM=256/BN=64, split-K x6 (KC=384): 648 blocks, weight read by exactly one block
  k_gemm_skM256<<<dim3(108,6), 256, 0, stream>>>(obj0, attn_in_w, skA, 200, 6912, 2304, 384);
  k_redk<<<1350, 256, 0, stream>>>(skA, attn_in_b, qkv, 200, 6912, 6);
  k_attn2<<<dim3(10,8,2), 256, 0, stream>>>(qkv, attnO);
  // attn_out: BM=256/BN=64, split-K x9 (KC=256): 324 blocks
  k_gemm_skM256<<<dim3(36,9), 256, 0, stream>>>(attnO, attn_out_w, skA, 200, 2304, 2304, 256);
  k_redk<<<450, 256, 0, stream>>>(skA, attn_out_b, tproj, 200, 2304, 9);
  k_add_ln2304<<<200, 256, 0, stream>>>(obj0, tproj, attn_ln_g, attn_ln_b, obj1);
  k_gemm_mfma<<<dim3(16,29), 256, 0, stream>>>(obj1, ffn_w1, ffn_b1, hbuf, 1800, 2048, 256, 1);
  // ffn2: split-K x4 (K=2048 -> 4x512); scratch in dead region above hbuf
  k_gemm_splitk<<<232, 256, 0, stream>>>(hbuf, ffn_w2, skB, 1800, 256, 2048, 512, 2, 29);
  k_redk<<<450, 256, 0, stream>>>(skB, ffn_b2, tmp, 1800, 256, 4);
  k_ln256<<<450, 256, 0, stream>>>(tmp, obj1, ffn_ln_g, ffn_ln_b, obj2, 1800, 0);
  k_gemm_mfma<<<dim3(2,29),  256, 0, stream>>>(obj2, mask_fc_ws,          nullptr, tmp, 1800, 256, 256, 0);
  k_ln256<<<450, 256, 0, stream>>>(tmp, nullptr, mask_fc_ln_g,       mask_fc_ln_b,       mf1, 1800, 1);
  k_gemm_mfma<<<dim3(2,29),  256, 0, stream>>>(mf1,  mask_fc_ws + 65536,  nullptr, tmp, 1800, 256, 256, 0);
  k_ln256<<<450, 256, 0, stream>>>(tmp, nullptr, mask_fc_ln_g + 256, mask_fc_ln_b + 256, mf2, 1800, 1);
  k_gemm_mfma<<<dim3(2,29),  256, 0, stream>>>(mf2,  mask_fc_ws + 131072, nullptr, tmp, 1800, 256, 256, 0);
  k_ln256<<<450, 256, 0, stream>>>(tmp, nullptr, mask_fc_ln_g + 512, mask_fc_ln_b + 512, mf1, 1800, 1);
  // final kernel GEMM stores bf16 directly (identical numerics: same RNE convert)
  k_gemm_mfma<<<dim3(2,29),  256, 0, stream>>>(mf1, fc_mask_w, fc_mask_b, mfF, 1800, 256, 256, 3);
  k_objk<<<1800, 256, 0, stream>>>(obj2, out_kern);
  k_permute_ker<<<288, 256, 0, stream>>>((const __bf16*)mfF, kerP);
  k_prep_x<<<6144, 256, 0, stream>>>(x, xT);
  k_conv_mfma<<<dim3(3,32,4), 256, 0, stream>>>(xT, kerP, out_masks);
}

// Round 7
// 716.995 us; speedup vs baseline: 1.0645x; 1.0075x over previous
//
#include <hip/hip_runtime.h>
#include <hip/hip_bf16.h>

#define N_ 2
#define P_ 100
#define C_ 256
#define H_ 128
#define W_ 192
#define HW_ 24576
#define KK_ 9
#define E_ 2304
#define NH_ 8
#define DH_ 288
#define FFN_ 2048
#define NP_ 200
#define ROWS_ 1800   // NP_*KK_
#define XKC_ 64      // xfeat split-K chunks

typedef __attribute__((ext_vector_type(8))) __bf16 bf16x8;
typedef __attribute__((ext_vector_type(4))) float f32x4;

// ---------------- softmax over P axis of mask_preds ----------------
__global__ __launch_bounds__(256) void k_softmax(const float* __restrict__ mp, float* __restrict__ sig){
  int idx = blockIdx.x*256 + threadIdx.x;
  if(idx >= N_*HW_) return;
  int n = idx / HW_, hw = idx - n*HW_;
  const float* base = mp + (size_t)n*P_*HW_ + hw;
  float m = -1e30f;
  for(int p=0;p<P_;p++) m = fmaxf(m, base[(size_t)p*HW_]);
  float s = 0.f;
  for(int p=0;p<P_;p++) s += __expf(base[(size_t)p*HW_] - m);
  float inv = 1.f/s;
  float* ob = sig + (size_t)n*P_*HW_ + hw;
  for(int p=0;p<P_;p++) ob[(size_t)p*HW_] = __expf(base[(size_t)p*HW_] - m)*inv;
}

// ---------------- pf permute: pf[np][kk][c] = prop[n][p][c*9+kk] ----------------
__global__ __launch_bounds__(256) void k_permute_pf(const float* __restrict__ prop, float* __restrict__ pf){
  int i = blockIdx.x*256 + threadIdx.x;
  if(i >= ROWS_*C_) return;
  int c = i & 255;
  int r = i >> 8;            // np*9+kk
  int kk = r % 9, np = r / 9;
  pf[i] = prop[(size_t)np*E_ + c*KK_ + kk];
}

// ---------------- x_feat stage 1: bf16 MFMA split-K ----------------
__global__ __launch_bounds__(256) void k_xfeat1m(const float* __restrict__ sig, const float* __restrict__ x,
                                                 float* __restrict__ partial){
  const int ct = blockIdx.x, kb = blockIdx.y, n = blockIdx.z;
  const int hw0 = kb*384;
  const int tid = threadIdx.x;
  const int wid = tid >> 6, lane = tid & 63;
  const int col = lane & 15, quad = lane >> 4;
  const int wm = wid & 1, wn = wid >> 1;
  const int MT = wm ? 3 : 4;
  __shared__ __bf16 As[112][72];
  __shared__ __bf16 Bs[128][72];
  f32x4 acc[4][4] = {};
  for(int k0=0; k0<384; k0+=64){
    __syncthreads();
    for(int i=tid; i<896; i+=256){
      int p = i >> 3, kg = i & 7;
      bf16x8 v;
      if(p < P_){
        const float* sp = &sig[((size_t)n*P_ + p)*HW_ + hw0 + k0 + kg*8];
        const float4 f0 = *(const float4*)sp;
        const float4 f1 = *(const float4*)(sp+4);
        v[0]=(__bf16)f0.x; v[1]=(__bf16)f0.y; v[2]=(__bf16)f0.z; v[3]=(__bf16)f0.w;
        v[4]=(__bf16)f1.x; v[5]=(__bf16)f1.y; v[6]=(__bf16)f1.z; v[7]=(__bf16)f1.w;
      } else {
        #pragma unroll
        for(int u=0;u<8;u++) v[u] = (__bf16)0.f;
      }
      *(bf16x8*)&As[p][kg*8] = v;
    }
    for(int i=tid; i<1024; i+=256){
      int c = i >> 3, kg = i & 7;
      const float* xp = &x[((size_t)n*C_ + ct*128 + c)*HW_ + hw0 + k0 + kg*8];
      const float4 f0 = *(const float4*)xp;
      const float4 f1 = *(const float4*)(xp+4);
      bf16x8 v;
      v[0]=(__bf16)f0.x; v[1]=(__bf16)f0.y; v[2]=(__bf16)f0.z; v[3]=(__bf16)f0.w;
      v[4]=(__bf16)f1.x; v[5]=(__bf16)f1.y; v[6]=(__bf16)f1.z; v[7]=(__bf16)f1.w;
      *(bf16x8*)&Bs[c][kg*8] = v;
    }
    __syncthreads();
    #pragma unroll
    for(int ks=0; ks<2; ks++){
      bf16x8 b[4];
      #pragma unroll
      for(int t=0;t<4;t++) b[t] = *(const bf16x8*)&Bs[(wn*4+t)*16 + col][ks*32 + quad*8];
      #pragma unroll
      for(int mt=0; mt<4; mt++){
        if(mt < MT){
          bf16x8 a = *(const bf16x8*)&As[(wm*4+mt)*16 + col][ks*32 + quad*8];
          #pragma unroll
          for(int t=0;t<4;t++)
            acc[mt][t] = __builtin_amdgcn_mfma_f32_16x16x32_bf16(a, b[t], acc[mt][t], 0, 0, 0);
        }
      }
    }
  }
  #pragma unroll
  for(int mt=0; mt<4; mt++){
    if(mt < MT){
      #pragma unroll
      for(int r=0;r<4;r++){
        int p = (wm*4+mt)*16 + quad*4 + r;
        if(p < P_){
          float* op = &partial[(((size_t)n*XKC_ + kb)*P_ + p)*C_ + ct*128 + wn*64 + col];
          #pragma unroll
          for(int t=0;t<4;t++) op[t*16] = acc[mt][t][r];
        }
      }
    }
  }
}

// ---------------- x_feat stage 2: reduce over XKC_ chunks ----------------
__global__ __launch_bounds__(256) void k_xfeat2(const float* __restrict__ partial, float* __restrict__ xfeat){
  int np = blockIdx.x;
  int n = np / P_, p = np - n*P_;
  int c = threadIdx.x;
  float s = 0.f;
  for(int kb=0;kb<XKC_;kb++) s += partial[(((size_t)n*XKC_ + kb)*P_ + p)*C_ + c];
  xfeat[(size_t)np*C_ + c] = s;
}

// ---------------- generic bf16 MFMA GEMM: out = act(A @ W^T + bias) ----------------
// BM=64, BN=128, BK=64. act: 0 none, 1 relu, 3 store-bf16.
__global__ __launch_bounds__(256) void k_gemm_mfma(const float* __restrict__ A, const float* __restrict__ Wt,
    const float* __restrict__ bias, float* __restrict__ out, int M, int N, int K, int act)
{
  const int n0 = blockIdx.x*128, m0 = blockIdx.y*64;
  const int tid = threadIdx.x;
  const int wid = tid >> 6, lane = tid & 63;
  const int col = lane & 15, quad = lane >> 4;
  const int wm = wid & 1, wn = wid >> 1;
  __shared__ __bf16 As[64][72];
  __shared__ __bf16 Bs[128][72];
  f32x4 acc[2][4] = {};
  for(int k0=0; k0<K; k0+=64){
    __syncthreads();
    for(int i=tid; i<512; i+=256){
      int r = i >> 3, kg = i & 7;
      int m = m0 + r;
      bf16x8 v;
      if(m < M){
        const float* ap = &A[(size_t)m*K + k0 + kg*8];
        const float4 f0 = *(const float4*)ap;
        const float4 f1 = *(const float4*)(ap+4);
        v[0]=(__bf16)f0.x; v[1]=(__bf16)f0.y; v[2]=(__bf16)f0.z; v[3]=(__bf16)f0.w;
        v[4]=(__bf16)f1.x; v[5]=(__bf16)f1.y; v[6]=(__bf16)f1.z; v[7]=(__bf16)f1.w;
      } else {
        #pragma unroll
        for(int u=0;u<8;u++) v[u] = (__bf16)0.f;
      }
      *(bf16x8*)&As[r][kg*8] = v;
    }
    for(int i=tid; i<1024; i+=256){
      int r = i >> 3, kg = i & 7;
      const float* wp = &Wt[(size_t)(n0 + r)*K + k0 + kg*8];
      const float4 f0 = *(const float4*)wp;
      const float4 f1 = *(const float4*)(wp+4);
      bf16x8 v;
      v[0]=(__bf16)f0.x; v[1]=(__bf16)f0.y; v[2]=(__bf16)f0.z; v[3]=(__bf16)f0.w;
      v[4]=(__bf16)f1.x; v[5]=(__bf16)f1.y; v[6]=(__bf16)f1.z; v[7]=(__bf16)f1.w;
      *(bf16x8*)&Bs[r][kg*8] = v;
    }
    __syncthreads();
    #pragma unroll
    for(int ks=0; ks<2; ks++){
      bf16x8 b[4], a[2];
      #pragma unroll
      for(int t=0;t<4;t++) b[t] = *(const bf16x8*)&Bs[(wn*4+t)*16 + col][ks*32 + quad*8];
      #pragma unroll
      for(int mt=0;mt<2;mt++) a[mt] = *(const bf16x8*)&As[(wm*2+mt)*16 + col][ks*32 + quad*8];
      #pragma unroll
      for(int mt=0;mt<2;mt++)
        #pragma unroll
        for(int t=0;t<4;t++)
          acc[mt][t] = __builtin_amdgcn_mfma_f32_16x16x32_bf16(a[mt], b[t], acc[mt][t], 0, 0, 0);
    }
  }
  #pragma unroll
  for(int mt=0;mt<2;mt++){
    #pragma unroll
    for(int r=0;r<4;r++){
      int m = m0 + (wm*2+mt)*16 + quad*4 + r;
      if(m < M){
        #pragma unroll
        for(int t=0;t<4;t++){
          int n = n0 + (wn*4+t)*16 + col;
          float v = acc[mt][t][r];
          if(bias) v += bias[n];
          if(act == 1) v = fmaxf(v, 0.f);
          if(act == 3) ((__bf16*)out)[(size_t)m*N + n] = (__bf16)v;
          else out[(size_t)m*N + n] = v;
        }
      }
    }
  }
}

// ---------------- full-M split-K GEMM: BM=256 x BN=64 ----------------
// Weight element -> exactly one block (no cross-XCD weight duplication) while
// BN=64 + deep split-K keeps >600 blocks (R5 lesson: dedup w/o parallelism loses).
__global__ __launch_bounds__(256) void k_gemm_skM256(const float* __restrict__ A, const float* __restrict__ Wt,
    float* __restrict__ part, int M, int N, int K, int KC)
{
  const int n0 = blockIdx.x*64;
  const int kz = blockIdx.y*KC;
  const int tid = threadIdx.x;
  const int wid = tid >> 6, lane = tid & 63;
  const int col = lane & 15, quad = lane >> 4;
  const int wm = wid & 1, wn = wid >> 1;   // wave tile: 128m x 32n
  __shared__ __bf16 As[256][72];
  __shared__ __bf16 Bs[64][72];
  f32x4 acc[8][2] = {};
  for(int k0=kz; k0<kz+KC; k0+=64){
    __syncthreads();
    for(int i=tid; i<2048; i+=256){
      int r = i >> 3, kg = i & 7;
      bf16x8 v;
      if(r < M){
        const float* ap = &A[(size_t)r*K + k0 + kg*8];
        const float4 f0 = *(const float4*)ap;
        const float4 f1 = *(const float4*)(ap+4);
        v[0]=(__bf16)f0.x; v[1]=(__bf16)f0.y; v[2]=(__bf16)f0.z; v[3]=(__bf16)f0.w;
        v[4]=(__bf16)f1.x; v[5]=(__bf16)f1.y; v[6]=(__bf16)f1.z; v[7]=(__bf16)f1.w;
      } else {
        #pragma unroll
        for(int u=0;u<8;u++) v[u] = (__bf16)0.f;
      }
      *(bf16x8*)&As[r][kg*8] = v;
    }
    for(int i=tid; i<512; i+=256){
      int r = i >> 3, kg = i & 7;
      const float* wp = &Wt[(size_t)(n0 + r)*K + k0 + kg*8];
      const float4 f0 = *(const float4*)wp;
      const float4 f1 = *(const float4*)(wp+4);
      bf16x8 v;
      v[0]=(__bf16)f0.x; v[1]=(__bf16)f0.y; v[2]=(__bf16)f0.z; v[3]=(__bf16)f0.w;
      v[4]=(__bf16)f1.x; v[5]=(__bf16)f1.y; v[6]=(__bf16)f1.z; v[7]=(__bf16)f1.w;
      *(bf16x8*)&Bs[r][kg*8] = v;
    }
    __syncthreads();
    #pragma unroll
    for(int ks=0; ks<2; ks++){
      bf16x8 b[2];
      #pragma unroll
      for(int t=0;t<2;t++) b[t] = *(const bf16x8*)&Bs[(wn*2+t)*16 + col][ks*32 + quad*8];
      #pragma unroll
      for(int mt=0;mt<8;mt++){
        bf16x8 a = *(const bf16x8*)&As[(wm*8+mt)*16 + col][ks*32 + quad*8];
        #pragma unroll
        for(int t=0;t<2;t++)
          acc[mt][t] = __builtin_amdgcn_mfma_f32_16x16x32_bf16(a, b[t], acc[mt][t], 0, 0, 0);
      }
    }
  }
  float* pbase = part + (size_t)blockIdx.y*M*N;
  #pragma unroll
  for(int mt=0;mt<8;mt++){
    #pragma unroll
    for(int r=0;r<4;r++){
      int m = (wm*8+mt)*16 + quad*4 + r;
      if(m < M){
        #pragma unroll
        for(int t=0;t<2;t++){
          int n = n0 + (wn*2+t)*16 + col;
          pbase[(size_t)m*N + n] = acc[mt][t][r];
        }
      }
    }
  }
}

// ---------------- split-K bf16 MFMA GEMM, XCD-grouped 1D grid (ffn2) ----------------
__global__ __launch_bounds__(256) void k_gemm_splitk(const float* __restrict__ A, const float* __restrict__ Wt,
    float* __restrict__ part, int M, int N, int K, int KC, int PX, int MY)
{
  const int wg = blockIdx.x;
  const int xcd = wg & 7, slot = wg >> 3;
  const int mb = slot % MY, pg = slot / MY;
  const int panel = xcd + 8*pg;
  const int PZ = K / KC;
  if(panel >= PX*PZ) return;
  const int px = panel % PX, pz = panel / PX;
  const int n0 = px*128, m0 = mb*64;
  const int kz = pz*KC;
  const int tid = threadIdx.x;
  const int wid = tid >> 6, lane = tid & 63;
  const int col = lane & 15, quad = lane >> 4;
  const int wm = wid & 1, wn = wid >> 1;
  __shared__ __bf16 As[64][72];
  __shared__ __bf16 Bs[128][72];
  f32x4 acc[2][4] = {};
  for(int k0=kz; k0<kz+KC; k0+=64){
    __syncthreads();
    for(int i=tid; i<512; i+=256){
      int r = i >> 3, kg = i & 7;
      int m = m0 + r;
      bf16x8 v;
      if(m < M){
        const float* ap = &A[(size_t)m*K + k0 + kg*8];
        const float4 f0 = *(const float4*)ap;
        const float4 f1 = *(const float4*)(ap+4);
        v[0]=(__bf16)f0.x; v[1]=(__bf16)f0.y; v[2]=(__bf16)f0.z; v[3]=(__bf16)f0.w;
        v[4]=(__bf16)f1.x; v[5]=(__bf16)f1.y; v[6]=(__bf16)f1.z; v[7]=(__bf16)f1.w;
      } else {
        #pragma unroll
        for(int u=0;u<8;u++) v[u] = (__bf16)0.f;
      }
      *(bf16x8*)&As[r][kg*8] = v;
    }
    for(int i=tid; i<1024; i+=256){
      int r = i >> 3, kg = i & 7;
      const float* wp = &Wt[(size_t)(n0 + r)*K + k0 + kg*8];
      const float4 f0 = *(const float4*)wp;
      const float4 f1 = *(const float4*)(wp+4);
      bf16x8 v;
      v[0]=(__bf16)f0.x; v[1]=(__bf16)f0.y; v[2]=(__bf16)f0.z; v[3]=(__bf16)f0.w;
      v[4]=(__bf16)f1.x; v[5]=(__bf16)f1.y; v[6]=(__bf16)f1.z; v[7]=(__bf16)f1.w;
      *(bf16x8*)&Bs[r][kg*8] = v;
    }
    __syncthreads();
    #pragma unroll
    for(int ks=0; ks<2; ks++){
      bf16x8 b[4], a[2];
      #pragma unroll
      for(int t=0;t<4;t++) b[t] = *(const bf16x8*)&Bs[(wn*4+t)*16 + col][ks*32 + quad*8];
      #pragma unroll
      for(int mt=0;mt<2;mt++) a[mt] = *(const bf16x8*)&As[(wm*2+mt)*16 + col][ks*32 + quad*8];
      #pragma unroll
      for(int mt=0;mt<2;mt++)
        #pragma unroll
        for(int t=0;t<4;t++)
          acc[mt][t] = __builtin_amdgcn_mfma_f32_16x16x32_bf16(a[mt], b[t], acc[mt][t], 0, 0, 0);
    }
  }
  float* pbase = part + (size_t)pz*M*N;
  #pragma unroll
  for(int mt=0;mt<2;mt++){
    #pragma unroll
    for(int r=0;r<4;r++){
      int m = m0 + (wm*2+mt)*16 + quad*4 + r;
      if(m < M){
        #pragma unroll
        for(int t=0;t<4;t++){
          int n = n0 + (wn*4+t)*16 + col;
          pbase[(size_t)m*N + n] = acc[mt][t][r];
        }
      }
    }
  }
}

// ---------------- split-K reduce: out = sum_z part[z] + bias ----------------
__global__ __launch_bounds__(256) void k_redk(const float* __restrict__ part, const float* __restrict__ bias,
    float* __restrict__ out, int M, int N, int S)
{
  size_t i4 = ((size_t)blockIdx.x*256 + threadIdx.x)*4;
  size_t MN = (size_t)M*N;
  if(i4 >= MN) return;
  float4 s = *(const float4*)&part[i4];
  for(int z=1; z<S; z++){
    const float4 p = *(const float4*)&part[(size_t)z*MN + i4];
    s.x+=p.x; s.y+=p.y; s.z+=p.z; s.w+=p.w;
  }
  if(bias){
    int n = (int)(i4 % (size_t)N);
    const float4 b = *(const float4*)&bias[n];
    s.x+=b.x; s.y+=b.y; s.z+=b.z; s.w+=b.w;
  }
  *(float4*)&out[i4] = s;
}

// ---------------- row LayerNorm over C=256 (+residual, +act) ----------------
__global__ __launch_bounds__(256) void k_ln256(const float* __restrict__ in, const float* __restrict__ res,
    const float* __restrict__ g, const float* __restrict__ b, float* __restrict__ out, int M, int act)
{
  int row = blockIdx.x*4 + (threadIdx.x >> 6);
  int lane = threadIdx.x & 63;
  if(row >= M) return;
  float4 v = *(const float4*)&in[(size_t)row*C_ + lane*4];
  if(res){
    const float4 rv = *(const float4*)&res[(size_t)row*C_ + lane*4];
    v.x += rv.x; v.y += rv.y; v.z += rv.z; v.w += rv.w;
  }
  float s = v.x + v.y + v.z + v.w;
  float q = v.x*v.x + v.y*v.y + v.z*v.z + v.w*v.w;
  #pragma unroll
  for(int off=32; off; off>>=1){ s += __shfl_xor(s, off, 64); q += __shfl_xor(q, off, 64); }
  float mean = s*(1.f/256.f);
  float rstd = rsqrtf(q*(1.f/256.f) - mean*mean + 1e-5f);
  const float4 gv = *(const float4*)&g[lane*4];
  const float4 bv = *(const float4*)&b[lane*4];
  float o[4] = {(v.x-mean)*rstd*gv.x + bv.x, (v.y-mean)*rstd*gv.y + bv.y,
                (v.z-mean)*rstd*gv.z + bv.z, (v.w-mean)*rstd*gv.w + bv.w};
  #pragma unroll
  for(int j=0;j<4;j++){
    if(act==1) o[j] = fmaxf(o[j], 0.f);
    else if(act==2) o[j] = 1.f/(1.f + __expf(-o[j]));
  }
  float4 ov = {o[0],o[1],o[2],o[3]};
  *(float4*)&out[(size_t)row*C_ + lane*4] = ov;
}

// ---------------- gate = i_in * p_in ----------------
__global__ __launch_bounds__(256) void k_gate(const float* __restrict__ inp, const float* __restrict__ params,
                                              float* __restrict__ gate){
  int i = blockIdx.x*256 + threadIdx.x;
  if(i >= ROWS_*C_) return;
  int c = i & 255, r = i >> 8;
  int np = r / 9;
  gate[i] = inp[(size_t)r*512 + c] * params[(size_t)np*512 + c];
}

// ---------------- block LN helper ----------------
__device__ __forceinline__ void block_stats(float v, float* red, int slot, float& mean, float& rstd){
  float s = v, q = v*v;
  #pragma unroll
  for(int off=32; off; off>>=1){ s += __shfl_xor(s, off, 64); q += __shfl_xor(q, off, 64); }
  int wid = threadIdx.x >> 6;
  if((threadIdx.x & 63) == 0){ red[slot + wid] = s; red[slot + 4 + wid] = q; }
  __syncthreads();
  s = red[slot+0]+red[slot+1]+red[slot+2]+red[slot+3];
  q = red[slot+4]+red[slot+5]+red[slot+6]+red[slot+7];
  mean = s*(1.f/256.f);
  rstd = rsqrtf(q*(1.f/256.f) - mean*mean + 1e-5f);
}

// ---------------- feat = ug * LN(p_out) + ig * LN(i_out) ----------------
__global__ __launch_bounds__(256) void k_combine(const float* __restrict__ params, const float* __restrict__ inp,
  const float* __restrict__ ug, const float* __restrict__ ig,
  const float* __restrict__ nout_g, const float* __restrict__ nout_b,
  const float* __restrict__ inout_g, const float* __restrict__ inout_b,
  float* __restrict__ feat)
{
  __shared__ float red[16];
  int r = blockIdx.x;           // np*9+kk
  int np = r / 9;
  int c = threadIdx.x;
  float pv = params[(size_t)np*512 + 256 + c];
  float mean, rstd;
  block_stats(pv, red, 0, mean, rstd);
  float pn = (pv - mean)*rstd*nout_g[c] + nout_b[c];
  float iv = inp[(size_t)r*512 + 256 + c];
  float mean2, rstd2;
  block_stats(iv, red, 8, mean2, rstd2);
  float iw = (iv - mean2)*rstd2*inout_g[c] + inout_b[c];
  size_t o = (size_t)r*C_ + c;
  feat[o] = ug[o]*pn + ig[o]*iw;
}

// ---------------- attention v2 ----------------
__global__ __launch_bounds__(256) void k_attn2(const float* __restrict__ qkv, float* __restrict__ attnO){
  const int qt = blockIdx.x, h = blockIdx.y, n = blockIdx.z;
  const int q0 = qt*10;
  const int tid = threadIdx.x;
  __shared__ float Qs[10][292];
  __shared__ float KVs[25][292];
  __shared__ float Ss[10][104];
  const float scale = 0.05892556509887896f;   // 1/sqrt(288)
  const size_t base = (size_t)n*P_*6912 + (size_t)h*DH_;
  for(int i=tid; i<10*DH_; i+=256){
    int qi = i/DH_, d = i - qi*DH_;
    Qs[qi][d] = qkv[base + (size_t)(q0+qi)*6912 + d] * scale;
  }
  for(int kt=0; kt<4; kt++){
    int kp0 = kt*25;
    __syncthreads();
    for(int i=tid; i<25*DH_; i+=256){
      int ki = i/DH_, d = i - ki*DH_;
      KVs[ki][d] = qkv[base + (size_t)(kp0+ki)*6912 + E_ + d];
    }
    __syncthreads();
    if(tid < 250){
      int qi = tid/25, ki = tid - qi*25;
      float s = 0.f;
      #pragma unroll 9
      for(int d=0; d<DH_; d+=4){
        const float4 a = *(const float4*)&Qs[qi][d];
        const float4 b = *(const float4*)&KVs[ki][d];
        s += a.x*b.x + a.y*b.y + a.z*b.z + a.w*b.w;
      }
      Ss[qi][kp0+ki] = s;
    }
  }
  __syncthreads();
  {
    int w = tid >> 6, lane = tid & 63;
    for(int r=w; r<10; r+=4){
      float v0 = (lane < 100) ? Ss[r][lane] : -1e30f;
      float v1 = (lane < 36)  ? Ss[r][64+lane] : -1e30f;
      float m = fmaxf(v0, v1);
      #pragma unroll
      for(int off=32; off; off>>=1) m = fmaxf(m, __shfl_xor(m, off, 64));
      float e0 = (lane < 100) ? __expf(v0-m) : 0.f;
      float e1 = (lane < 36)  ? __expf(v1-m) : 0.f;
      float s = e0 + e1;
      #pragma unroll
      for(int off=32; off; off>>=1) s += __shfl_xor(s, off, 64);
      float inv = 1.f/s;
      if(lane < 100) Ss[r][lane] = e0*inv;
      if(lane < 36)  Ss[r][64+lane] = e1*inv;
    }
  }
  float acc[12];
  #pragma unroll
  for(int j=0;j<12;j++) acc[j]=0.f;
  for(int kt=0; kt<4; kt++){
    int kp0 = kt*25;
    __syncthreads();
    for(int i=tid; i<25*DH_; i+=256){
      int ki = i/DH_, d = i - ki*DH_;
      KVs[ki][d] = qkv[base + (size_t)(kp0+ki)*6912 + 2*E_ + d];
    }
    __syncthreads();
    int j = 0;
    for(int i=tid; i<10*DH_; i+=256, j++){
      int qi = i/DH_, d = i - qi*DH_;
      float s = acc[j];
      #pragma unroll
      for(int ki=0; ki<25; ki++) s += Ss[qi][kp0+ki]*KVs[ki][d];
      acc[j] = s;
    }
  }
  {
    int j = 0;
    for(int i=tid; i<10*DH_; i+=256, j++){
      int qi = i/DH_, d = i - qi*DH_;
      attnO[(size_t)(n*P_ + q0 + qi)*E_ + h*DH_ + d] = acc[j];
    }
  }
}

// ---------------- obj1 = LN(obj0 + tproj) over E=2304 ----------------
__global__ __launch_bounds__(256) void k_add_ln2304(const float* __restrict__ obj0, const float* __restrict__ tp,
  const float* __restrict__ g, const float* __restrict__ b, float* __restrict__ out)
{
  __shared__ float red[8];
  int row = blockIdx.x;
  float v[9]; float s=0.f, q=0.f;
  #pragma unroll
  for(int j=0;j<9;j++){
    int e = threadIdx.x + j*256;
    float t = obj0[(size_t)row*E_ + e] + tp[(size_t)row*E_ + e];
    v[j]=t; s+=t; q+=t*t;
  }
  #pragma unroll
  for(int off=32; off; off>>=1){ s += __shfl_xor(s, off, 64); q += __shfl_xor(q, off, 64); }
  int wid = threadIdx.x>>6;
  if((threadIdx.x&63)==0){ red[wid]=s; red[4+wid]=q; }
  __syncthreads();
  s = red[0]+red[1]+red[2]+red[3]; q = red[4]+red[5]+red[6]+red[7];
  float mean = s*(1.f/2304.f);
  float rstd = rsqrtf(q*(1.f/2304.f) - mean*mean + 1e-5f);
  #pragma unroll
  for(int j=0;j<9;j++){
    int e = threadIdx.x + j*256;
    out[(size_t)row*E_ + e] = (v[j]-mean)*rstd*g[e] + b[e];
  }
}

// ---------------- obj_kernels output transpose ----------------
__global__ __launch_bounds__(256) void k_objk(const float* __restrict__ obj2, float* __restrict__ outk){
  int i = blockIdx.x*256 + threadIdx.x;
  if(i >= ROWS_*C_) return;
  int kk = i % 9; int t = i / 9; int c = t & 255; int np = t >> 8;
  outk[i] = obj2[((size_t)np*9 + kk)*C_ + c];
}

// ---------------- x pre-transpose to bf16: xT[n][c/8][h][w][8] ----------------
__global__ __launch_bounds__(256) void k_prep_x(const float* __restrict__ x, __bf16* __restrict__ xT){
  int i = blockIdx.x*256 + threadIdx.x;     // (n, g, h, w) flattened
  if(i >= N_*32*H_*W_) return;
  int w = i % W_; int t = i / W_;
  int h = t % H_; t /= H_;
  int g = t % 32; int n = t / 32;
  const float* xp = &x[((size_t)(n*C_ + g*8)*H_ + h)*W_ + w];
  bf16x8 v;
  #pragma unroll
  for(int u=0;u<8;u++) v[u] = (__bf16)xp[(size_t)u*HW_];
  *(bf16x8*)&xT[(size_t)i*8] = v;
}

// ---------------- kernel permute: kerP[nps][c0b][tap][oct][pl][8] from mfF(bf16) ----------------
__global__ __launch_bounds__(256) void k_permute_ker(const __bf16* __restrict__ mfFb, __bf16* __restrict__ kerP){
  int i = blockIdx.x*256 + threadIdx.x;   // bf16x8 index
  if(i >= 73728) return;                  // 4 nps * 8 c0b * 9 tap * 4 oct * 64 pl
  int pl = i & 63; int t = i >> 6;
  int oct = t & 3; t >>= 2;
  int tap = t % 9; t /= 9;
  int c0b = t & 7; int nps = t >> 3;
  int n = nps >> 1, ps = nps & 1;
  int p = ps*64 + pl;
  bf16x8 v;
  if(p < P_){
    v = *(const bf16x8*)&mfFb[((size_t)(n*P_+p)*9 + tap)*C_ + c0b*32 + oct*8];
  } else {
    #pragma unroll
    for(int u=0;u<8;u++) v[u] = (__bf16)0.f;
  }
  *(bf16x8*)&kerP[(size_t)i*8] = v;
}

// ---------------- dynamic conv via implicit-GEMM bf16 MFMA ----------------
// Register-staged double buffer (T14 async-STAGE split): next c0-step's global
// loads are issued right after the barrier and fly during the MFMA cluster;
// ds_writes happen after the next barrier. Staging addresses precomputed once
// (step offset is linear: x +786432 elems, ker +18432 elems per step).
__global__ __launch_bounds__(256) void k_conv_mfma(const __bf16* __restrict__ xT, const __bf16* __restrict__ kerP,
                                                   float* __restrict__ out){
  const int wt = blockIdx.x, ht = blockIdx.y, z = blockIdx.z;
  const int n = z >> 1, ps = z & 1;
  const int pbase = ps*64;
  const int NT = ps ? 3 : 4;
  const int tid = threadIdx.x;
  const int hi = tid >> 6;
  const int lane = tid & 63;
  const int col = lane & 15, quad = lane >> 4;
  const int w0 = wt*64, h0 = ht*4;

  __shared__ __bf16 xs[6][4][66][8];
  __shared__ __bf16 ks[9][4][64][8];
  __bf16* ksf = &ks[0][0][0][0];

  f32x4 acc[4][4] = {};

  // precompute per-thread staging slots (step-invariant)
  int xoff[7];
  __bf16* xlds[7];
  #pragma unroll
  for(int j=0;j<7;j++){
    int i = tid + j*256;
    if(i < 1584){
      int oct = i/396; int rem = i - oct*396;
      int hy = rem/66, wx = rem - hy*66;
      int hh = h0 - 1 + hy, ww = w0 - 1 + wx;
      xlds[j] = &xs[hy][oct][wx][0];
      xoff[j] = (hh>=0 && hh<H_ && ww>=0 && ww<W_) ? (((n*32+oct)*H_ + hh)*W_ + ww)*8 : -1;
    } else { xlds[j] = nullptr; xoff[j] = -1; }
  }
  const __bf16* kbase = kerP + (size_t)(n*2+ps)*8*2304*8;

  bf16x8 xv[7], kv[9];
  bf16x8 zro;
  #pragma unroll
  for(int u=0;u<8;u++) zro[u] = (__bf16)0.f;
  #pragma unroll
  for(int j=0;j<7;j++) xv[j] = zro;
  // prologue: load step 0
  #pragma unroll
  for(int j=0;j<7;j++)
    if(xoff[j] >= 0) xv[j] = *(const bf16x8*)&xT[xoff[j]];
  #pragma unroll
  for(int j=0;j<9;j++) kv[j] = *(const bf16x8*)&kbase[(size_t)(tid + j*256)*8];

  for(int s=0; s<8; s++){
    __syncthreads();                       // prior step's LDS consumers done
    #pragma unroll
    for(int j=0;j<7;j++)
      if(tid + j*256 < 1584) *(bf16x8*)xlds[j] = xv[j];
    #pragma unroll
    for(int j=0;j<9;j++) *(bf16x8*)&ksf[(size_t)(tid + j*256)*8] = kv[j];
    __syncthreads();                       // tiles visible
    if(s < 7){                             // issue NEXT step's loads (fly during MFMAs)
      #pragma unroll
      for(int j=0;j<7;j++)
        if(xoff[j] >= 0) xv[j] = *(const bf16x8*)&xT[xoff[j] + (s+1)*786432];
      const __bf16* kb2 = kbase + (size_t)(s+1)*18432;
      #pragma unroll
      for(int j=0;j<9;j++) kv[j] = *(const bf16x8*)&kb2[(size_t)(tid + j*256)*8];
    }
    #pragma unroll
    for(int ky=0; ky<3; ky++){
      #pragma unroll
      for(int kx=0; kx<3; kx++){
        const int tap = ky*3 + kx;
        const int hy = hi + ky;
        bf16x8 b[4];
        #pragma unroll
        for(int t=0;t<4;t++) b[t] = *(const bf16x8*)&xs[hy][quad][t*16 + col + kx][0];
        #pragma unroll
        for(int pt=0; pt<4; pt++){
          if(pt < NT){
            bf16x8 a = *(const bf16x8*)&ks[tap][quad][pt*16 + col][0];
            #pragma unroll
            for(int t=0;t<4;t++)
              acc[pt][t] = __builtin_amdgcn_mfma_f32_16x16x32_bf16(a, b[t], acc[pt][t], 0, 0, 0);
          }
        }
      }
    }
  }
  const int h = h0 + hi;
  #pragma unroll
  for(int pt=0; pt<4; pt++){
    if(pt < NT){
      #pragma unroll
      for(int r=0;r<4;r++){
        int p = pbase + pt*16 + quad*4 + r;
        if(p < P_){
          float* op = &out[((size_t)(n*P_+p)*H_ + h)*W_ + w0 + col];
          #pragma unroll
          for(int t=0;t<4;t++) op[t*16] = acc[pt][t][r];
        }
      }
    }
  }
}

extern "C" void kernel_launch(void* const* d_in, const int* in_sizes, int n_in,
                              void* d_out, int out_size, void* d_ws, size_t ws_size,
                              hipStream_t stream)
{
  (void)in_sizes; (void)n_in; (void)out_size; (void)ws_size;
  const float* x          = (const float*)d_in[0];
  const float* prop       = (const float*)d_in[1];
  const float* mask_pred  = (const float*)d_in[2];
  const float* ku_dyn_w   = (const float*)d_in[3];
  const float* ku_dyn_b   = (const float*)d_in[4];
  const float* ku_in_w    = (const float*)d_in[5];
  const float* ku_in_b    = (const float*)d_in[6];
  const float* ku_ig_w    = (const float*)d_in[7];
  const float* ku_ig_b    = (const float*)d_in[8];
  const float* ku_ug_w    = (const float*)d_in[9];
  const float* ku_ug_b    = (const float*)d_in[10];
  const float* ku_nin_g   = (const float*)d_in[11];
  const float* ku_nin_b   = (const float*)d_in[12];
  const float* ku_nout_g  = (const float*)d_in[13];
  const float* ku_nout_b  = (const float*)d_in[14];
  const float* ku_inin_g  = (const float*)d_in[15];
  const float* ku_inin_b  = (const float*)d_in[16];
  const float* ku_inout_g = (const float*)d_in[17];
  const float* ku_inout_b = (const float*)d_in[18];
  const float* ku_fc_w    = (const float*)d_in[19];
  const float* ku_fc_b    = (const float*)d_in[20];
  const float* ku_fcn_g   = (const float*)d_in[21];
  const float* ku_fcn_b   = (const float*)d_in[22];
  const float* attn_in_w  = (const float*)d_in[23];
  const float* attn_in_b  = (const float*)d_in[24];
  const float* attn_out_w = (const float*)d_in[25];
  const float* attn_out_b = (const float*)d_in[26];
  const float* attn_ln_g  = (const float*)d_in[27];
  const float* attn_ln_b  = (const float*)d_in[28];
  const float* ffn_w1     = (const float*)d_in[29];
  const float* ffn_b1     = (const float*)d_in[30];
  const float* ffn_w2     = (const float*)d_in[31];
  const float* ffn_b2     = (const float*)d_in[32];
  const float* ffn_ln_g   = (const float*)d_in[33];
  const float* ffn_ln_b   = (const float*)d_in[34];
  const float* mask_fc_ws = (const float*)d_in[35];
  const float* mask_fc_ln_g = (const float*)d_in[36];
  const float* mask_fc_ln_b = (const float*)d_in[37];
  const float* fc_mask_w  = (const float*)d_in[38];
  const float* fc_mask_b  = (const float*)d_in[39];

  float* ws = (float*)d_ws;
  float* sig     = ws;
  float* hbuf    = ws;
  float* skA     = ws;                // split-K scratch: attn_in S=6 needs 8.29M floats [0..8294400)
  float* partial = ws + 4915200;      // dead after k_xfeat2
  float* skB     = ws + 4915200;      // split-K scratch (ffn2)
  float* attnO   = ws + 4915200 + 1382400;
  float* tproj   = ws + 4915200 + 1843200;
  float* tmp     = ws + 4915200 + 2304000;  // pre-LN gemm output (1800x256)
  // qkv relocated to [8294400..9676800) so attn_in's 6 partial slabs fit below it.
  float* qkv     = ws + 8294400;
  float* xfeat   = ws + 9830400;
  float* params  = xfeat + 51200;
  float* pf      = params + 102400;
  float* inp     = pf + 460800;
  float* gate    = inp + 921600;
  float* ig      = gate + 460800;
  float* ug      = ig + 460800;
  float* feat    = ug + 460800;
  float* obj0    = feat + 460800;
  float* obj1    = obj0 + 460800;
  float* obj2    = obj1 + 460800;
  float* mf1     = obj2 + 460800;
  float* mf2     = mf1 + 460800;
  float* mfF     = mf2 + 460800;
  // xT (bf16) at ws[0..6291456 float slots): sig/hbuf/skA/skB dead by k_prep_x.
  __bf16* xT = (__bf16*)ws;
  // kerP (bf16, 589824 elems = 294912 float slots) in dead tproj region (cap 460800).
  __bf16* kerP = (__bf16*)(ws + 6758400);

  float* out_masks = (float*)d_out;
  float* out_kern  = out_masks + (size_t)N_*P_*HW_;

  k_softmax<<<192, 256, 0, stream>>>(mask_pred, sig);
  k_permute_pf<<<1800, 256, 0, stream>>>(prop, pf);
  k_xfeat1m<<<dim3(2,XKC_,2), 256, 0, stream>>>(sig, x, partial);
  k_xfeat2<<<200, 256, 0, stream>>>(partial, xfeat);
  k_gemm_mfma<<<dim3(4,4),   256, 0, stream>>>(xfeat, ku_dyn_w, ku_dyn_b, params, 200, 512, 256, 0);
  k_gemm_mfma<<<dim3(4,29),  256, 0, stream>>>(pf, ku_in_w, ku_in_b, inp, 1800, 512, 256, 0);
  k_gate<<<1800, 256, 0, stream>>>(inp, params, gate);
  k_gemm_mfma<<<dim3(2,29),  256, 0, stream>>>(gate, ku_ig_w, ku_ig_b, tmp, 1800, 256, 256, 0);
  k_ln256<<<450, 256, 0, stream>>>(tmp, nullptr, ku_inin_g, ku_inin_b, ig, 1800, 2);
  k_gemm_mfma<<<dim3(2,29),  256, 0, stream>>>(gate, ku_ug_w, ku_ug_b, tmp, 1800, 256, 256, 0);
  k_ln256<<<450, 256, 0, stream>>>(tmp, nullptr, ku_nin_g, ku_nin_b, ug, 1800, 2);
  k_combine<<<1800, 256, 0, stream>>>(params, inp, ug, ig, ku_nout_g, ku_nout_b, ku_inout_g, ku_inout_b, feat);
  k_gemm_mfma<<<dim3(2,29),  256, 0, stream>>>(feat, ku_fc_w, ku_fc_b, tmp, 1800, 256, 256, 0);
  k_ln256<<<450, 256, 0, stream>>>(tmp, nullptr, ku_fcn_g, ku_fcn_b, obj0, 1800, 1);
  // attn_in: BM=256/BN=64, split-K x6 (KC=384): 648 blocks, weight read by exactly one block
  k_gemm_skM256<<<dim3(108,6), 256, 0, stream>>>(obj0, attn_in_w, skA, 200, 6912, 2304, 384);
  k_redk<<<1350, 256, 0, stream>>>(skA, attn_in_b, qkv, 200, 6912, 6);
  k_attn2<<<dim3(10,8,2), 256, 0, stream>>>(qkv, attnO);
  // attn_out: BM=256/BN=64, split-K x9 (KC=256): 324 blocks
  k_gemm_skM256<<<dim3(36,9), 256, 0, stream>>>(attnO, attn_out_w, skA, 200, 2304, 2304, 256);
  k_redk<<<450, 256, 0, stream>>>(skA, attn_out_b, tproj, 200, 2304, 9);
  k_add_ln2304<<<200, 256, 0, stream>>>(obj0, tproj, attn_ln_g, attn_ln_b, obj1);
  k_gemm_mfma<<<dim3(16,29), 256, 0, stream>>>(obj1, ffn_w1, ffn_b1, hbuf, 1800, 2048, 256, 1);
  // ffn2: split-K x4 (K=2048 -> 4x512); scratch in dead region above hbuf
  k_gemm_splitk<<<232, 256, 0, stream>>>(hbuf, ffn_w2, skB, 1800, 256, 2048, 512, 2, 29);
  k_redk<<<450, 256, 0, stream>>>(skB, ffn_b2, tmp, 1800, 256, 4);
  k_ln256<<<450, 256, 0, stream>>>(tmp, obj1, ffn_ln_g, ffn_ln_b, obj2, 1800, 0);
  k_gemm_mfma<<<dim3(2,29),  256, 0, stream>>>(obj2, mask_fc_ws,          nullptr, tmp, 1800, 256, 256, 0);
  k_ln256<<<450, 256, 0, stream>>>(tmp, nullptr, mask_fc_ln_g,       mask_fc_ln_b,       mf1, 1800, 1);
  k_gemm_mfma<<<dim3(2,29),  256, 0, stream>>>(mf1,  mask_fc_ws + 65536,  nullptr, tmp, 1800, 256, 256, 0);
  k_ln256<<<450, 256, 0, stream>>>(tmp, nullptr, mask_fc_ln_g + 256, mask_fc_ln_b + 256, mf2, 1800, 1);
  k_gemm_mfma<<<dim3(2,29),  256, 0, stream>>>(mf2,  mask_fc_ws + 131072, nullptr, tmp, 1800, 256, 256, 0);
  k_ln256<<<450, 256, 0, stream>>>(tmp, nullptr, mask_fc_ln_g + 512, mask_fc_ln_b + 512, mf1, 1800, 1);
  // final kernel GEMM stores bf16 directly (identical numerics: same RNE convert)
  k_gemm_mfma<<<dim3(2,29),  256, 0, stream>>>(mf1, fc_mask_w, fc_mask_b, mfF, 1800, 256, 256, 3);
  k_objk<<<1800, 256, 0, stream>>>(obj2, out_kern);
  k_permute_ker<<<288, 256, 0, stream>>>((const __bf16*)mfF, kerP);
  k_prep_x<<<6144, 256, 0, stream>>>(x, xT);
  k_conv_mfma<<<dim3(3,32,4), 256, 0, stream>>>(xT, kerP, out_masks);
}

// Round 8
// 697.148 us; speedup vs baseline: 1.0948x; 1.0285x over previous
//
#include <hip/hip_runtime.h>
#include <hip/hip_bf16.h>

#define N_ 2
#define P_ 100
#define C_ 256
#define H_ 128
#define W_ 192
#define HW_ 24576
#define KK_ 9
#define E_ 2304
#define NH_ 8
#define DH_ 288
#define FFN_ 2048
#define NP_ 200
#define ROWS_ 1800   // NP_*KK_
#define XKC_ 64      // xfeat split-K chunks

typedef __attribute__((ext_vector_type(8))) __bf16 bf16x8;
typedef __attribute__((ext_vector_type(4))) float f32x4;

// ---------------- softmax over P axis of mask_preds ----------------
__global__ __launch_bounds__(256) void k_softmax(const float* __restrict__ mp, float* __restrict__ sig){
  int idx = blockIdx.x*256 + threadIdx.x;
  if(idx >= N_*HW_) return;
  int n = idx / HW_, hw = idx - n*HW_;
  const float* base = mp + (size_t)n*P_*HW_ + hw;
  float m = -1e30f;
  for(int p=0;p<P_;p++) m = fmaxf(m, base[(size_t)p*HW_]);
  float s = 0.f;
  for(int p=0;p<P_;p++) s += __expf(base[(size_t)p*HW_] - m);
  float inv = 1.f/s;
  float* ob = sig + (size_t)n*P_*HW_ + hw;
  for(int p=0;p<P_;p++) ob[(size_t)p*HW_] = __expf(base[(size_t)p*HW_] - m)*inv;
}

// ---------------- pf permute: pf[np][kk][c] = prop[n][p][c*9+kk] ----------------
__global__ __launch_bounds__(256) void k_permute_pf(const float* __restrict__ prop, float* __restrict__ pf){
  int i = blockIdx.x*256 + threadIdx.x;
  if(i >= ROWS_*C_) return;
  int c = i & 255;
  int r = i >> 8;            // np*9+kk
  int kk = r % 9, np = r / 9;
  pf[i] = prop[(size_t)np*E_ + c*KK_ + kk];
}

// ---------------- x_feat stage 1: bf16 MFMA split-K ----------------
__global__ __launch_bounds__(256) void k_xfeat1m(const float* __restrict__ sig, const float* __restrict__ x,
                                                 float* __restrict__ partial){
  const int ct = blockIdx.x, kb = blockIdx.y, n = blockIdx.z;
  const int hw0 = kb*384;
  const int tid = threadIdx.x;
  const int wid = tid >> 6, lane = tid & 63;
  const int col = lane & 15, quad = lane >> 4;
  const int wm = wid & 1, wn = wid >> 1;
  const int MT = wm ? 3 : 4;
  __shared__ __bf16 As[112][72];
  __shared__ __bf16 Bs[128][72];
  f32x4 acc[4][4] = {};
  for(int k0=0; k0<384; k0+=64){
    __syncthreads();
    for(int i=tid; i<896; i+=256){
      int p = i >> 3, kg = i & 7;
      bf16x8 v;
      if(p < P_){
        const float* sp = &sig[((size_t)n*P_ + p)*HW_ + hw0 + k0 + kg*8];
        const float4 f0 = *(const float4*)sp;
        const float4 f1 = *(const float4*)(sp+4);
        v[0]=(__bf16)f0.x; v[1]=(__bf16)f0.y; v[2]=(__bf16)f0.z; v[3]=(__bf16)f0.w;
        v[4]=(__bf16)f1.x; v[5]=(__bf16)f1.y; v[6]=(__bf16)f1.z; v[7]=(__bf16)f1.w;
      } else {
        #pragma unroll
        for(int u=0;u<8;u++) v[u] = (__bf16)0.f;
      }
      *(bf16x8*)&As[p][kg*8] = v;
    }
    for(int i=tid; i<1024; i+=256){
      int c = i >> 3, kg = i & 7;
      const float* xp = &x[((size_t)n*C_ + ct*128 + c)*HW_ + hw0 + k0 + kg*8];
      const float4 f0 = *(const float4*)xp;
      const float4 f1 = *(const float4*)(xp+4);
      bf16x8 v;
      v[0]=(__bf16)f0.x; v[1]=(__bf16)f0.y; v[2]=(__bf16)f0.z; v[3]=(__bf16)f0.w;
      v[4]=(__bf16)f1.x; v[5]=(__bf16)f1.y; v[6]=(__bf16)f1.z; v[7]=(__bf16)f1.w;
      *(bf16x8*)&Bs[c][kg*8] = v;
    }
    __syncthreads();
    #pragma unroll
    for(int ks=0; ks<2; ks++){
      bf16x8 b[4];
      #pragma unroll
      for(int t=0;t<4;t++) b[t] = *(const bf16x8*)&Bs[(wn*4+t)*16 + col][ks*32 + quad*8];
      #pragma unroll
      for(int mt=0; mt<4; mt++){
        if(mt < MT){
          bf16x8 a = *(const bf16x8*)&As[(wm*4+mt)*16 + col][ks*32 + quad*8];
          #pragma unroll
          for(int t=0;t<4;t++)
            acc[mt][t] = __builtin_amdgcn_mfma_f32_16x16x32_bf16(a, b[t], acc[mt][t], 0, 0, 0);
        }
      }
    }
  }
  #pragma unroll
  for(int mt=0; mt<4; mt++){
    if(mt < MT){
      #pragma unroll
      for(int r=0;r<4;r++){
        int p = (wm*4+mt)*16 + quad*4 + r;
        if(p < P_){
          float* op = &partial[(((size_t)n*XKC_ + kb)*P_ + p)*C_ + ct*128 + wn*64 + col];
          #pragma unroll
          for(int t=0;t<4;t++) op[t*16] = acc[mt][t][r];
        }
      }
    }
  }
}

// ---------------- x_feat stage 2: reduce over XKC_ chunks ----------------
__global__ __launch_bounds__(256) void k_xfeat2(const float* __restrict__ partial, float* __restrict__ xfeat){
  int np = blockIdx.x;
  int n = np / P_, p = np - n*P_;
  int c = threadIdx.x;
  float s = 0.f;
  for(int kb=0;kb<XKC_;kb++) s += partial[(((size_t)n*XKC_ + kb)*P_ + p)*C_ + c];
  xfeat[(size_t)np*C_ + c] = s;
}

// ---------------- generic bf16 MFMA GEMM: out = act(A @ W^T + bias) ----------------
// BM=64, BN=128, BK=64. act: 0 none, 1 relu, 3 store-bf16.
__global__ __launch_bounds__(256) void k_gemm_mfma(const float* __restrict__ A, const float* __restrict__ Wt,
    const float* __restrict__ bias, float* __restrict__ out, int M, int N, int K, int act)
{
  const int n0 = blockIdx.x*128, m0 = blockIdx.y*64;
  const int tid = threadIdx.x;
  const int wid = tid >> 6, lane = tid & 63;
  const int col = lane & 15, quad = lane >> 4;
  const int wm = wid & 1, wn = wid >> 1;
  __shared__ __bf16 As[64][72];
  __shared__ __bf16 Bs[128][72];
  f32x4 acc[2][4] = {};
  for(int k0=0; k0<K; k0+=64){
    __syncthreads();
    for(int i=tid; i<512; i+=256){
      int r = i >> 3, kg = i & 7;
      int m = m0 + r;
      bf16x8 v;
      if(m < M){
        const float* ap = &A[(size_t)m*K + k0 + kg*8];
        const float4 f0 = *(const float4*)ap;
        const float4 f1 = *(const float4*)(ap+4);
        v[0]=(__bf16)f0.x; v[1]=(__bf16)f0.y; v[2]=(__bf16)f0.z; v[3]=(__bf16)f0.w;
        v[4]=(__bf16)f1.x; v[5]=(__bf16)f1.y; v[6]=(__bf16)f1.z; v[7]=(__bf16)f1.w;
      } else {
        #pragma unroll
        for(int u=0;u<8;u++) v[u] = (__bf16)0.f;
      }
      *(bf16x8*)&As[r][kg*8] = v;
    }
    for(int i=tid; i<1024; i+=256){
      int r = i >> 3, kg = i & 7;
      const float* wp = &Wt[(size_t)(n0 + r)*K + k0 + kg*8];
      const float4 f0 = *(const float4*)wp;
      const float4 f1 = *(const float4*)(wp+4);
      bf16x8 v;
      v[0]=(__bf16)f0.x; v[1]=(__bf16)f0.y; v[2]=(__bf16)f0.z; v[3]=(__bf16)f0.w;
      v[4]=(__bf16)f1.x; v[5]=(__bf16)f1.y; v[6]=(__bf16)f1.z; v[7]=(__bf16)f1.w;
      *(bf16x8*)&Bs[r][kg*8] = v;
    }
    __syncthreads();
    #pragma unroll
    for(int ks=0; ks<2; ks++){
      bf16x8 b[4], a[2];
      #pragma unroll
      for(int t=0;t<4;t++) b[t] = *(const bf16x8*)&Bs[(wn*4+t)*16 + col][ks*32 + quad*8];
      #pragma unroll
      for(int mt=0;mt<2;mt++) a[mt] = *(const bf16x8*)&As[(wm*2+mt)*16 + col][ks*32 + quad*8];
      #pragma unroll
      for(int mt=0;mt<2;mt++)
        #pragma unroll
        for(int t=0;t<4;t++)
          acc[mt][t] = __builtin_amdgcn_mfma_f32_16x16x32_bf16(a[mt], b[t], acc[mt][t], 0, 0, 0);
    }
  }
  #pragma unroll
  for(int mt=0;mt<2;mt++){
    #pragma unroll
    for(int r=0;r<4;r++){
      int m = m0 + (wm*2+mt)*16 + quad*4 + r;
      if(m < M){
        #pragma unroll
        for(int t=0;t<4;t++){
          int n = n0 + (wn*4+t)*16 + col;
          float v = acc[mt][t][r];
          if(bias) v += bias[n];
          if(act == 1) v = fmaxf(v, 0.f);
          if(act == 3) ((__bf16*)out)[(size_t)m*N + n] = (__bf16)v;
          else out[(size_t)m*N + n] = v;
        }
      }
    }
  }
}

// ---------------- full-M split-K GEMM: BM=256 x BN=64 ----------------
// Weight element -> exactly one block (no cross-XCD weight duplication) while
// BN=64 + deep split-K keeps >600 blocks (R5 lesson: dedup w/o parallelism loses).
__global__ __launch_bounds__(256) void k_gemm_skM256(const float* __restrict__ A, const float* __restrict__ Wt,
    float* __restrict__ part, int M, int N, int K, int KC)
{
  const int n0 = blockIdx.x*64;
  const int kz = blockIdx.y*KC;
  const int tid = threadIdx.x;
  const int wid = tid >> 6, lane = tid & 63;
  const int col = lane & 15, quad = lane >> 4;
  const int wm = wid & 1, wn = wid >> 1;   // wave tile: 128m x 32n
  __shared__ __bf16 As[256][72];
  __shared__ __bf16 Bs[64][72];
  f32x4 acc[8][2] = {};
  for(int k0=kz; k0<kz+KC; k0+=64){
    __syncthreads();
    for(int i=tid; i<2048; i+=256){
      int r = i >> 3, kg = i & 7;
      bf16x8 v;
      if(r < M){
        const float* ap = &A[(size_t)r*K + k0 + kg*8];
        const float4 f0 = *(const float4*)ap;
        const float4 f1 = *(const float4*)(ap+4);
        v[0]=(__bf16)f0.x; v[1]=(__bf16)f0.y; v[2]=(__bf16)f0.z; v[3]=(__bf16)f0.w;
        v[4]=(__bf16)f1.x; v[5]=(__bf16)f1.y; v[6]=(__bf16)f1.z; v[7]=(__bf16)f1.w;
      } else {
        #pragma unroll
        for(int u=0;u<8;u++) v[u] = (__bf16)0.f;
      }
      *(bf16x8*)&As[r][kg*8] = v;
    }
    for(int i=tid; i<512; i+=256){
      int r = i >> 3, kg = i & 7;
      const float* wp = &Wt[(size_t)(n0 + r)*K + k0 + kg*8];
      const float4 f0 = *(const float4*)wp;
      const float4 f1 = *(const float4*)(wp+4);
      bf16x8 v;
      v[0]=(__bf16)f0.x; v[1]=(__bf16)f0.y; v[2]=(__bf16)f0.z; v[3]=(__bf16)f0.w;
      v[4]=(__bf16)f1.x; v[5]=(__bf16)f1.y; v[6]=(__bf16)f1.z; v[7]=(__bf16)f1.w;
      *(bf16x8*)&Bs[r][kg*8] = v;
    }
    __syncthreads();
    #pragma unroll
    for(int ks=0; ks<2; ks++){
      bf16x8 b[2];
      #pragma unroll
      for(int t=0;t<2;t++) b[t] = *(const bf16x8*)&Bs[(wn*2+t)*16 + col][ks*32 + quad*8];
      #pragma unroll
      for(int mt=0;mt<8;mt++){
        bf16x8 a = *(const bf16x8*)&As[(wm*8+mt)*16 + col][ks*32 + quad*8];
        #pragma unroll
        for(int t=0;t<2;t++)
          acc[mt][t] = __builtin_amdgcn_mfma_f32_16x16x32_bf16(a, b[t], acc[mt][t], 0, 0, 0);
      }
    }
  }
  float* pbase = part + (size_t)blockIdx.y*M*N;
  #pragma unroll
  for(int mt=0;mt<8;mt++){
    #pragma unroll
    for(int r=0;r<4;r++){
      int m = (wm*8+mt)*16 + quad*4 + r;
      if(m < M){
        #pragma unroll
        for(int t=0;t<2;t++){
          int n = n0 + (wn*2+t)*16 + col;
          pbase[(size_t)m*N + n] = acc[mt][t][r];
        }
      }
    }
  }
}

// ---------------- split-K bf16 MFMA GEMM, XCD-grouped 1D grid (ffn2) ----------------
__global__ __launch_bounds__(256) void k_gemm_splitk(const float* __restrict__ A, const float* __restrict__ Wt,
    float* __restrict__ part, int M, int N, int K, int KC, int PX, int MY)
{
  const int wg = blockIdx.x;
  const int xcd = wg & 7, slot = wg >> 3;
  const int mb = slot % MY, pg = slot / MY;
  const int panel = xcd + 8*pg;
  const int PZ = K / KC;
  if(panel >= PX*PZ) return;
  const int px = panel % PX, pz = panel / PX;
  const int n0 = px*128, m0 = mb*64;
  const int kz = pz*KC;
  const int tid = threadIdx.x;
  const int wid = tid >> 6, lane = tid & 63;
  const int col = lane & 15, quad = lane >> 4;
  const int wm = wid & 1, wn = wid >> 1;
  __shared__ __bf16 As[64][72];
  __shared__ __bf16 Bs[128][72];
  f32x4 acc[2][4] = {};
  for(int k0=kz; k0<kz+KC; k0+=64){
    __syncthreads();
    for(int i=tid; i<512; i+=256){
      int r = i >> 3, kg = i & 7;
      int m = m0 + r;
      bf16x8 v;
      if(m < M){
        const float* ap = &A[(size_t)m*K + k0 + kg*8];
        const float4 f0 = *(const float4*)ap;
        const float4 f1 = *(const float4*)(ap+4);
        v[0]=(__bf16)f0.x; v[1]=(__bf16)f0.y; v[2]=(__bf16)f0.z; v[3]=(__bf16)f0.w;
        v[4]=(__bf16)f1.x; v[5]=(__bf16)f1.y; v[6]=(__bf16)f1.z; v[7]=(__bf16)f1.w;
      } else {
        #pragma unroll
        for(int u=0;u<8;u++) v[u] = (__bf16)0.f;
      }
      *(bf16x8*)&As[r][kg*8] = v;
    }
    for(int i=tid; i<1024; i+=256){
      int r = i >> 3, kg = i & 7;
      const float* wp = &Wt[(size_t)(n0 + r)*K + k0 + kg*8];
      const float4 f0 = *(const float4*)wp;
      const float4 f1 = *(const float4*)(wp+4);
      bf16x8 v;
      v[0]=(__bf16)f0.x; v[1]=(__bf16)f0.y; v[2]=(__bf16)f0.z; v[3]=(__bf16)f0.w;
      v[4]=(__bf16)f1.x; v[5]=(__bf16)f1.y; v[6]=(__bf16)f1.z; v[7]=(__bf16)f1.w;
      *(bf16x8*)&Bs[r][kg*8] = v;
    }
    __syncthreads();
    #pragma unroll
    for(int ks=0; ks<2; ks++){
      bf16x8 b[4], a[2];
      #pragma unroll
      for(int t=0;t<4;t++) b[t] = *(const bf16x8*)&Bs[(wn*4+t)*16 + col][ks*32 + quad*8];
      #pragma unroll
      for(int mt=0;mt<2;mt++) a[mt] = *(const bf16x8*)&As[(wm*2+mt)*16 + col][ks*32 + quad*8];
      #pragma unroll
      for(int mt=0;mt<2;mt++)
        #pragma unroll
        for(int t=0;t<4;t++)
          acc[mt][t] = __builtin_amdgcn_mfma_f32_16x16x32_bf16(a[mt], b[t], acc[mt][t], 0, 0, 0);
    }
  }
  float* pbase = part + (size_t)pz*M*N;
  #pragma unroll
  for(int mt=0;mt<2;mt++){
    #pragma unroll
    for(int r=0;r<4;r++){
      int m = m0 + (wm*2+mt)*16 + quad*4 + r;
      if(m < M){
        #pragma unroll
        for(int t=0;t<4;t++){
          int n = n0 + (wn*4+t)*16 + col;
          pbase[(size_t)m*N + n] = acc[mt][t][r];
        }
      }
    }
  }
}

// ---------------- split-K reduce: out = sum_z part[z] + bias ----------------
__global__ __launch_bounds__(256) void k_redk(const float* __restrict__ part, const float* __restrict__ bias,
    float* __restrict__ out, int M, int N, int S)
{
  size_t i4 = ((size_t)blockIdx.x*256 + threadIdx.x)*4;
  size_t MN = (size_t)M*N;
  if(i4 >= MN) return;
  float4 s = *(const float4*)&part[i4];
  for(int z=1; z<S; z++){
    const float4 p = *(const float4*)&part[(size_t)z*MN + i4];
    s.x+=p.x; s.y+=p.y; s.z+=p.z; s.w+=p.w;
  }
  if(bias){
    int n = (int)(i4 % (size_t)N);
    const float4 b = *(const float4*)&bias[n];
    s.x+=b.x; s.y+=b.y; s.z+=b.z; s.w+=b.w;
  }
  *(float4*)&out[i4] = s;
}

// ---------------- row LayerNorm over C=256 (+residual, +act) ----------------
__global__ __launch_bounds__(256) void k_ln256(const float* __restrict__ in, const float* __restrict__ res,
    const float* __restrict__ g, const float* __restrict__ b, float* __restrict__ out, int M, int act)
{
  int row = blockIdx.x*4 + (threadIdx.x >> 6);
  int lane = threadIdx.x & 63;
  if(row >= M) return;
  float4 v = *(const float4*)&in[(size_t)row*C_ + lane*4];
  if(res){
    const float4 rv = *(const float4*)&res[(size_t)row*C_ + lane*4];
    v.x += rv.x; v.y += rv.y; v.z += rv.z; v.w += rv.w;
  }
  float s = v.x + v.y + v.z + v.w;
  float q = v.x*v.x + v.y*v.y + v.z*v.z + v.w*v.w;
  #pragma unroll
  for(int off=32; off; off>>=1){ s += __shfl_xor(s, off, 64); q += __shfl_xor(q, off, 64); }
  float mean = s*(1.f/256.f);
  float rstd = rsqrtf(q*(1.f/256.f) - mean*mean + 1e-5f);
  const float4 gv = *(const float4*)&g[lane*4];
  const float4 bv = *(const float4*)&b[lane*4];
  float o[4] = {(v.x-mean)*rstd*gv.x + bv.x, (v.y-mean)*rstd*gv.y + bv.y,
                (v.z-mean)*rstd*gv.z + bv.z, (v.w-mean)*rstd*gv.w + bv.w};
  #pragma unroll
  for(int j=0;j<4;j++){
    if(act==1) o[j] = fmaxf(o[j], 0.f);
    else if(act==2) o[j] = 1.f/(1.f + __expf(-o[j]));
  }
  float4 ov = {o[0],o[1],o[2],o[3]};
  *(float4*)&out[(size_t)row*C_ + lane*4] = ov;
}

// ---------------- gate = i_in * p_in ----------------
__global__ __launch_bounds__(256) void k_gate(const float* __restrict__ inp, const float* __restrict__ params,
                                              float* __restrict__ gate){
  int i = blockIdx.x*256 + threadIdx.x;
  if(i >= ROWS_*C_) return;
  int c = i & 255, r = i >> 8;
  int np = r / 9;
  gate[i] = inp[(size_t)r*512 + c] * params[(size_t)np*512 + c];
}

// ---------------- block LN helper ----------------
__device__ __forceinline__ void block_stats(float v, float* red, int slot, float& mean, float& rstd){
  float s = v, q = v*v;
  #pragma unroll
  for(int off=32; off; off>>=1){ s += __shfl_xor(s, off, 64); q += __shfl_xor(q, off, 64); }
  int wid = threadIdx.x >> 6;
  if((threadIdx.x & 63) == 0){ red[slot + wid] = s; red[slot + 4 + wid] = q; }
  __syncthreads();
  s = red[slot+0]+red[slot+1]+red[slot+2]+red[slot+3];
  q = red[slot+4]+red[slot+5]+red[slot+6]+red[slot+7];
  mean = s*(1.f/256.f);
  rstd = rsqrtf(q*(1.f/256.f) - mean*mean + 1e-5f);
}

// ---------------- feat = ug * LN(p_out) + ig * LN(i_out) ----------------
__global__ __launch_bounds__(256) void k_combine(const float* __restrict__ params, const float* __restrict__ inp,
  const float* __restrict__ ug, const float* __restrict__ ig,
  const float* __restrict__ nout_g, const float* __restrict__ nout_b,
  const float* __restrict__ inout_g, const float* __restrict__ inout_b,
  float* __restrict__ feat)
{
  __shared__ float red[16];
  int r = blockIdx.x;           // np*9+kk
  int np = r / 9;
  int c = threadIdx.x;
  float pv = params[(size_t)np*512 + 256 + c];
  float mean, rstd;
  block_stats(pv, red, 0, mean, rstd);
  float pn = (pv - mean)*rstd*nout_g[c] + nout_b[c];
  float iv = inp[(size_t)r*512 + 256 + c];
  float mean2, rstd2;
  block_stats(iv, red, 8, mean2, rstd2);
  float iw = (iv - mean2)*rstd2*inout_g[c] + inout_b[c];
  size_t o = (size_t)r*C_ + c;
  feat[o] = ug[o]*pn + ig[o]*iw;
}

// ---------------- K transpose for attention: kT2[((n*8+h)*288+d)*64 + l] = (K[2l][d], K[2l+1][d]) ----------------
__global__ __launch_bounds__(256) void k_prep_kT(const float* __restrict__ qkv, float2* __restrict__ kT2){
  int i = blockIdx.x*256 + threadIdx.x;
  if(i >= N_*NH_*DH_*64) return;
  int l = i & 63; int t = i >> 6;
  int d = t % DH_; t /= DH_;
  int h = t & 7, n = t >> 3;
  float2 v = {0.f, 0.f};
  if(l < 50){
    size_t base = (size_t)(n*P_ + 2*l)*6912 + E_ + (size_t)h*DH_ + d;
    v.x = qkv[base];
    v.y = qkv[base + 6912];
  }
  kT2[i] = v;
}

// ---------------- attention v3: one wave per (q,h), zero staging barriers ----------------
// Scores: lanes-over-keys via float2 kT reads (lane l holds keys 2l,2l+1; lanes>=50 padded).
// Softmax: in-wave shfl reduce. PV: lanes-over-d, float4 V reads, P broadcast from LDS.
__global__ __launch_bounds__(256) void k_attn3(const float* __restrict__ qkv, const float2* __restrict__ kT2,
                                               float* __restrict__ attnO){
  const int qb = blockIdx.x, h = blockIdx.y, n = blockIdx.z;
  const int w = threadIdx.x >> 6, lane = threadIdx.x & 63;
  const int q = qb*4 + w;
  __shared__ float Qs[4][288];
  __shared__ float Ps[4][128];
  const float scale = 0.05892556509887896f;   // 1/sqrt(288)
  // Q row -> LDS (wave-local), scaled; float4 loads
  {
    const float4* qrow4 = (const float4*)(qkv + (size_t)(n*P_ + q)*6912 + (size_t)h*DH_);
    float4* qs4 = (float4*)&Qs[w][0];
    float4 a = qrow4[lane];
    a.x*=scale; a.y*=scale; a.z*=scale; a.w*=scale;
    qs4[lane] = a;
    if(lane < 8){
      float4 b = qrow4[64+lane];
      b.x*=scale; b.y*=scale; b.z*=scale; b.w*=scale;
      qs4[64+lane] = b;
    }
  }
  __syncthreads();
  // scores: s0 = key 2*lane, s1 = key 2*lane+1 (valid lanes < 50)
  const float2* kcol = kT2 + (size_t)(n*NH_ + h)*DH_*64;
  float s0 = 0.f, s1 = 0.f;
  #pragma unroll 8
  for(int d=0; d<DH_; d++){
    float qv = Qs[w][d];
    float2 kk = kcol[d*64 + lane];
    s0 += qv*kk.x;
    s1 += qv*kk.y;
  }
  bool valid = lane < 50;
  float m = valid ? fmaxf(s0, s1) : -1e30f;
  #pragma unroll
  for(int off=32; off; off>>=1) m = fmaxf(m, __shfl_xor(m, off, 64));
  float e0 = valid ? __expf(s0 - m) : 0.f;
  float e1 = valid ? __expf(s1 - m) : 0.f;
  float sum = e0 + e1;
  #pragma unroll
  for(int off=32; off; off>>=1) sum += __shfl_xor(sum, off, 64);
  float inv = 1.f/sum;
  if(valid){
    Ps[w][2*lane]   = e0*inv;
    Ps[w][2*lane+1] = e1*inv;
  }
  __syncthreads();
  // PV: lanes-over-d. accA covers d=4*lane..4*lane+3; accB tail d=256+4*(lane&7).
  float4 accA = {0,0,0,0}, accB = {0,0,0,0};
  const float* vbase = qkv + (size_t)n*P_*6912 + 2*E_ + (size_t)h*DH_;
  #pragma unroll 4
  for(int k=0; k<P_; k++){
    float pk = Ps[w][k];
    const float4* vr4 = (const float4*)(vbase + (size_t)k*6912);
    float4 va = vr4[lane];
    accA.x += pk*va.x; accA.y += pk*va.y; accA.z += pk*va.z; accA.w += pk*va.w;
    float4 vb = vr4[64 + (lane & 7)];
    accB.x += pk*vb.x; accB.y += pk*vb.y; accB.z += pk*vb.z; accB.w += pk*vb.w;
  }
  float4* orow4 = (float4*)(attnO + (size_t)(n*P_+q)*E_ + (size_t)h*DH_);
  orow4[lane] = accA;
  if(lane < 8) orow4[64+lane] = accB;
}

// ---------------- obj1 = LN(obj0 + tproj) over E=2304 ----------------
__global__ __launch_bounds__(256) void k_add_ln2304(const float* __restrict__ obj0, const float* __restrict__ tp,
  const float* __restrict__ g, const float* __restrict__ b, float* __restrict__ out)
{
  __shared__ float red[8];
  int row = blockIdx.x;
  float v[9]; float s=0.f, q=0.f;
  #pragma unroll
  for(int j=0;j<9;j++){
    int e = threadIdx.x + j*256;
    float t = obj0[(size_t)row*E_ + e] + tp[(size_t)row*E_ + e];
    v[j]=t; s+=t; q+=t*t;
  }
  #pragma unroll
  for(int off=32; off; off>>=1){ s += __shfl_xor(s, off, 64); q += __shfl_xor(q, off, 64); }
  int wid = threadIdx.x>>6;
  if((threadIdx.x&63)==0){ red[wid]=s; red[4+wid]=q; }
  __syncthreads();
  s = red[0]+red[1]+red[2]+red[3]; q = red[4]+red[5]+red[6]+red[7];
  float mean = s*(1.f/2304.f);
  float rstd = rsqrtf(q*(1.f/2304.f) - mean*mean + 1e-5f);
  #pragma unroll
  for(int j=0;j<9;j++){
    int e = threadIdx.x + j*256;
    out[(size_t)row*E_ + e] = (v[j]-mean)*rstd*g[e] + b[e];
  }
}

// ---------------- obj_kernels output transpose ----------------
__global__ __launch_bounds__(256) void k_objk(const float* __restrict__ obj2, float* __restrict__ outk){
  int i = blockIdx.x*256 + threadIdx.x;
  if(i >= ROWS_*C_) return;
  int kk = i % 9; int t = i / 9; int c = t & 255; int np = t >> 8;
  outk[i] = obj2[((size_t)np*9 + kk)*C_ + c];
}

// ---------------- x pre-transpose to bf16: xT[n][c/8][h][w][8] ----------------
__global__ __launch_bounds__(256) void k_prep_x(const float* __restrict__ x, __bf16* __restrict__ xT){
  int i = blockIdx.x*256 + threadIdx.x;     // (n, g, h, w) flattened
  if(i >= N_*32*H_*W_) return;
  int w = i % W_; int t = i / W_;
  int h = t % H_; t /= H_;
  int g = t % 32; int n = t / 32;
  const float* xp = &x[((size_t)(n*C_ + g*8)*H_ + h)*W_ + w];
  bf16x8 v;
  #pragma unroll
  for(int u=0;u<8;u++) v[u] = (__bf16)xp[(size_t)u*HW_];
  *(bf16x8*)&xT[(size_t)i*8] = v;
}

// ---------------- kernel permute: kerP[nps][c0b][tap][oct][pl][8] from mfF(bf16) ----------------
__global__ __launch_bounds__(256) void k_permute_ker(const __bf16* __restrict__ mfFb, __bf16* __restrict__ kerP){
  int i = blockIdx.x*256 + threadIdx.x;   // bf16x8 index
  if(i >= 73728) return;                  // 4 nps * 8 c0b * 9 tap * 4 oct * 64 pl
  int pl = i & 63; int t = i >> 6;
  int oct = t & 3; t >>= 2;
  int tap = t % 9; t /= 9;
  int c0b = t & 7; int nps = t >> 3;
  int n = nps >> 1, ps = nps & 1;
  int p = ps*64 + pl;
  bf16x8 v;
  if(p < P_){
    v = *(const bf16x8*)&mfFb[((size_t)(n*P_+p)*9 + tap)*C_ + c0b*32 + oct*8];
  } else {
    #pragma unroll
    for(int u=0;u<8;u++) v[u] = (__bf16)0.f;
  }
  *(bf16x8*)&kerP[(size_t)i*8] = v;
}

// ---------------- dynamic conv via implicit-GEMM bf16 MFMA ----------------
// Register-staged double buffer: next c0-step's global loads issue right after
// the barrier and fly during the MFMA cluster; ds_writes after the next barrier.
__global__ __launch_bounds__(256) void k_conv_mfma(const __bf16* __restrict__ xT, const __bf16* __restrict__ kerP,
                                                   float* __restrict__ out){
  const int wt = blockIdx.x, ht = blockIdx.y, z = blockIdx.z;
  const int n = z >> 1, ps = z & 1;
  const int pbase = ps*64;
  const int NT = ps ? 3 : 4;
  const int tid = threadIdx.x;
  const int hi = tid >> 6;
  const int lane = tid & 63;
  const int col = lane & 15, quad = lane >> 4;
  const int w0 = wt*64, h0 = ht*4;

  __shared__ __bf16 xs[6][4][66][8];
  __shared__ __bf16 ks[9][4][64][8];
  __bf16* ksf = &ks[0][0][0][0];

  f32x4 acc[4][4] = {};

  int xoff[7];
  __bf16* xlds[7];
  #pragma unroll
  for(int j=0;j<7;j++){
    int i = tid + j*256;
    if(i < 1584){
      int oct = i/396; int rem = i - oct*396;
      int hy = rem/66, wx = rem - hy*66;
      int hh = h0 - 1 + hy, ww = w0 - 1 + wx;
      xlds[j] = &xs[hy][oct][wx][0];
      xoff[j] = (hh>=0 && hh<H_ && ww>=0 && ww<W_) ? (((n*32+oct)*H_ + hh)*W_ + ww)*8 : -1;
    } else { xlds[j] = nullptr; xoff[j] = -1; }
  }
  const __bf16* kbase = kerP + (size_t)(n*2+ps)*8*2304*8;

  bf16x8 xv[7], kv[9];
  bf16x8 zro;
  #pragma unroll
  for(int u=0;u<8;u++) zro[u] = (__bf16)0.f;
  #pragma unroll
  for(int j=0;j<7;j++) xv[j] = zro;
  #pragma unroll
  for(int j=0;j<7;j++)
    if(xoff[j] >= 0) xv[j] = *(const bf16x8*)&xT[xoff[j]];
  #pragma unroll
  for(int j=0;j<9;j++) kv[j] = *(const bf16x8*)&kbase[(size_t)(tid + j*256)*8];

  for(int s=0; s<8; s++){
    __syncthreads();
    #pragma unroll
    for(int j=0;j<7;j++)
      if(tid + j*256 < 1584) *(bf16x8*)xlds[j] = xv[j];
    #pragma unroll
    for(int j=0;j<9;j++) *(bf16x8*)&ksf[(size_t)(tid + j*256)*8] = kv[j];
    __syncthreads();
    if(s < 7){
      #pragma unroll
      for(int j=0;j<7;j++)
        if(xoff[j] >= 0) xv[j] = *(const bf16x8*)&xT[xoff[j] + (s+1)*786432];
      const __bf16* kb2 = kbase + (size_t)(s+1)*18432;
      #pragma unroll
      for(int j=0;j<9;j++) kv[j] = *(const bf16x8*)&kb2[(size_t)(tid + j*256)*8];
    }
    #pragma unroll
    for(int ky=0; ky<3; ky++){
      #pragma unroll
      for(int kx=0; kx<3; kx++){
        const int tap = ky*3 + kx;
        const int hy = hi + ky;
        bf16x8 b[4];
        #pragma unroll
        for(int t=0;t<4;t++) b[t] = *(const bf16x8*)&xs[hy][quad][t*16 + col + kx][0];
        #pragma unroll
        for(int pt=0; pt<4; pt++){
          if(pt < NT){
            bf16x8 a = *(const bf16x8*)&ks[tap][quad][pt*16 + col][0];
            #pragma unroll
            for(int t=0;t<4;t++)
              acc[pt][t] = __builtin_amdgcn_mfma_f32_16x16x32_bf16(a, b[t], acc[pt][t], 0, 0, 0);
          }
        }
      }
    }
  }
  const int h = h0 + hi;
  #pragma unroll
  for(int pt=0; pt<4; pt++){
    if(pt < NT){
      #pragma unroll
      for(int r=0;r<4;r++){
        int p = pbase + pt*16 + quad*4 + r;
        if(p < P_){
          float* op = &out[((size_t)(n*P_+p)*H_ + h)*W_ + w0 + col];
          #pragma unroll
          for(int t=0;t<4;t++) op[t*16] = acc[pt][t][r];
        }
      }
    }
  }
}

extern "C" void kernel_launch(void* const* d_in, const int* in_sizes, int n_in,
                              void* d_out, int out_size, void* d_ws, size_t ws_size,
                              hipStream_t stream)
{
  (void)in_sizes; (void)n_in; (void)out_size; (void)ws_size;
  const float* x          = (const float*)d_in[0];
  const float* prop       = (const float*)d_in[1];
  const float* mask_pred  = (const float*)d_in[2];
  const float* ku_dyn_w   = (const float*)d_in[3];
  const float* ku_dyn_b   = (const float*)d_in[4];
  const float* ku_in_w    = (const float*)d_in[5];
  const float* ku_in_b    = (const float*)d_in[6];
  const float* ku_ig_w    = (const float*)d_in[7];
  const float* ku_ig_b    = (const float*)d_in[8];
  const float* ku_ug_w    = (const float*)d_in[9];
  const float* ku_ug_b    = (const float*)d_in[10];
  const float* ku_nin_g   = (const float*)d_in[11];
  const float* ku_nin_b   = (const float*)d_in[12];
  const float* ku_nout_g  = (const float*)d_in[13];
  const float* ku_nout_b  = (const float*)d_in[14];
  const float* ku_inin_g  = (const float*)d_in[15];
  const float* ku_inin_b  = (const float*)d_in[16];
  const float* ku_inout_g = (const float*)d_in[17];
  const float* ku_inout_b = (const float*)d_in[18];
  const float* ku_fc_w    = (const float*)d_in[19];
  const float* ku_fc_b    = (const float*)d_in[20];
  const float* ku_fcn_g   = (const float*)d_in[21];
  const float* ku_fcn_b   = (const float*)d_in[22];
  const float* attn_in_w  = (const float*)d_in[23];
  const float* attn_in_b  = (const float*)d_in[24];
  const float* attn_out_w = (const float*)d_in[25];
  const float* attn_out_b = (const float*)d_in[26];
  const float* attn_ln_g  = (const float*)d_in[27];
  const float* attn_ln_b  = (const float*)d_in[28];
  const float* ffn_w1     = (const float*)d_in[29];
  const float* ffn_b1     = (const float*)d_in[30];
  const float* ffn_w2     = (const float*)d_in[31];
  const float* ffn_b2     = (const float*)d_in[32];
  const float* ffn_ln_g   = (const float*)d_in[33];
  const float* ffn_ln_b   = (const float*)d_in[34];
  const float* mask_fc_ws = (const float*)d_in[35];
  const float* mask_fc_ln_g = (const float*)d_in[36];
  const float* mask_fc_ln_b = (const float*)d_in[37];
  const float* fc_mask_w  = (const float*)d_in[38];
  const float* fc_mask_b  = (const float*)d_in[39];

  float* ws = (float*)d_ws;
  float* sig     = ws;
  float* hbuf    = ws;
  float* skA     = ws;                // split-K scratch: attn_in S=6 needs 8.29M floats [0..8294400)
  float* kT      = ws;                // attn K-transpose (589824 floats) — lives after redk, dead before attn_out GEMM
  float* partial = ws + 4915200;      // dead after k_xfeat2
  float* skB     = ws + 4915200;      // split-K scratch (ffn2)
  float* attnO   = ws + 4915200 + 1382400;
  float* tproj   = ws + 4915200 + 1843200;
  float* tmp     = ws + 4915200 + 2304000;  // pre-LN gemm output (1800x256)
  // qkv at [8294400..9676800) so attn_in's 6 partial slabs fit below it.
  float* qkv     = ws + 8294400;
  float* xfeat   = ws + 9830400;
  float* params  = xfeat + 51200;
  float* pf      = params + 102400;
  float* inp     = pf + 460800;
  float* gate    = inp + 921600;
  float* ig      = gate + 460800;
  float* ug      = ig + 460800;
  float* feat    = ug + 460800;
  float* obj0    = feat + 460800;
  float* obj1    = obj0 + 460800;
  float* obj2    = obj1 + 460800;
  float* mf1     = obj2 + 460800;
  float* mf2     = mf1 + 460800;
  float* mfF     = mf2 + 460800;
  // xT (bf16) at ws[0..6291456 float slots): sig/hbuf/skA/skB dead by k_prep_x.
  __bf16* xT = (__bf16*)ws;
  // kerP (bf16, 589824 elems = 294912 float slots) in dead tproj region (cap 460800).
  __bf16* kerP = (__bf16*)(ws + 6758400);

  float* out_masks = (float*)d_out;
  float* out_kern  = out_masks + (size_t)N_*P_*HW_;

  k_softmax<<<192, 256, 0, stream>>>(mask_pred, sig);
  k_permute_pf<<<1800, 256, 0, stream>>>(prop, pf);
  k_xfeat1m<<<dim3(2,XKC_,2), 256, 0, stream>>>(sig, x, partial);
  k_xfeat2<<<200, 256, 0, stream>>>(partial, xfeat);
  k_gemm_mfma<<<dim3(4,4),   256, 0, stream>>>(xfeat, ku_dyn_w, ku_dyn_b, params, 200, 512, 256, 0);
  k_gemm_mfma<<<dim3(4,29),  256, 0, stream>>>(pf, ku_in_w, ku_in_b, inp, 1800, 512, 256, 0);
  k_gate<<<1800, 256, 0, stream>>>(inp, params, gate);
  k_gemm_mfma<<<dim3(2,29),  256, 0, stream>>>(gate, ku_ig_w, ku_ig_b, tmp, 1800, 256, 256, 0);
  k_ln256<<<450, 256, 0, stream>>>(tmp, nullptr, ku_inin_g, ku_inin_b, ig, 1800, 2);
  k_gemm_mfma<<<dim3(2,29),  256, 0, stream>>>(gate, ku_ug_w, ku_ug_b, tmp, 1800, 256, 256, 0);
  k_ln256<<<450, 256, 0, stream>>>(tmp, nullptr, ku_nin_g, ku_nin_b, ug, 1800, 2);
  k_combine<<<1800, 256, 0, stream>>>(params, inp, ug, ig, ku_nout_g, ku_nout_b, ku_inout_g, ku_inout_b, feat);
  k_gemm_mfma<<<dim3(2,29),  256, 0, stream>>>(feat, ku_fc_w, ku_fc_b, tmp, 1800, 256, 256, 0);
  k_ln256<<<450, 256, 0, stream>>>(tmp, nullptr, ku_fcn_g, ku_fcn_b, obj0, 1800, 1);
  // attn_in: BM=256/BN=64, split-K x6 (KC=384): 648 blocks, weight read by exactly one block
  k_gemm_skM256<<<dim3(108,6), 256, 0, stream>>>(obj0, attn_in_w, skA, 200, 6912, 2304, 384);
  k_redk<<<1350, 256, 0, stream>>>(skA, attn_in_b, qkv, 200, 6912, 6);
  // attention: K transpose then barrier-free wave-per-(q,h)
  k_prep_kT<<<1152, 256, 0, stream>>>(qkv, (float2*)kT);
  k_attn3<<<dim3(25,8,2), 256, 0, stream>>>(qkv, (const float2*)kT, attnO);
  // attn_out: BM=256/BN=64, split-K x9 (KC=256): 324 blocks
  k_gemm_skM256<<<dim3(36,9), 256, 0, stream>>>(attnO, attn_out_w, skA, 200, 2304, 2304, 256);
  k_redk<<<450, 256, 0, stream>>>(skA, attn_out_b, tproj, 200, 2304, 9);
  k_add_ln2304<<<200, 256, 0, stream>>>(obj0, tproj, attn_ln_g, attn_ln_b, obj1);
  k_gemm_mfma<<<dim3(16,29), 256, 0, stream>>>(obj1, ffn_w1, ffn_b1, hbuf, 1800, 2048, 256, 1);
  // ffn2: split-K x4 (K=2048 -> 4x512); scratch in dead region above hbuf
  k_gemm_splitk<<<232, 256, 0, stream>>>(hbuf, ffn_w2, skB, 1800, 256, 2048, 512, 2, 29);
  k_redk<<<450, 256, 0, stream>>>(skB, ffn_b2, tmp, 1800, 256, 4);
  k_ln256<<<450, 256, 0, stream>>>(tmp, obj1, ffn_ln_g, ffn_ln_b, obj2, 1800, 0);
  k_gemm_mfma<<<dim3(2,29),  256, 0, stream>>>(obj2, mask_fc_ws,          nullptr, tmp, 1800, 256, 256, 0);
  k_ln256<<<450, 256, 0, stream>>>(tmp, nullptr, mask_fc_ln_g,       mask_fc_ln_b,       mf1, 1800, 1);
  k_gemm_mfma<<<dim3(2,29),  256, 0, stream>>>(mf1,  mask_fc_ws + 65536,  nullptr, tmp, 1800, 256, 256, 0);
  k_ln256<<<450, 256, 0, stream>>>(tmp, nullptr, mask_fc_ln_g + 256, mask_fc_ln_b + 256, mf2, 1800, 1);
  k_gemm_mfma<<<dim3(2,29),  256, 0, stream>>>(mf2,  mask_fc_ws + 131072, nullptr, tmp, 1800, 256, 256, 0);
  k_ln256<<<450, 256, 0, stream>>>(tmp, nullptr, mask_fc_ln_g + 512, mask_fc_ln_b + 512, mf1, 1800, 1);
  // final kernel GEMM stores bf16 directly (identical numerics: same RNE convert)
  k_gemm_mfma<<<dim3(2,29),  256, 0, stream>>>(mf1, fc_mask_w, fc_mask_b, mfF, 1800, 256, 256, 3);
  k_objk<<<1800, 256, 0, stream>>>(obj2, out_kern);
  k_permute_ker<<<288, 256, 0, stream>>>((const __bf16*)mfF, kerP);
  k_prep_x<<<6144, 256, 0, stream>>>(x, xT);
  k_conv_mfma<<<dim3(3,32,4), 256, 0, stream>>>(xT, kerP, out_masks);
}

// Round 9
// 677.950 us; speedup vs baseline: 1.1258x; 1.0283x over previous
//
#include <hip/hip_runtime.h>
#include <hip/hip_bf16.h>

#define N_ 2
#define P_ 100
#define C_ 256
#define H_ 128
#define W_ 192
#define HW_ 24576
#define KK_ 9
#define E_ 2304
#define NH_ 8
#define DH_ 288
#define FFN_ 2048
#define NP_ 200
#define ROWS_ 1800   // NP_*KK_
#define XKC_ 64      // xfeat split-K chunks

typedef __attribute__((ext_vector_type(8))) __bf16 bf16x8;
typedef __attribute__((ext_vector_type(4))) float f32x4;

// ---------------- softmax over P axis of mask_preds ----------------
__global__ __launch_bounds__(256) void k_softmax(const float* __restrict__ mp, float* __restrict__ sig){
  int idx = blockIdx.x*256 + threadIdx.x;
  if(idx >= N_*HW_) return;
  int n = idx / HW_, hw = idx - n*HW_;
  const float* base = mp + (size_t)n*P_*HW_ + hw;
  float m = -1e30f;
  for(int p=0;p<P_;p++) m = fmaxf(m, base[(size_t)p*HW_]);
  float s = 0.f;
  for(int p=0;p<P_;p++) s += __expf(base[(size_t)p*HW_] - m);
  float inv = 1.f/s;
  float* ob = sig + (size_t)n*P_*HW_ + hw;
  for(int p=0;p<P_;p++) ob[(size_t)p*HW_] = __expf(base[(size_t)p*HW_] - m)*inv;
}

// ---------------- pf permute: pf[np][kk][c] = prop[n][p][c*9+kk] ----------------
__global__ __launch_bounds__(256) void k_permute_pf(const float* __restrict__ prop, float* __restrict__ pf){
  int i = blockIdx.x*256 + threadIdx.x;
  if(i >= ROWS_*C_) return;
  int c = i & 255;
  int r = i >> 8;            // np*9+kk
  int kk = r % 9, np = r / 9;
  pf[i] = prop[(size_t)np*E_ + c*KK_ + kk];
}

// ---------------- x_feat stage 1: bf16 MFMA split-K ----------------
__global__ __launch_bounds__(256) void k_xfeat1m(const float* __restrict__ sig, const float* __restrict__ x,
                                                 float* __restrict__ partial){
  const int ct = blockIdx.x, kb = blockIdx.y, n = blockIdx.z;
  const int hw0 = kb*384;
  const int tid = threadIdx.x;
  const int wid = tid >> 6, lane = tid & 63;
  const int col = lane & 15, quad = lane >> 4;
  const int wm = wid & 1, wn = wid >> 1;
  const int MT = wm ? 3 : 4;
  __shared__ __bf16 As[112][72];
  __shared__ __bf16 Bs[128][72];
  f32x4 acc[4][4] = {};
  for(int k0=0; k0<384; k0+=64){
    __syncthreads();
    for(int i=tid; i<896; i+=256){
      int p = i >> 3, kg = i & 7;
      bf16x8 v;
      if(p < P_){
        const float* sp = &sig[((size_t)n*P_ + p)*HW_ + hw0 + k0 + kg*8];
        const float4 f0 = *(const float4*)sp;
        const float4 f1 = *(const float4*)(sp+4);
        v[0]=(__bf16)f0.x; v[1]=(__bf16)f0.y; v[2]=(__bf16)f0.z; v[3]=(__bf16)f0.w;
        v[4]=(__bf16)f1.x; v[5]=(__bf16)f1.y; v[6]=(__bf16)f1.z; v[7]=(__bf16)f1.w;
      } else {
        #pragma unroll
        for(int u=0;u<8;u++) v[u] = (__bf16)0.f;
      }
      *(bf16x8*)&As[p][kg*8] = v;
    }
    for(int i=tid; i<1024; i+=256){
      int c = i >> 3, kg = i & 7;
      const float* xp = &x[((size_t)n*C_ + ct*128 + c)*HW_ + hw0 + k0 + kg*8];
      const float4 f0 = *(const float4*)xp;
      const float4 f1 = *(const float4*)(xp+4);
      bf16x8 v;
      v[0]=(__bf16)f0.x; v[1]=(__bf16)f0.y; v[2]=(__bf16)f0.z; v[3]=(__bf16)f0.w;
      v[4]=(__bf16)f1.x; v[5]=(__bf16)f1.y; v[6]=(__bf16)f1.z; v[7]=(__bf16)f1.w;
      *(bf16x8*)&Bs[c][kg*8] = v;
    }
    __syncthreads();
    #pragma unroll
    for(int ks=0; ks<2; ks++){
      bf16x8 b[4];
      #pragma unroll
      for(int t=0;t<4;t++) b[t] = *(const bf16x8*)&Bs[(wn*4+t)*16 + col][ks*32 + quad*8];
      #pragma unroll
      for(int mt=0; mt<4; mt++){
        if(mt < MT){
          bf16x8 a = *(const bf16x8*)&As[(wm*4+mt)*16 + col][ks*32 + quad*8];
          #pragma unroll
          for(int t=0;t<4;t++)
            acc[mt][t] = __builtin_amdgcn_mfma_f32_16x16x32_bf16(a, b[t], acc[mt][t], 0, 0, 0);
        }
      }
    }
  }
  #pragma unroll
  for(int mt=0; mt<4; mt++){
    if(mt < MT){
      #pragma unroll
      for(int r=0;r<4;r++){
        int p = (wm*4+mt)*16 + quad*4 + r;
        if(p < P_){
          float* op = &partial[(((size_t)n*XKC_ + kb)*P_ + p)*C_ + ct*128 + wn*64 + col];
          #pragma unroll
          for(int t=0;t<4;t++) op[t*16] = acc[mt][t][r];
        }
      }
    }
  }
}

// ---------------- x_feat stage 2: reduce over XKC_ chunks ----------------
__global__ __launch_bounds__(256) void k_xfeat2(const float* __restrict__ partial, float* __restrict__ xfeat){
  int np = blockIdx.x;
  int n = np / P_, p = np - n*P_;
  int c = threadIdx.x;
  float s = 0.f;
  for(int kb=0;kb<XKC_;kb++) s += partial[(((size_t)n*XKC_ + kb)*P_ + p)*C_ + c];
  xfeat[(size_t)np*C_ + c] = s;
}

// ---------------- generic bf16 MFMA GEMM: out = act(A @ W^T + bias) ----------------
// BM=64, BN=128, BK=64. act: 0 none, 1 relu, 3 store-bf16.
__global__ __launch_bounds__(256) void k_gemm_mfma(const float* __restrict__ A, const float* __restrict__ Wt,
    const float* __restrict__ bias, float* __restrict__ out, int M, int N, int K, int act)
{
  const int n0 = blockIdx.x*128, m0 = blockIdx.y*64;
  const int tid = threadIdx.x;
  const int wid = tid >> 6, lane = tid & 63;
  const int col = lane & 15, quad = lane >> 4;
  const int wm = wid & 1, wn = wid >> 1;
  __shared__ __bf16 As[64][72];
  __shared__ __bf16 Bs[128][72];
  f32x4 acc[2][4] = {};
  for(int k0=0; k0<K; k0+=64){
    __syncthreads();
    for(int i=tid; i<512; i+=256){
      int r = i >> 3, kg = i & 7;
      int m = m0 + r;
      bf16x8 v;
      if(m < M){
        const float* ap = &A[(size_t)m*K + k0 + kg*8];
        const float4 f0 = *(const float4*)ap;
        const float4 f1 = *(const float4*)(ap+4);
        v[0]=(__bf16)f0.x; v[1]=(__bf16)f0.y; v[2]=(__bf16)f0.z; v[3]=(__bf16)f0.w;
        v[4]=(__bf16)f1.x; v[5]=(__bf16)f1.y; v[6]=(__bf16)f1.z; v[7]=(__bf16)f1.w;
      } else {
        #pragma unroll
        for(int u=0;u<8;u++) v[u] = (__bf16)0.f;
      }
      *(bf16x8*)&As[r][kg*8] = v;
    }
    for(int i=tid; i<1024; i+=256){
      int r = i >> 3, kg = i & 7;
      const float* wp = &Wt[(size_t)(n0 + r)*K + k0 + kg*8];
      const float4 f0 = *(const float4*)wp;
      const float4 f1 = *(const float4*)(wp+4);
      bf16x8 v;
      v[0]=(__bf16)f0.x; v[1]=(__bf16)f0.y; v[2]=(__bf16)f0.z; v[3]=(__bf16)f0.w;
      v[4]=(__bf16)f1.x; v[5]=(__bf16)f1.y; v[6]=(__bf16)f1.z; v[7]=(__bf16)f1.w;
      *(bf16x8*)&Bs[r][kg*8] = v;
    }
    __syncthreads();
    #pragma unroll
    for(int ks=0; ks<2; ks++){
      bf16x8 b[4], a[2];
      #pragma unroll
      for(int t=0;t<4;t++) b[t] = *(const bf16x8*)&Bs[(wn*4+t)*16 + col][ks*32 + quad*8];
      #pragma unroll
      for(int mt=0;mt<2;mt++) a[mt] = *(const bf16x8*)&As[(wm*2+mt)*16 + col][ks*32 + quad*8];
      #pragma unroll
      for(int mt=0;mt<2;mt++)
        #pragma unroll
        for(int t=0;t<4;t++)
          acc[mt][t] = __builtin_amdgcn_mfma_f32_16x16x32_bf16(a[mt], b[t], acc[mt][t], 0, 0, 0);
    }
  }
  #pragma unroll
  for(int mt=0;mt<2;mt++){
    #pragma unroll
    for(int r=0;r<4;r++){
      int m = m0 + (wm*2+mt)*16 + quad*4 + r;
      if(m < M){
        #pragma unroll
        for(int t=0;t<4;t++){
          int n = n0 + (wn*4+t)*16 + col;
          float v = acc[mt][t][r];
          if(bias) v += bias[n];
          if(act == 1) v = fmaxf(v, 0.f);
          if(act == 3) ((__bf16*)out)[(size_t)m*N + n] = (__bf16)v;
          else out[(size_t)m*N + n] = v;
        }
      }
    }
  }
}

// ---------------- full-M split-K GEMM: BM=256 x BN=64, register-staged dbuf ----------------
// Weight element -> exactly one block (dedup) + T14 async-STAGE: next K-step's
// fp32 tiles prefetch into registers during the MFMA cluster (the R6 conv fix).
// Staging algebra is step-invariant: kg=tid&7, rows=tid>>3+32j.
__global__ __launch_bounds__(256) void k_gemm_skM256(const float* __restrict__ A, const float* __restrict__ Wt,
    float* __restrict__ part, int M, int N, int K, int KC)
{
  const int n0 = blockIdx.x*64;
  const int kz = blockIdx.y*KC;
  const int tid = threadIdx.x;
  const int wid = tid >> 6, lane = tid & 63;
  const int col = lane & 15, quad = lane >> 4;
  const int wm = wid & 1, wn = wid >> 1;   // wave tile: 128m x 32n
  const int rbase = tid >> 3, kg8 = (tid & 7)*8;
  const int NS = KC/64;
  __shared__ __bf16 As[256][72];
  __shared__ __bf16 Bs[64][72];
  f32x4 acc[8][2] = {};

  float4 fa0[8], fa1[8], fb0[2], fb1[2];
  const float4 z4 = {0,0,0,0};
  // prologue: load step 0
  #pragma unroll
  for(int j=0;j<8;j++){
    int r = rbase + j*32;
    if(r < M){
      const float* ap = &A[(size_t)r*K + kz + kg8];
      fa0[j] = *(const float4*)ap; fa1[j] = *(const float4*)(ap+4);
    } else { fa0[j] = z4; fa1[j] = z4; }
  }
  #pragma unroll
  for(int j=0;j<2;j++){
    const float* wp = &Wt[(size_t)(n0 + rbase + j*32)*K + kz + kg8];
    fb0[j] = *(const float4*)wp; fb1[j] = *(const float4*)(wp+4);
  }

  for(int s=0; s<NS; s++){
    __syncthreads();                 // prior step's LDS consumers done
    #pragma unroll
    for(int j=0;j<8;j++){
      bf16x8 v;
      v[0]=(__bf16)fa0[j].x; v[1]=(__bf16)fa0[j].y; v[2]=(__bf16)fa0[j].z; v[3]=(__bf16)fa0[j].w;
      v[4]=(__bf16)fa1[j].x; v[5]=(__bf16)fa1[j].y; v[6]=(__bf16)fa1[j].z; v[7]=(__bf16)fa1[j].w;
      *(bf16x8*)&As[rbase + j*32][kg8] = v;
    }
    #pragma unroll
    for(int j=0;j<2;j++){
      bf16x8 v;
      v[0]=(__bf16)fb0[j].x; v[1]=(__bf16)fb0[j].y; v[2]=(__bf16)fb0[j].z; v[3]=(__bf16)fb0[j].w;
      v[4]=(__bf16)fb1[j].x; v[5]=(__bf16)fb1[j].y; v[6]=(__bf16)fb1[j].z; v[7]=(__bf16)fb1[j].w;
      *(bf16x8*)&Bs[rbase + j*32][kg8] = v;
    }
    __syncthreads();                 // tiles visible
    if(s < NS-1){                    // issue NEXT step's loads (fly during MFMAs)
      int k0 = kz + (s+1)*64;
      #pragma unroll
      for(int j=0;j<8;j++){
        int r = rbase + j*32;
        if(r < M){
          const float* ap = &A[(size_t)r*K + k0 + kg8];
          fa0[j] = *(const float4*)ap; fa1[j] = *(const float4*)(ap+4);
        }
      }
      #pragma unroll
      for(int j=0;j<2;j++){
        const float* wp = &Wt[(size_t)(n0 + rbase + j*32)*K + k0 + kg8];
        fb0[j] = *(const float4*)wp; fb1[j] = *(const float4*)(wp+4);
      }
    }
    #pragma unroll
    for(int ks=0; ks<2; ks++){
      bf16x8 b[2];
      #pragma unroll
      for(int t=0;t<2;t++) b[t] = *(const bf16x8*)&Bs[(wn*2+t)*16 + col][ks*32 + quad*8];
      #pragma unroll
      for(int mt=0;mt<8;mt++){
        bf16x8 a = *(const bf16x8*)&As[(wm*8+mt)*16 + col][ks*32 + quad*8];
        #pragma unroll
        for(int t=0;t<2;t++)
          acc[mt][t] = __builtin_amdgcn_mfma_f32_16x16x32_bf16(a, b[t], acc[mt][t], 0, 0, 0);
      }
    }
  }
  float* pbase = part + (size_t)blockIdx.y*M*N;
  #pragma unroll
  for(int mt=0;mt<8;mt++){
    #pragma unroll
    for(int r=0;r<4;r++){
      int m = (wm*8+mt)*16 + quad*4 + r;
      if(m < M){
        #pragma unroll
        for(int t=0;t<2;t++){
          int n = n0 + (wn*2+t)*16 + col;
          pbase[(size_t)m*N + n] = acc[mt][t][r];
        }
      }
    }
  }
}

// ---------------- split-K bf16 MFMA GEMM, XCD-grouped 1D grid (ffn2) ----------------
__global__ __launch_bounds__(256) void k_gemm_splitk(const float* __restrict__ A, const float* __restrict__ Wt,
    float* __restrict__ part, int M, int N, int K, int KC, int PX, int MY)
{
  const int wg = blockIdx.x;
  const int xcd = wg & 7, slot = wg >> 3;
  const int mb = slot % MY, pg = slot / MY;
  const int panel = xcd + 8*pg;
  const int PZ = K / KC;
  if(panel >= PX*PZ) return;
  const int px = panel % PX, pz = panel / PX;
  const int n0 = px*128, m0 = mb*64;
  const int kz = pz*KC;
  const int tid = threadIdx.x;
  const int wid = tid >> 6, lane = tid & 63;
  const int col = lane & 15, quad = lane >> 4;
  const int wm = wid & 1, wn = wid >> 1;
  __shared__ __bf16 As[64][72];
  __shared__ __bf16 Bs[128][72];
  f32x4 acc[2][4] = {};
  for(int k0=kz; k0<kz+KC; k0+=64){
    __syncthreads();
    for(int i=tid; i<512; i+=256){
      int r = i >> 3, kg = i & 7;
      int m = m0 + r;
      bf16x8 v;
      if(m < M){
        const float* ap = &A[(size_t)m*K + k0 + kg*8];
        const float4 f0 = *(const float4*)ap;
        const float4 f1 = *(const float4*)(ap+4);
        v[0]=(__bf16)f0.x; v[1]=(__bf16)f0.y; v[2]=(__bf16)f0.z; v[3]=(__bf16)f0.w;
        v[4]=(__bf16)f1.x; v[5]=(__bf16)f1.y; v[6]=(__bf16)f1.z; v[7]=(__bf16)f1.w;
      } else {
        #pragma unroll
        for(int u=0;u<8;u++) v[u] = (__bf16)0.f;
      }
      *(bf16x8*)&As[r][kg*8] = v;
    }
    for(int i=tid; i<1024; i+=256){
      int r = i >> 3, kg = i & 7;
      const float* wp = &Wt[(size_t)(n0 + r)*K + k0 + kg*8];
      const float4 f0 = *(const float4*)wp;
      const float4 f1 = *(const float4*)(wp+4);
      bf16x8 v;
      v[0]=(__bf16)f0.x; v[1]=(__bf16)f0.y; v[2]=(__bf16)f0.z; v[3]=(__bf16)f0.w;
      v[4]=(__bf16)f1.x; v[5]=(__bf16)f1.y; v[6]=(__bf16)f1.z; v[7]=(__bf16)f1.w;
      *(bf16x8*)&Bs[r][kg*8] = v;
    }
    __syncthreads();
    #pragma unroll
    for(int ks=0; ks<2; ks++){
      bf16x8 b[4], a[2];
      #pragma unroll
      for(int t=0;t<4;t++) b[t] = *(const bf16x8*)&Bs[(wn*4+t)*16 + col][ks*32 + quad*8];
      #pragma unroll
      for(int mt=0;mt<2;mt++) a[mt] = *(const bf16x8*)&As[(wm*2+mt)*16 + col][ks*32 + quad*8];
      #pragma unroll
      for(int mt=0;mt<2;mt++)
        #pragma unroll
        for(int t=0;t<4;t++)
          acc[mt][t] = __builtin_amdgcn_mfma_f32_16x16x32_bf16(a[mt], b[t], acc[mt][t], 0, 0, 0);
    }
  }
  float* pbase = part + (size_t)pz*M*N;
  #pragma unroll
  for(int mt=0;mt<2;mt++){
    #pragma unroll
    for(int r=0;r<4;r++){
      int m = m0 + (wm*2+mt)*16 + quad*4 + r;
      if(m < M){
        #pragma unroll
        for(int t=0;t<4;t++){
          int n = n0 + (wn*4+t)*16 + col;
          pbase[(size_t)m*N + n] = acc[mt][t][r];
        }
      }
    }
  }
}

// ---------------- split-K reduce: out = sum_z part[z] + bias ----------------
__global__ __launch_bounds__(256) void k_redk(const float* __restrict__ part, const float* __restrict__ bias,
    float* __restrict__ out, int M, int N, int S)
{
  size_t i4 = ((size_t)blockIdx.x*256 + threadIdx.x)*4;
  size_t MN = (size_t)M*N;
  if(i4 >= MN) return;
  float4 s = *(const float4*)&part[i4];
  for(int z=1; z<S; z++){
    const float4 p = *(const float4*)&part[(size_t)z*MN + i4];
    s.x+=p.x; s.y+=p.y; s.z+=p.z; s.w+=p.w;
  }
  if(bias){
    int n = (int)(i4 % (size_t)N);
    const float4 b = *(const float4*)&bias[n];
    s.x+=b.x; s.y+=b.y; s.z+=b.z; s.w+=b.w;
  }
  *(float4*)&out[i4] = s;
}

// ---------------- row LayerNorm over C=256 (+residual, +act) ----------------
__global__ __launch_bounds__(256) void k_ln256(const float* __restrict__ in, const float* __restrict__ res,
    const float* __restrict__ g, const float* __restrict__ b, float* __restrict__ out, int M, int act)
{
  int row = blockIdx.x*4 + (threadIdx.x >> 6);
  int lane = threadIdx.x & 63;
  if(row >= M) return;
  float4 v = *(const float4*)&in[(size_t)row*C_ + lane*4];
  if(res){
    const float4 rv = *(const float4*)&res[(size_t)row*C_ + lane*4];
    v.x += rv.x; v.y += rv.y; v.z += rv.z; v.w += rv.w;
  }
  float s = v.x + v.y + v.z + v.w;
  float q = v.x*v.x + v.y*v.y + v.z*v.z + v.w*v.w;
  #pragma unroll
  for(int off=32; off; off>>=1){ s += __shfl_xor(s, off, 64); q += __shfl_xor(q, off, 64); }
  float mean = s*(1.f/256.f);
  float rstd = rsqrtf(q*(1.f/256.f) - mean*mean + 1e-5f);
  const float4 gv = *(const float4*)&g[lane*4];
  const float4 bv = *(const float4*)&b[lane*4];
  float o[4] = {(v.x-mean)*rstd*gv.x + bv.x, (v.y-mean)*rstd*gv.y + bv.y,
                (v.z-mean)*rstd*gv.z + bv.z, (v.w-mean)*rstd*gv.w + bv.w};
  #pragma unroll
  for(int j=0;j<4;j++){
    if(act==1) o[j] = fmaxf(o[j], 0.f);
    else if(act==2) o[j] = 1.f/(1.f + __expf(-o[j]));
  }
  float4 ov = {o[0],o[1],o[2],o[3]};
  *(float4*)&out[(size_t)row*C_ + lane*4] = ov;
}

// ---------------- gate = i_in * p_in ----------------
__global__ __launch_bounds__(256) void k_gate(const float* __restrict__ inp, const float* __restrict__ params,
                                              float* __restrict__ gate){
  int i = blockIdx.x*256 + threadIdx.x;
  if(i >= ROWS_*C_) return;
  int c = i & 255, r = i >> 8;
  int np = r / 9;
  gate[i] = inp[(size_t)r*512 + c] * params[(size_t)np*512 + c];
}

// ---------------- block LN helper ----------------
__device__ __forceinline__ void block_stats(float v, float* red, int slot, float& mean, float& rstd){
  float s = v, q = v*v;
  #pragma unroll
  for(int off=32; off; off>>=1){ s += __shfl_xor(s, off, 64); q += __shfl_xor(q, off, 64); }
  int wid = threadIdx.x >> 6;
  if((threadIdx.x & 63) == 0){ red[slot + wid] = s; red[slot + 4 + wid] = q; }
  __syncthreads();
  s = red[slot+0]+red[slot+1]+red[slot+2]+red[slot+3];
  q = red[slot+4]+red[slot+5]+red[slot+6]+red[slot+7];
  mean = s*(1.f/256.f);
  rstd = rsqrtf(q*(1.f/256.f) - mean*mean + 1e-5f);
}

// ---------------- feat = ug * LN(p_out) + ig * LN(i_out) ----------------
__global__ __launch_bounds__(256) void k_combine(const float* __restrict__ params, const float* __restrict__ inp,
  const float* __restrict__ ug, const float* __restrict__ ig,
  const float* __restrict__ nout_g, const float* __restrict__ nout_b,
  const float* __restrict__ inout_g, const float* __restrict__ inout_b,
  float* __restrict__ feat)
{
  __shared__ float red[16];
  int r = blockIdx.x;           // np*9+kk
  int np = r / 9;
  int c = threadIdx.x;
  float pv = params[(size_t)np*512 + 256 + c];
  float mean, rstd;
  block_stats(pv, red, 0, mean, rstd);
  float pn = (pv - mean)*rstd*nout_g[c] + nout_b[c];
  float iv = inp[(size_t)r*512 + 256 + c];
  float mean2, rstd2;
  block_stats(iv, red, 8, mean2, rstd2);
  float iw = (iv - mean2)*rstd2*inout_g[c] + inout_b[c];
  size_t o = (size_t)r*C_ + c;
  feat[o] = ug[o]*pn + ig[o]*iw;
}

// ---------------- K transpose for attention: kT2[((n*8+h)*288+d)*64 + l] = (K[2l][d], K[2l+1][d]) ----------------
__global__ __launch_bounds__(256) void k_prep_kT(const float* __restrict__ qkv, float2* __restrict__ kT2){
  int i = blockIdx.x*256 + threadIdx.x;
  if(i >= N_*NH_*DH_*64) return;
  int l = i & 63; int t = i >> 6;
  int d = t % DH_; t /= DH_;
  int h = t & 7, n = t >> 3;
  float2 v = {0.f, 0.f};
  if(l < 50){
    size_t base = (size_t)(n*P_ + 2*l)*6912 + E_ + (size_t)h*DH_ + d;
    v.x = qkv[base];
    v.y = qkv[base + 6912];
  }
  kT2[i] = v;
}

// ---------------- attention v3: one wave per (q,h), zero staging barriers ----------------
__global__ __launch_bounds__(256) void k_attn3(const float* __restrict__ qkv, const float2* __restrict__ kT2,
                                               float* __restrict__ attnO){
  const int qb = blockIdx.x, h = blockIdx.y, n = blockIdx.z;
  const int w = threadIdx.x >> 6, lane = threadIdx.x & 63;
  const int q = qb*4 + w;
  __shared__ float Qs[4][288];
  __shared__ float Ps[4][128];
  const float scale = 0.05892556509887896f;   // 1/sqrt(288)
  {
    const float4* qrow4 = (const float4*)(qkv + (size_t)(n*P_ + q)*6912 + (size_t)h*DH_);
    float4* qs4 = (float4*)&Qs[w][0];
    float4 a = qrow4[lane];
    a.x*=scale; a.y*=scale; a.z*=scale; a.w*=scale;
    qs4[lane] = a;
    if(lane < 8){
      float4 b = qrow4[64+lane];
      b.x*=scale; b.y*=scale; b.z*=scale; b.w*=scale;
      qs4[64+lane] = b;
    }
  }
  __syncthreads();
  const float2* kcol = kT2 + (size_t)(n*NH_ + h)*DH_*64;
  float s0 = 0.f, s1 = 0.f;
  #pragma unroll 8
  for(int d=0; d<DH_; d++){
    float qv = Qs[w][d];
    float2 kk = kcol[d*64 + lane];
    s0 += qv*kk.x;
    s1 += qv*kk.y;
  }
  bool valid = lane < 50;
  float m = valid ? fmaxf(s0, s1) : -1e30f;
  #pragma unroll
  for(int off=32; off; off>>=1) m = fmaxf(m, __shfl_xor(m, off, 64));
  float e0 = valid ? __expf(s0 - m) : 0.f;
  float e1 = valid ? __expf(s1 - m) : 0.f;
  float sum = e0 + e1;
  #pragma unroll
  for(int off=32; off; off>>=1) sum += __shfl_xor(sum, off, 64);
  float inv = 1.f/sum;
  if(valid){
    Ps[w][2*lane]   = e0*inv;
    Ps[w][2*lane+1] = e1*inv;
  }
  __syncthreads();
  float4 accA = {0,0,0,0}, accB = {0,0,0,0};
  const float* vbase = qkv + (size_t)n*P_*6912 + 2*E_ + (size_t)h*DH_;
  #pragma unroll 4
  for(int k=0; k<P_; k++){
    float pk = Ps[w][k];
    const float4* vr4 = (const float4*)(vbase + (size_t)k*6912);
    float4 va = vr4[lane];
    accA.x += pk*va.x; accA.y += pk*va.y; accA.z += pk*va.z; accA.w += pk*va.w;
    float4 vb = vr4[64 + (lane & 7)];
    accB.x += pk*vb.x; accB.y += pk*vb.y; accB.z += pk*vb.z; accB.w += pk*vb.w;
  }
  float4* orow4 = (float4*)(attnO + (size_t)(n*P_+q)*E_ + (size_t)h*DH_);
  orow4[lane] = accA;
  if(lane < 8) orow4[64+lane] = accB;
}

// ---------------- obj1 = LN(obj0 + tproj) over E=2304 ----------------
__global__ __launch_bounds__(256) void k_add_ln2304(const float* __restrict__ obj0, const float* __restrict__ tp,
  const float* __restrict__ g, const float* __restrict__ b, float* __restrict__ out)
{
  __shared__ float red[8];
  int row = blockIdx.x;
  float v[9]; float s=0.f, q=0.f;
  #pragma unroll
  for(int j=0;j<9;j++){
    int e = threadIdx.x + j*256;
    float t = obj0[(size_t)row*E_ + e] + tp[(size_t)row*E_ + e];
    v[j]=t; s+=t; q+=t*t;
  }
  #pragma unroll
  for(int off=32; off; off>>=1){ s += __shfl_xor(s, off, 64); q += __shfl_xor(q, off, 64); }
  int wid = threadIdx.x>>6;
  if((threadIdx.x&63)==0){ red[wid]=s; red[4+wid]=q; }
  __syncthreads();
  s = red[0]+red[1]+red[2]+red[3]; q = red[4]+red[5]+red[6]+red[7];
  float mean = s*(1.f/2304.f);
  float rstd = rsqrtf(q*(1.f/2304.f) - mean*mean + 1e-5f);
  #pragma unroll
  for(int j=0;j<9;j++){
    int e = threadIdx.x + j*256;
    out[(size_t)row*E_ + e] = (v[j]-mean)*rstd*g[e] + b[e];
  }
}

// ---------------- obj_kernels output transpose ----------------
__global__ __launch_bounds__(256) void k_objk(const float* __restrict__ obj2, float* __restrict__ outk){
  int i = blockIdx.x*256 + threadIdx.x;
  if(i >= ROWS_*C_) return;
  int kk = i % 9; int t = i / 9; int c = t & 255; int np = t >> 8;
  outk[i] = obj2[((size_t)np*9 + kk)*C_ + c];
}

// ---------------- x pre-transpose to bf16: xT[n][c/8][h][w][8] ----------------
__global__ __launch_bounds__(256) void k_prep_x(const float* __restrict__ x, __bf16* __restrict__ xT){
  int i = blockIdx.x*256 + threadIdx.x;     // (n, g, h, w) flattened
  if(i >= N_*32*H_*W_) return;
  int w = i % W_; int t = i / W_;
  int h = t % H_; t /= H_;
  int g = t % 32; int n = t / 32;
  const float* xp = &x[((size_t)(n*C_ + g*8)*H_ + h)*W_ + w];
  bf16x8 v;
  #pragma unroll
  for(int u=0;u<8;u++) v[u] = (__bf16)xp[(size_t)u*HW_];
  *(bf16x8*)&xT[(size_t)i*8] = v;
}

// ---------------- kernel permute: kerP[nps][c0b][tap][oct][pl][8] from mfF(bf16) ----------------
__global__ __launch_bounds__(256) void k_permute_ker(const __bf16* __restrict__ mfFb, __bf16* __restrict__ kerP){
  int i = blockIdx.x*256 + threadIdx.x;   // bf16x8 index
  if(i >= 73728) return;                  // 4 nps * 8 c0b * 9 tap * 4 oct * 64 pl
  int pl = i & 63; int t = i >> 6;
  int oct = t & 3; t >>= 2;
  int tap = t % 9; t /= 9;
  int c0b = t & 7; int nps = t >> 3;
  int n = nps >> 1, ps = nps & 1;
  int p = ps*64 + pl;
  bf16x8 v;
  if(p < P_){
    v = *(const bf16x8*)&mfFb[((size_t)(n*P_+p)*9 + tap)*C_ + c0b*32 + oct*8];
  } else {
    #pragma unroll
    for(int u=0;u<8;u++) v[u] = (__bf16)0.f;
  }
  *(bf16x8*)&kerP[(size_t)i*8] = v;
}

// ---------------- dynamic conv via implicit-GEMM bf16 MFMA ----------------
// Register-staged double buffer: next c0-step's global loads issue right after
// the barrier and fly during the MFMA cluster; ds_writes after the next barrier.
__global__ __launch_bounds__(256) void k_conv_mfma(const __bf16* __restrict__ xT, const __bf16* __restrict__ kerP,
                                                   float* __restrict__ out){
  const int wt = blockIdx.x, ht = blockIdx.y, z = blockIdx.z;
  const int n = z >> 1, ps = z & 1;
  const int pbase = ps*64;
  const int NT = ps ? 3 : 4;
  const int tid = threadIdx.x;
  const int hi = tid >> 6;
  const int lane = tid & 63;
  const int col = lane & 15, quad = lane >> 4;
  const int w0 = wt*64, h0 = ht*4;

  __shared__ __bf16 xs[6][4][66][8];
  __shared__ __bf16 ks[9][4][64][8];
  __bf16* ksf = &ks[0][0][0][0];

  f32x4 acc[4][4] = {};

  int xoff[7];
  __bf16* xlds[7];
  #pragma unroll
  for(int j=0;j<7;j++){
    int i = tid + j*256;
    if(i < 1584){
      int oct = i/396; int rem = i - oct*396;
      int hy = rem/66, wx = rem - hy*66;
      int hh = h0 - 1 + hy, ww = w0 - 1 + wx;
      xlds[j] = &xs[hy][oct][wx][0];
      xoff[j] = (hh>=0 && hh<H_ && ww>=0 && ww<W_) ? (((n*32+oct)*H_ + hh)*W_ + ww)*8 : -1;
    } else { xlds[j] = nullptr; xoff[j] = -1; }
  }
  const __bf16* kbase = kerP + (size_t)(n*2+ps)*8*2304*8;

  bf16x8 xv[7], kv[9];
  bf16x8 zro;
  #pragma unroll
  for(int u=0;u<8;u++) zro[u] = (__bf16)0.f;
  #pragma unroll
  for(int j=0;j<7;j++) xv[j] = zro;
  #pragma unroll
  for(int j=0;j<7;j++)
    if(xoff[j] >= 0) xv[j] = *(const bf16x8*)&xT[xoff[j]];
  #pragma unroll
  for(int j=0;j<9;j++) kv[j] = *(const bf16x8*)&kbase[(size_t)(tid + j*256)*8];

  for(int s=0; s<8; s++){
    __syncthreads();
    #pragma unroll
    for(int j=0;j<7;j++)
      if(tid + j*256 < 1584) *(bf16x8*)xlds[j] = xv[j];
    #pragma unroll
    for(int j=0;j<9;j++) *(bf16x8*)&ksf[(size_t)(tid + j*256)*8] = kv[j];
    __syncthreads();
    if(s < 7){
      #pragma unroll
      for(int j=0;j<7;j++)
        if(xoff[j] >= 0) xv[j] = *(const bf16x8*)&xT[xoff[j] + (s+1)*786432];
      const __bf16* kb2 = kbase + (size_t)(s+1)*18432;
      #pragma unroll
      for(int j=0;j<9;j++) kv[j] = *(const bf16x8*)&kb2[(size_t)(tid + j*256)*8];
    }
    #pragma unroll
    for(int ky=0; ky<3; ky++){
      #pragma unroll
      for(int kx=0; kx<3; kx++){
        const int tap = ky*3 + kx;
        const int hy = hi + ky;
        bf16x8 b[4];
        #pragma unroll
        for(int t=0;t<4;t++) b[t] = *(const bf16x8*)&xs[hy][quad][t*16 + col + kx][0];
        #pragma unroll
        for(int pt=0; pt<4; pt++){
          if(pt < NT){
            bf16x8 a = *(const bf16x8*)&ks[tap][quad][pt*16 + col][0];
            #pragma unroll
            for(int t=0;t<4;t++)
              acc[pt][t] = __builtin_amdgcn_mfma_f32_16x16x32_bf16(a, b[t], acc[pt][t], 0, 0, 0);
          }
        }
      }
    }
  }
  const int h = h0 + hi;
  #pragma unroll
  for(int pt=0; pt<4; pt++){
    if(pt < NT){
      #pragma unroll
      for(int r=0;r<4;r++){
        int p = pbase + pt*16 + quad*4 + r;
        if(p < P_){
          float* op = &out[((size_t)(n*P_+p)*H_ + h)*W_ + w0 + col];
          #pragma unroll
          for(int t=0;t<4;t++) op[t*16] = acc[pt][t][r];
        }
      }
    }
  }
}

extern "C" void kernel_launch(void* const* d_in, const int* in_sizes, int n_in,
                              void* d_out, int out_size, void* d_ws, size_t ws_size,
                              hipStream_t stream)
{
  (void)in_sizes; (void)n_in; (void)out_size; (void)ws_size;
  const float* x          = (const float*)d_in[0];
  const float* prop       = (const float*)d_in[1];
  const float* mask_pred  = (const float*)d_in[2];
  const float* ku_dyn_w   = (const float*)d_in[3];
  const float* ku_dyn_b   = (const float*)d_in[4];
  const float* ku_in_w    = (const float*)d_in[5];
  const float* ku_in_b    = (const float*)d_in[6];
  const float* ku_ig_w    = (const float*)d_in[7];
  const float* ku_ig_b    = (const float*)d_in[8];
  const float* ku_ug_w    = (const float*)d_in[9];
  const float* ku_ug_b    = (const float*)d_in[10];
  const float* ku_nin_g   = (const float*)d_in[11];
  const float* ku_nin_b   = (const float*)d_in[12];
  const float* ku_nout_g  = (const float*)d_in[13];
  const float* ku_nout_b  = (const float*)d_in[14];
  const float* ku_inin_g  = (const float*)d_in[15];
  const float* ku_inin_b  = (const float*)d_in[16];
  const float* ku_inout_g = (const float*)d_in[17];
  const float* ku_inout_b = (const float*)d_in[18];
  const float* ku_fc_w    = (const float*)d_in[19];
  const float* ku_fc_b    = (const float*)d_in[20];
  const float* ku_fcn_g   = (const float*)d_in[21];
  const float* ku_fcn_b   = (const float*)d_in[22];
  const float* attn_in_w  = (const float*)d_in[23];
  const float* attn_in_b  = (const float*)d_in[24];
  const float* attn_out_w = (const float*)d_in[25];
  const float* attn_out_b = (const float*)d_in[26];
  const float* attn_ln_g  = (const float*)d_in[27];
  const float* attn_ln_b  = (const float*)d_in[28];
  const float* ffn_w1     = (const float*)d_in[29];
  const float* ffn_b1     = (const float*)d_in[30];
  const float* ffn_w2     = (const float*)d_in[31];
  const float* ffn_b2     = (const float*)d_in[32];
  const float* ffn_ln_g   = (const float*)d_in[33];
  const float* ffn_ln_b   = (const float*)d_in[34];
  const float* mask_fc_ws = (const float*)d_in[35];
  const float* mask_fc_ln_g = (const float*)d_in[36];
  const float* mask_fc_ln_b = (const float*)d_in[37];
  const float* fc_mask_w  = (const float*)d_in[38];
  const float* fc_mask_b  = (const float*)d_in[39];

  float* ws = (float*)d_ws;
  float* sig     = ws;
  float* hbuf    = ws;
  float* skA     = ws;                // split-K scratch: attn_in S=6 needs 8.29M floats [0..8294400)
  float* kT      = ws;                // attn K-transpose (589824 floats) — dead before attn_out GEMM
  float* partial = ws + 4915200;      // dead after k_xfeat2
  float* skB     = ws + 4915200;      // split-K scratch (ffn2)
  float* attnO   = ws + 4915200 + 1382400;
  float* tproj   = ws + 4915200 + 1843200;
  float* tmp     = ws + 4915200 + 2304000;  // pre-LN gemm output (1800x256)
  float* qkv     = ws + 8294400;
  float* xfeat   = ws + 9830400;
  float* params  = xfeat + 51200;
  float* pf      = params + 102400;
  float* inp     = pf + 460800;
  float* gate    = inp + 921600;
  float* ig      = gate + 460800;
  float* ug      = ig + 460800;
  float* feat    = ug + 460800;
  float* obj0    = feat + 460800;
  float* obj1    = obj0 + 460800;
  float* obj2    = obj1 + 460800;
  float* mf1     = obj2 + 460800;
  float* mf2     = mf1 + 460800;
  float* mfF     = mf2 + 460800;
  __bf16* xT = (__bf16*)ws;
  __bf16* kerP = (__bf16*)(ws + 6758400);

  float* out_masks = (float*)d_out;
  float* out_kern  = out_masks + (size_t)N_*P_*HW_;

  k_softmax<<<192, 256, 0, stream>>>(mask_pred, sig);
  k_permute_pf<<<1800, 256, 0, stream>>>(prop, pf);
  k_xfeat1m<<<dim3(2,XKC_,2), 256, 0, stream>>>(sig, x, partial);
  k_xfeat2<<<200, 256, 0, stream>>>(partial, xfeat);
  k_gemm_mfma<<<dim3(4,4),   256, 0, stream>>>(xfeat, ku_dyn_w, ku_dyn_b, params, 200, 512, 256, 0);
  k_gemm_mfma<<<dim3(4,29),  256, 0, stream>>>(pf, ku_in_w, ku_in_b, inp, 1800, 512, 256, 0);
  k_gate<<<1800, 256, 0, stream>>>(inp, params, gate);
  k_gemm_mfma<<<dim3(2,29),  256, 0, stream>>>(gate, ku_ig_w, ku_ig_b, tmp, 1800, 256, 256, 0);
  k_ln256<<<450, 256, 0, stream>>>(tmp, nullptr, ku_inin_g, ku_inin_b, ig, 1800, 2);
  k_gemm_mfma<<<dim3(2,29),  256, 0, stream>>>(gate, ku_ug_w, ku_ug_b, tmp, 1800, 256, 256, 0);
  k_ln256<<<450, 256, 0, stream>>>(tmp, nullptr, ku_nin_g, ku_nin_b, ug, 1800, 2);
  k_combine<<<1800, 256, 0, stream>>>(params, inp, ug, ig, ku_nout_g, ku_nout_b, ku_inout_g, ku_inout_b, feat);
  k_gemm_mfma<<<dim3(2,29),  256, 0, stream>>>(feat, ku_fc_w, ku_fc_b, tmp, 1800, 256, 256, 0);
  k_ln256<<<450, 256, 0, stream>>>(tmp, nullptr, ku_fcn_g, ku_fcn_b, obj0, 1800, 1);
  // attn_in: BM=256/BN=64, split-K x6 (KC=384), register-staged dbuf
  k_gemm_skM256<<<dim3(108,6), 256, 0, stream>>>(obj0, attn_in_w, skA, 200, 6912, 2304, 384);
  k_redk<<<1350, 256, 0, stream>>>(skA, attn_in_b, qkv, 200, 6912, 6);
  // attention: K transpose then barrier-free wave-per-(q,h)
  k_prep_kT<<<1152, 256, 0, stream>>>(qkv, (float2*)kT);
  k_attn3<<<dim3(25,8,2), 256, 0, stream>>>(qkv, (const float2*)kT, attnO);
  // attn_out: BM=256/BN=64, split-K x9 (KC=256), register-staged dbuf
  k_gemm_skM256<<<dim3(36,9), 256, 0, stream>>>(attnO, attn_out_w, skA, 200, 2304, 2304, 256);
  k_redk<<<450, 256, 0, stream>>>(skA, attn_out_b, tproj, 200, 2304, 9);
  k_add_ln2304<<<200, 256, 0, stream>>>(obj0, tproj, attn_ln_g, attn_ln_b, obj1);
  k_gemm_mfma<<<dim3(16,29), 256, 0, stream>>>(obj1, ffn_w1, ffn_b1, hbuf, 1800, 2048, 256, 1);
  // ffn2: split-K x4 (K=2048 -> 4x512); scratch in dead region above hbuf
  k_gemm_splitk<<<232, 256, 0, stream>>>(hbuf, ffn_w2, skB, 1800, 256, 2048, 512, 2, 29);
  k_redk<<<450, 256, 0, stream>>>(skB, ffn_b2, tmp, 1800, 256, 4);
  k_ln256<<<450, 256, 0, stream>>>(tmp, obj1, ffn_ln_g, ffn_ln_b, obj2, 1800, 0);
  k_gemm_mfma<<<dim3(2,29),  256, 0, stream>>>(obj2, mask_fc_ws,          nullptr, tmp, 1800, 256, 256, 0);
  k_ln256<<<450, 256, 0, stream>>>(tmp, nullptr, mask_fc_ln_g,       mask_fc_ln_b,       mf1, 1800, 1);
  k_gemm_mfma<<<dim3(2,29),  256, 0, stream>>>(mf1,  mask_fc_ws + 65536,  nullptr, tmp, 1800, 256, 256, 0);
  k_ln256<<<450, 256, 0, stream>>>(tmp, nullptr, mask_fc_ln_g + 256, mask_fc_ln_b + 256, mf2, 1800, 1);
  k_gemm_mfma<<<dim3(2,29),  256, 0, stream>>>(mf2,  mask_fc_ws + 131072, nullptr, tmp, 1800, 256, 256, 0);
  k_ln256<<<450, 256, 0, stream>>>(tmp, nullptr, mask_fc_ln_g + 512, mask_fc_ln_b + 512, mf1, 1800, 1);
  // final kernel GEMM stores bf16 directly (identical numerics: same RNE convert)
  k_gemm_mfma<<<dim3(2,29),  256, 0, stream>>>(mf1, fc_mask_w, fc_mask_b, mfF, 1800, 256, 256, 3);
  k_objk<<<1800, 256, 0, stream>>>(obj2, out_kern);
  k_permute_ker<<<288, 256, 0, stream>>>((const __bf16*)mfF, kerP);
  k_prep_x<<<6144, 256, 0, stream>>>(x, xT);
  k_conv_mfma<<<dim3(3,32,4), 256, 0, stream>>>(xT, kerP, out_masks);
}